// Round 2
// baseline (2057.938 us; speedup 1.0000x reference)
//
#include <hip/hip_runtime.h>
#include <hip/hip_bf16.h>
#include <math.h>

typedef __hip_bfloat16 bf16;

#define B_    8
#define T_    32
#define N_    64
#define F_    6
#define D_    128
#define E_    4032      // N*(N-1)
#define BT_   256       // B*T
#define NT_   16384     // BT*N  (spatial rows)
#define BN_   512       // B*N   (temporal batches)
#define ROWS_ 16384     // BN*T  (temporal rows)

__device__ __forceinline__ float gelu_exact(float x) {
    return 0.5f * x * (1.0f + erff(x * 0.70710678118654752f));
}

// ---------------------------------------------------------------------------
// Dtype detector: interpret probe as bf16[n]; count implausible exponents.
// True bf16 weights (|x| ~ 1e-4..0.3): exponent in [100,130], junk ~0.
// fp32 data read as bf16 pairs: low halves have uniform-random exponents,
// junk ~44%. flag=1 -> fp32 inputs, flag=0 -> bf16 inputs.
__global__ void k_detect(const unsigned short* __restrict__ probe, int n,
                         int* __restrict__ flag) {
    __shared__ int cnt;
    if (threadIdx.x == 0) cnt = 0;
    __syncthreads();
    int junk = 0;
    for (int i = threadIdx.x; i < n; i += blockDim.x) {
        unsigned short u = probe[i];
        int e = (u >> 7) & 0xFF;
        if (e != 0 && (e < 100 || e > 130)) junk++;
    }
    atomicAdd(&cnt, junk);
    __syncthreads();
    if (threadIdx.x == 0) *flag = (cnt * 4 > n) ? 1 : 0;
}

// Convert input i (bf16 or fp32 per flag) to fp32 in ws.
__global__ void k_cvt(const void* __restrict__ src, float* __restrict__ dst,
                      int n, const int* __restrict__ flag) {
    int i = blockIdx.x * blockDim.x + threadIdx.x;
    if (i >= n) return;
    if (*flag) dst[i] = ((const float*)src)[i];
    else       dst[i] = __bfloat162float(((const bf16*)src)[i]);
}

// ---------------------------------------------------------------------------
// h[node,d] = input[node,:6] @ proj_W[:,d] + proj_b[d]
__global__ void k_proj(const float* __restrict__ inp, const float* __restrict__ W,
                       const float* __restrict__ b, float* __restrict__ h) {
    int i = blockIdx.x * blockDim.x + threadIdx.x;   // NT_*D_ threads
    int d = i & (D_ - 1);
    int node = i >> 7;
    float acc = b[d];
#pragma unroll
    for (int k = 0; k < F_; k++)
        acc = fmaf(inp[node * F_ + k], W[k * D_ + d], acc);
    h[i] = acc;
}

// ---------------------------------------------------------------------------
// Generic row-GEMM: one block per row m, blockDim.x = N columns.
__global__ void k_gemm(const float* __restrict__ A, int K,
                       const float* __restrict__ Bm, const float* __restrict__ bias,
                       float* __restrict__ C, int ldc, int act) {
    extern __shared__ float a_s[];
    int m = blockIdx.x;
    int n = threadIdx.x;
    int N = blockDim.x;
    for (int k = n; k < K; k += N) a_s[k] = A[(size_t)m * K + k];
    __syncthreads();
    float acc = bias[n];
    for (int k = 0; k < K; k++)
        acc = fmaf(a_s[k], Bm[(size_t)k * N + n], acc);
    if (act == 1) acc = gelu_exact(acc);
    C[(size_t)m * ldc + n] = acc;
}

// ---------------------------------------------------------------------------
// Fused: y = LN( z_row + (optional res2_row) + A_row @ B + bias ) * g + b
__global__ __launch_bounds__(128)
void k_gemm_ln(const float* __restrict__ A, int K,
               const float* __restrict__ Bm, const float* __restrict__ bias,
               const float* __restrict__ res2,
               const float* __restrict__ g, const float* __restrict__ bb,
               float* __restrict__ z) {
    __shared__ float a_s[512];
    __shared__ float wsum[2];
    __shared__ float wsum2[2];
    int m = blockIdx.x;
    int n = threadIdx.x;
    for (int k = n; k < K; k += 128) a_s[k] = A[(size_t)m * K + k];
    __syncthreads();
    float acc = bias[n];
    for (int k = 0; k < K; k++)
        acc = fmaf(a_s[k], Bm[(size_t)k * D_ + n], acc);
    acc += z[(size_t)m * D_ + n];
    if (res2) acc += res2[(size_t)m * D_ + n];
    float s = acc;
#pragma unroll
    for (int off = 32; off >= 1; off >>= 1) s += __shfl_down(s, off, 64);
    if ((n & 63) == 0) wsum[n >> 6] = s;
    __syncthreads();
    float mean = (wsum[0] + wsum[1]) * (1.0f / 128.0f);
    float d = acc - mean;
    float s2 = d * d;
#pragma unroll
    for (int off = 32; off >= 1; off >>= 1) s2 += __shfl_down(s2, off, 64);
    if ((n & 63) == 0) wsum2[n >> 6] = s2;
    __syncthreads();
    float var = (wsum2[0] + wsum2[1]) * (1.0f / 128.0f);
    float y = d * rsqrtf(var + 1e-5f) * g[n] + bb[n];
    z[(size_t)m * D_ + n] = y;
}

// ---------------------------------------------------------------------------
// Spatial edge attention. grid = (BT_, 2 head-pairs), block = 128.
// e = ea*We + be is rank-1: never materialized.
__global__ __launch_bounds__(128)
void k_edge_attn(const float* __restrict__ q, const float* __restrict__ k,
                 const float* __restrict__ v, const float* __restrict__ ea,
                 const float* __restrict__ We, const float* __restrict__ be,
                 float* __restrict__ agg) {
    int bt = blockIdx.x;
    int hp = blockIdx.y;
    __shared__ float Ks[64 * 64];
    __shared__ float Vs[64 * 64];
    __shared__ float EAs[E_];
    __shared__ float WeS[64], beS[64];
    int tid = threadIdx.x;
    const float* kb = k + (size_t)bt * 64 * 128 + hp * 64;
    const float* vb = v + (size_t)bt * 64 * 128 + hp * 64;
    for (int i = tid; i < 64 * 64; i += 128) {
        int r = i >> 6, c = i & 63;
        Ks[i] = kb[r * 128 + c];
        Vs[i] = vb[r * 128 + c];
    }
    const float* eab = ea + (size_t)bt * E_;
    for (int i = tid; i < E_; i += 128) EAs[i] = eab[i];
    if (tid < 64) { WeS[tid] = We[hp * 64 + tid]; beS[tid] = be[hp * 64 + tid]; }
    __syncthreads();

    int dst = tid & 63, hh = tid >> 6;
    int cb = hh * 32;
    const float* qrow = q + (size_t)bt * 8192 + dst * 128 + hp * 64 + cb;
    float qr[32];
#pragma unroll
    for (int c = 0; c < 32; c++) qr[c] = qrow[c];
    float qWe = 0.f, qbe = 0.f;
#pragma unroll
    for (int c = 0; c < 32; c++) {
        qWe = fmaf(qr[c], WeS[cb + c], qWe);
        qbe = fmaf(qr[c], beS[cb + c], qbe);
    }
    const float scale = 0.17677669529663687f;   // 1/sqrt(32)
    float mmax = -1e30f, l = 0.f, accEA = 0.f;
    float acc[32];
#pragma unroll
    for (int c = 0; c < 32; c++) acc[c] = 0.f;

    for (int s = 0; s < 64; s++) {
        if (s == dst) continue;
        float dot = 0.f;
        const float* kr = &Ks[s * 64 + cb];
#pragma unroll
        for (int c = 0; c < 32; c++) dot = fmaf(qr[c], kr[c], dot);
        int eid = s * 63 + dst - (dst > s ? 1 : 0);
        float eav = EAs[eid];
        float alpha = scale * (dot + eav * qWe + qbe);
        float mnew = fmaxf(mmax, alpha);
        float corr = __expf(mmax - mnew);
        float w = __expf(alpha - mnew);
        l = l * corr + w;
        accEA = accEA * corr + w * eav;
        const float* vr = &Vs[s * 64 + cb];
#pragma unroll
        for (int c = 0; c < 32; c++) acc[c] = fmaf(acc[c], corr, w * vr[c]);
        mmax = mnew;
    }
    float inv = 1.0f / l;
    float* ag = agg + (size_t)bt * 8192 + dst * 128 + hp * 64 + cb;
#pragma unroll
    for (int c = 0; c < 32; c++) ag[c] = fmaf(accEA * WeS[cb + c] + acc[c], inv, beS[cb + c]);
}

// ---------------------------------------------------------------------------
// h (B,T,N,D) -> z (B*N, T, D) with temporal positional add
__global__ void k_trans(const float* __restrict__ h, const float* __restrict__ pos,
                        float* __restrict__ z) {
    int i = blockIdx.x * blockDim.x + threadIdx.x;   // ROWS_*D_
    int d = i & 127;
    int r = i >> 7;          // r = bn*T + t
    int t = r & 31;
    int bn = r >> 5;
    int b = bn >> 6;
    int n = bn & 63;
    int node = (b * T_ + t) * N_ + n;
    z[i] = h[(size_t)node * D_ + d] + pos[t * D_ + d];
}

// ---------------------------------------------------------------------------
// Temporal causal attention. grid = BN_, block = 128 (32 t x 4 heads).
__global__ __launch_bounds__(128)
void k_tattn(const float* __restrict__ qkv, float* __restrict__ o) {
    int bn = blockIdx.x;
    __shared__ float Ks[32 * 128];
    __shared__ float Vs[32 * 128];
    int tid = threadIdx.x;
    const float* base = qkv + (size_t)bn * 32 * 384;
    for (int i = tid; i < 32 * 128; i += 128) {
        int r = i >> 7, c = i & 127;
        Ks[i] = base[r * 384 + 128 + c];
        Vs[i] = base[r * 384 + 256 + c];
    }
    __syncthreads();
    int t = tid & 31, h = tid >> 5;
    int cb = h * 32;
    float qr[32];
    const float* qrow = base + t * 384 + cb;
#pragma unroll
    for (int c = 0; c < 32; c++) qr[c] = qrow[c];
    const float scale = 0.17677669529663687f;
    float mmax = -1e30f, l = 0.f, acc[32];
#pragma unroll
    for (int c = 0; c < 32; c++) acc[c] = 0.f;
    for (int j = 0; j <= t; j++) {
        float dot = 0.f;
        const float* kr = &Ks[j * 128 + cb];
#pragma unroll
        for (int c = 0; c < 32; c++) dot = fmaf(qr[c], kr[c], dot);
        float alpha = dot * scale;
        float mnew = fmaxf(mmax, alpha);
        float corr = __expf(mmax - mnew);
        float w = __expf(alpha - mnew);
        l = l * corr + w;
        const float* vr = &Vs[j * 128 + cb];
#pragma unroll
        for (int c = 0; c < 32; c++) acc[c] = fmaf(acc[c], corr, w * vr[c]);
        mmax = mnew;
    }
    float inv = 1.0f / l;
    float* orow = o + (size_t)(bn * 32 + t) * 128 + cb;
#pragma unroll
    for (int c = 0; c < 32; c++) orow[c] = acc[c] * inv;
}

// ---------------------------------------------------------------------------
// Head: out[bn,:6] = gelu(z_last @ W1 + b1) @ W2 + b2  (dtype per flag)
__global__ __launch_bounds__(128)
void k_head(const float* __restrict__ z, const float* __restrict__ W1,
            const float* __restrict__ b1, const float* __restrict__ W2,
            const float* __restrict__ b2, void* __restrict__ out,
            const int* __restrict__ flag) {
    int bn = blockIdx.x;
    int d = threadIdx.x;
    __shared__ float zl[128], h1[128];
    zl[d] = z[(size_t)(bn * 32 + 31) * 128 + d];
    __syncthreads();
    float acc = b1[d];
    for (int k = 0; k < 128; k++) acc = fmaf(zl[k], W1[k * 128 + d], acc);
    h1[d] = gelu_exact(acc);
    __syncthreads();
    if (d < F_) {
        float o = b2[d];
        for (int k = 0; k < 128; k++) o = fmaf(h1[k], W2[k * F_ + d], o);
        if (*flag) ((float*)out)[bn * F_ + d] = o;
        else       ((bf16*)out)[bn * F_ + d] = __float2bfloat16(o);
    }
}

// ---------------------------------------------------------------------------
extern "C" void kernel_launch(void* const* d_in, const int* in_sizes, int n_in,
                              void* d_out, int out_size, void* d_ws, size_t ws_size,
                              hipStream_t stream) {
    char* wsb = (char*)d_ws;
    int* flag = (int*)wsb;                           // 256 B reserved
    float* f = (float*)(wsb + 256);
    float* h   = f;                                  // NT_*D_
    float* z   = f + (size_t)NT_ * D_;               // ROWS_*D_
    float* agg = f + 2 * (size_t)NT_ * D_;           // NT_*D_
    float* big = f + 3 * (size_t)NT_ * D_;           // NT_*512
    float* bq  = big;
    float* bk  = big + (size_t)NT_ * D_;
    float* bv  = big + 2 * (size_t)NT_ * D_;

    // dtype detect on proj_W (768 elements; probe 768 bf16 = 1536 B, in
    // bounds for either dtype)
    k_detect<<<1, 256, 0, stream>>>((const unsigned short*)d_in[2], 768, flag);

    // convert all 33 float inputs (index 33 = edge_index, int32) to fp32 in ws
    float* cvt[33];
    float* cur = f + (size_t)NT_ * 896;              // after compute region
    for (int i = 0; i < 33; i++) {
        int n = in_sizes[i];
        cvt[i] = cur;
        cur += n;
        k_cvt<<<(n + 255) / 256, 256, 0, stream>>>(d_in[i], cvt[i], n, flag);
    }

    const float* input_frames = cvt[0];
    const float* edge_attr    = cvt[1];
    const float* proj_W = cvt[2],  *proj_b = cvt[3];
    const float* sp_Wq = cvt[4],   *sp_bq = cvt[5];
    const float* sp_Wk = cvt[6],   *sp_bk = cvt[7];
    const float* sp_Wv = cvt[8],   *sp_bv = cvt[9];
    const float* sp_We = cvt[10],  *sp_be = cvt[11];
    const float* sp_Ws = cvt[12],  *sp_bs = cvt[13];
    const float* sp_lng = cvt[14], *sp_lnb = cvt[15];
    const float* tpos = cvt[16];
    const float* t_Wqkv = cvt[17], *t_bqkv = cvt[18];
    const float* t_Wo = cvt[19],   *t_bo = cvt[20];
    const float* t_ln1g = cvt[21], *t_ln1b = cvt[22];
    const float* t_W1 = cvt[23],   *t_b1 = cvt[24];
    const float* t_W2 = cvt[25],   *t_b2 = cvt[26];
    const float* t_ln2g = cvt[27], *t_ln2b = cvt[28];
    const float* head_W1 = cvt[29], *head_b1 = cvt[30];
    const float* head_W2 = cvt[31], *head_b2 = cvt[32];

    k_proj<<<NT_ * D_ / 256, 256, 0, stream>>>(input_frames, proj_W, proj_b, h);

    for (int l = 0; l < 3; l++) {
        k_gemm<<<NT_, 128, 128 * 4, stream>>>(h, 128, sp_Wq + (size_t)l * D_ * D_,
                                              sp_bq + l * D_, bq, 128, 0);
        k_gemm<<<NT_, 128, 128 * 4, stream>>>(h, 128, sp_Wk + (size_t)l * D_ * D_,
                                              sp_bk + l * D_, bk, 128, 0);
        k_gemm<<<NT_, 128, 128 * 4, stream>>>(h, 128, sp_Wv + (size_t)l * D_ * D_,
                                              sp_bv + l * D_, bv, 128, 0);
        dim3 g(BT_, 2);
        k_edge_attn<<<g, 128, 0, stream>>>(bq, bk, bv, edge_attr,
                                           sp_We + l * D_, sp_be + l * D_, agg);
        k_gemm_ln<<<NT_, 128, 0, stream>>>(h, 128, sp_Ws + (size_t)l * D_ * D_,
                                           sp_bs + l * D_, agg,
                                           sp_lng + l * D_, sp_lnb + l * D_, h);
    }

    k_trans<<<ROWS_ * D_ / 256, 256, 0, stream>>>(h, tpos, z);

    for (int l = 0; l < 3; l++) {
        k_gemm<<<ROWS_, 384, 128 * 4, stream>>>(z, 128, t_Wqkv + (size_t)l * D_ * 384,
                                                t_bqkv + l * 384, big, 384, 0);
        k_tattn<<<BN_, 128, 0, stream>>>(big, agg);
        k_gemm_ln<<<ROWS_, 128, 0, stream>>>(agg, 128, t_Wo + (size_t)l * D_ * D_,
                                             t_bo + l * D_, nullptr,
                                             t_ln1g + l * D_, t_ln1b + l * D_, z);
        k_gemm<<<ROWS_, 512, 128 * 4, stream>>>(z, 128, t_W1 + (size_t)l * D_ * 512,
                                                t_b1 + l * 512, big, 512, 1);
        k_gemm_ln<<<ROWS_, 128, 0, stream>>>(big, 512, t_W2 + (size_t)l * 512 * D_,
                                             t_b2 + l * D_, nullptr,
                                             t_ln2g + l * D_, t_ln2b + l * D_, z);
    }

    k_head<<<BN_, 128, 0, stream>>>(z, head_W1, head_b1, head_W2, head_b2,
                                    d_out, flag);
}

// Round 3
// 578.278 us; speedup vs baseline: 3.5587x; 3.5587x over previous
//
#include <hip/hip_runtime.h>
#include <hip/hip_bf16.h>
#include <math.h>

typedef __hip_bfloat16 bf16;
typedef short short8 __attribute__((ext_vector_type(8)));
typedef float floatx4 __attribute__((ext_vector_type(4)));

#define B_    8
#define T_    32
#define N_    64
#define F_    6
#define D_    128
#define E_    4032      // N*(N-1)
#define BT_   256       // B*T
#define NT_   16384     // BT*N  (spatial rows)
#define BN_   512       // B*N   (temporal batches)
#define ROWS_ 16384     // BN*T  (temporal rows)

__device__ __forceinline__ float gelu_exact(float x) {
    return 0.5f * x * (1.0f + erff(x * 0.70710678118654752f));
}

// ---------------------------------------------------------------------------
// Repack weights (fp32, row-major KxN, L layers) into MFMA B-fragment layout:
// Bp[((l*ktiles + kt)*ntt + nt + ntoff)*64 + lane][j] =
//     bf16( W[l][kt*32 + (lane>>4)*8 + j][nt*16 + (lane&15)] )
struct RepackDesc { const float* W; bf16* out; int K, N, ntt, ntoff, L, start; };
struct RepackArgs { RepackDesc d[8]; int total; };

__global__ void k_repack(RepackArgs ra) {
    int gid = blockIdx.x * blockDim.x + threadIdx.x;
    if (gid >= ra.total) return;
    int fi = 0;
    while (fi < 7 && gid >= ra.d[fi + 1].start) fi++;
    RepackDesc dd = ra.d[fi];
    int r = gid - dd.start;
    int lane = r & 63; r >>= 6;
    int ntiles = dd.N >> 4;
    int nt = r % ntiles; r /= ntiles;
    int ktiles = dd.K >> 5;
    int kt = r % ktiles;
    int l = r / ktiles;
    int quad = lane >> 4, cc = lane & 15;
    const float* Wl = dd.W + (size_t)l * dd.K * dd.N;
    bf16* o = dd.out + ((((size_t)l * ktiles + kt) * dd.ntt + nt + dd.ntoff) * 64 + lane) * 8;
    int kb = kt * 32 + quad * 8;
    int n = nt * 16 + cc;
#pragma unroll
    for (int j = 0; j < 8; j++)
        o[j] = __float2bfloat16(Wl[(size_t)(kb + j) * dd.N + n]);
}

// concat spatial q/k/v biases: spb[l][0:128)=bq, [128:256)=bk, [256:384)=bv
__global__ void k_packbias(const float* __restrict__ bq, const float* __restrict__ bk,
                           const float* __restrict__ bv, float* __restrict__ out) {
    int i = blockIdx.x * blockDim.x + threadIdx.x;
    if (i >= 3 * 384) return;
    int l = i / 384, c = i % 384;
    float v = (c < 128) ? bq[l * 128 + c]
            : (c < 256) ? bk[l * 128 + c - 128]
                        : bv[l * 128 + c - 256];
    out[i] = v;
}

// ---------------------------------------------------------------------------
// MFMA GEMM: C[M x N] = A[M x K](bf16) * B(repacked bf16) + bias.
// Block = 256 thr = 4 waves; wave w -> rows blk*64 + w*16; NT 16-col tiles per
// wave (ntbase = blockIdx.y*NT). A-frag: lane holds A[m=lane&15][quad*8+j],
// one contiguous 16B load. C/D: col=lane&15, row=quad*4+reg.
template<int NT, int ACT, int OBF>
__global__ __launch_bounds__(256)
void k_mfma_gemm(const bf16* __restrict__ A, int K, const short8* __restrict__ Bp,
                 int ntt, const float* __restrict__ bias, void* __restrict__ Cv,
                 int ldc) {
    int lane = threadIdx.x & 63;
    int wave = threadIdx.x >> 6;
    int quad = lane >> 4, col = lane & 15;
    int ntbase = blockIdx.y * NT;
    size_t arow = (size_t)(blockIdx.x * 64 + wave * 16 + col) * K;
    const short8* Ap = (const short8*)(A + arow) + quad;
    floatx4 acc[NT];
#pragma unroll
    for (int t = 0; t < NT; t++) acc[t] = (floatx4){0.f, 0.f, 0.f, 0.f};
    int kch = K >> 5;
    for (int kt = 0; kt < kch; kt++) {
        short8 a = Ap[kt * 4];
        const short8* bp = Bp + ((size_t)kt * ntt + ntbase) * 64 + lane;
#pragma unroll
        for (int t = 0; t < NT; t++)
            acc[t] = __builtin_amdgcn_mfma_f32_16x16x32_bf16(a, bp[t * 64], acc[t], 0, 0, 0);
    }
    int orow0 = blockIdx.x * 64 + wave * 16 + quad * 4;
#pragma unroll
    for (int t = 0; t < NT; t++) {
        int oc = (ntbase + t) * 16 + col;
        float bv = bias[oc];
#pragma unroll
        for (int r = 0; r < 4; r++) {
            float v = acc[t][r] + bv;
            if (ACT) v = gelu_exact(v);
            size_t idx = (size_t)(orow0 + r) * ldc + oc;
            if (OBF) ((bf16*)Cv)[idx] = __float2bfloat16(v);
            else     ((float*)Cv)[idx] = v;
        }
    }
}

// ---------------------------------------------------------------------------
// h = input @ proj_W + proj_b ; writes fp32 master + bf16 copy
__global__ void k_proj(const float* __restrict__ inp, const float* __restrict__ W,
                       const float* __restrict__ b, float* __restrict__ h,
                       bf16* __restrict__ hb) {
    int i = blockIdx.x * blockDim.x + threadIdx.x;
    int d = i & (D_ - 1);
    int node = i >> 7;
    float acc = b[d];
#pragma unroll
    for (int k = 0; k < F_; k++)
        acc = fmaf(inp[node * F_ + k], W[k * D_ + d], acc);
    h[i] = acc;
    hb[i] = __float2bfloat16(acc);
}

// ---------------------------------------------------------------------------
// y = LN(x1 + x2 [+ x3]) * g + b  -> out32 (fp32) + outb (bf16)
// one row per wave (64 lanes x 2 cols), 4 rows per block
__global__ __launch_bounds__(256)
void k_ln(const float* __restrict__ x1, const float* __restrict__ x2,
          const float* __restrict__ x3, const float* __restrict__ g,
          const float* __restrict__ bb, float* __restrict__ out32,
          bf16* __restrict__ outb) {
    int row = blockIdx.x * 4 + (threadIdx.x >> 6);
    int lane = threadIdx.x & 63;
    size_t base = (size_t)row * 128;
    const float2* p1 = (const float2*)(x1 + base);
    const float2* p2 = (const float2*)(x2 + base);
    float2 v1 = p1[lane], v2 = p2[lane];
    float a = v1.x + v2.x, b = v1.y + v2.y;
    if (x3) {
        float2 v3 = ((const float2*)(x3 + base))[lane];
        a += v3.x; b += v3.y;
    }
    float s = a + b;
#pragma unroll
    for (int m = 32; m >= 1; m >>= 1) s += __shfl_xor(s, m, 64);
    float mean = s * (1.0f / 128.0f);
    float da = a - mean, db = b - mean;
    float s2 = da * da + db * db;
#pragma unroll
    for (int m = 32; m >= 1; m >>= 1) s2 += __shfl_xor(s2, m, 64);
    float inv = rsqrtf(s2 * (1.0f / 128.0f) + 1e-5f);
    int c = lane * 2;
    float ya = da * inv * g[c] + bb[c];
    float yb = db * inv * g[c + 1] + bb[c + 1];
    ((float2*)(out32 + base))[lane] = make_float2(ya, yb);
    outb[base + c]     = __float2bfloat16(ya);
    outb[base + c + 1] = __float2bfloat16(yb);
}

// ---------------------------------------------------------------------------
// Spatial edge attention; qkv rows stride 384 (q@0, k@128, v@256).
// e = ea*We + be is rank-1: never materialized.
__global__ __launch_bounds__(128)
void k_edge_attn(const float* __restrict__ qkv, const float* __restrict__ ea,
                 const float* __restrict__ We, const float* __restrict__ be,
                 float* __restrict__ agg) {
    int bt = blockIdx.x;
    int hp = blockIdx.y;
    __shared__ float Ks[64 * 64];
    __shared__ float Vs[64 * 64];
    __shared__ float EAs[E_];
    __shared__ float WeS[64], beS[64];
    int tid = threadIdx.x;
    const float* kb = qkv + (size_t)bt * 64 * 384 + 128 + hp * 64;
    const float* vb = qkv + (size_t)bt * 64 * 384 + 256 + hp * 64;
    for (int i = tid; i < 64 * 64; i += 128) {
        int r = i >> 6, c = i & 63;
        Ks[i] = kb[r * 384 + c];
        Vs[i] = vb[r * 384 + c];
    }
    const float* eab = ea + (size_t)bt * E_;
    for (int i = tid; i < E_; i += 128) EAs[i] = eab[i];
    if (tid < 64) { WeS[tid] = We[hp * 64 + tid]; beS[tid] = be[hp * 64 + tid]; }
    __syncthreads();

    int dst = tid & 63, hh = tid >> 6;
    int cb = hh * 32;
    const float* qrow = qkv + (size_t)(bt * 64 + dst) * 384 + hp * 64 + cb;
    float qr[32];
#pragma unroll
    for (int c = 0; c < 32; c++) qr[c] = qrow[c];
    float qWe = 0.f, qbe = 0.f;
#pragma unroll
    for (int c = 0; c < 32; c++) {
        qWe = fmaf(qr[c], WeS[cb + c], qWe);
        qbe = fmaf(qr[c], beS[cb + c], qbe);
    }
    const float scale = 0.17677669529663687f;   // 1/sqrt(32)
    float mmax = -1e30f, l = 0.f, accEA = 0.f;
    float acc[32];
#pragma unroll
    for (int c = 0; c < 32; c++) acc[c] = 0.f;

    for (int s = 0; s < 64; s++) {
        if (s == dst) continue;
        float dot = 0.f;
        const float* kr = &Ks[s * 64 + cb];
#pragma unroll
        for (int c = 0; c < 32; c++) dot = fmaf(qr[c], kr[c], dot);
        int eid = s * 63 + dst - (dst > s ? 1 : 0);
        float eav = EAs[eid];
        float alpha = scale * (dot + eav * qWe + qbe);
        float mnew = fmaxf(mmax, alpha);
        float corr = __expf(mmax - mnew);
        float w = __expf(alpha - mnew);
        l = l * corr + w;
        accEA = accEA * corr + w * eav;
        const float* vr = &Vs[s * 64 + cb];
#pragma unroll
        for (int c = 0; c < 32; c++) acc[c] = fmaf(acc[c], corr, w * vr[c]);
        mmax = mnew;
    }
    float inv = 1.0f / l;
    float* ag = agg + (size_t)(bt * 64 + dst) * 128 + hp * 64 + cb;
#pragma unroll
    for (int c = 0; c < 32; c++) ag[c] = fmaf(accEA * WeS[cb + c] + acc[c], inv, beS[cb + c]);
}

// ---------------------------------------------------------------------------
// h (B,T,N,D) -> z (B*N, T, D) + temporal pos; fp32 + bf16
__global__ void k_trans(const float* __restrict__ h, const float* __restrict__ pos,
                        float* __restrict__ z, bf16* __restrict__ zb) {
    int i = blockIdx.x * blockDim.x + threadIdx.x;
    int d = i & 127;
    int r = i >> 7;          // r = bn*T + t
    int t = r & 31;
    int bn = r >> 5;
    int b = bn >> 6;
    int n = bn & 63;
    int node = (b * T_ + t) * N_ + n;
    float v = h[(size_t)node * D_ + d] + pos[t * D_ + d];
    z[i] = v;
    zb[i] = __float2bfloat16(v);
}

// ---------------------------------------------------------------------------
// Temporal causal attention; qkv rows stride 384; output bf16.
__global__ __launch_bounds__(128)
void k_tattn(const float* __restrict__ qkv, bf16* __restrict__ o) {
    int bn = blockIdx.x;
    __shared__ float Ks[32 * 128];
    __shared__ float Vs[32 * 128];
    int tid = threadIdx.x;
    const float* base = qkv + (size_t)bn * 32 * 384;
    for (int i = tid; i < 32 * 128; i += 128) {
        int r = i >> 7, c = i & 127;
        Ks[i] = base[r * 384 + 128 + c];
        Vs[i] = base[r * 384 + 256 + c];
    }
    __syncthreads();
    int t = tid & 31, h = tid >> 5;
    int cb = h * 32;
    float qr[32];
    const float* qrow = base + t * 384 + cb;
#pragma unroll
    for (int c = 0; c < 32; c++) qr[c] = qrow[c];
    const float scale = 0.17677669529663687f;
    float mmax = -1e30f, l = 0.f, acc[32];
#pragma unroll
    for (int c = 0; c < 32; c++) acc[c] = 0.f;
    for (int j = 0; j <= t; j++) {
        float dot = 0.f;
        const float* kr = &Ks[j * 128 + cb];
#pragma unroll
        for (int c = 0; c < 32; c++) dot = fmaf(qr[c], kr[c], dot);
        float alpha = dot * scale;
        float mnew = fmaxf(mmax, alpha);
        float corr = __expf(mmax - mnew);
        float w = __expf(alpha - mnew);
        l = l * corr + w;
        const float* vr = &Vs[j * 128 + cb];
#pragma unroll
        for (int c = 0; c < 32; c++) acc[c] = fmaf(acc[c], corr, w * vr[c]);
        mmax = mnew;
    }
    float inv = 1.0f / l;
    bf16* orow = o + (size_t)(bn * 32 + t) * 128 + cb;
#pragma unroll
    for (int c = 0; c < 32; c++) orow[c] = __float2bfloat16(acc[c] * inv);
}

// ---------------------------------------------------------------------------
// Head: out[bn,:6] = gelu(z_last @ W1 + b1) @ W2 + b2  (fp32 out)
__global__ __launch_bounds__(128)
void k_head(const float* __restrict__ z, const float* __restrict__ W1,
            const float* __restrict__ b1, const float* __restrict__ W2,
            const float* __restrict__ b2, float* __restrict__ out) {
    int bn = blockIdx.x;
    int d = threadIdx.x;
    __shared__ float zl[128], h1[128];
    zl[d] = z[(size_t)(bn * 32 + 31) * 128 + d];
    __syncthreads();
    float acc = b1[d];
    for (int k = 0; k < 128; k++) acc = fmaf(zl[k], W1[k * 128 + d], acc);
    h1[d] = gelu_exact(acc);
    __syncthreads();
    if (d < F_) {
        float o = b2[d];
        for (int k = 0; k < 128; k++) o = fmaf(h1[k], W2[k * F_ + d], o);
        out[bn * F_ + d] = o;
    }
}

// ---------------------------------------------------------------------------
extern "C" void kernel_launch(void* const* d_in, const int* in_sizes, int n_in,
                              void* d_out, int out_size, void* d_ws, size_t ws_size,
                              hipStream_t stream) {
    const float* input_frames = (const float*)d_in[0];
    const float* edge_attr    = (const float*)d_in[1];
    const float* proj_W  = (const float*)d_in[2];
    const float* proj_b  = (const float*)d_in[3];
    const float* sp_Wq   = (const float*)d_in[4];
    const float* sp_bq   = (const float*)d_in[5];
    const float* sp_Wk   = (const float*)d_in[6];
    const float* sp_bk   = (const float*)d_in[7];
    const float* sp_Wv   = (const float*)d_in[8];
    const float* sp_bv   = (const float*)d_in[9];
    const float* sp_We   = (const float*)d_in[10];
    const float* sp_be   = (const float*)d_in[11];
    const float* sp_Ws   = (const float*)d_in[12];
    const float* sp_bs   = (const float*)d_in[13];
    const float* sp_lng  = (const float*)d_in[14];
    const float* sp_lnb  = (const float*)d_in[15];
    const float* tpos    = (const float*)d_in[16];
    const float* t_Wqkv  = (const float*)d_in[17];
    const float* t_bqkv  = (const float*)d_in[18];
    const float* t_Wo    = (const float*)d_in[19];
    const float* t_bo    = (const float*)d_in[20];
    const float* t_ln1g  = (const float*)d_in[21];
    const float* t_ln1b  = (const float*)d_in[22];
    const float* t_W1    = (const float*)d_in[23];
    const float* t_b1    = (const float*)d_in[24];
    const float* t_W2    = (const float*)d_in[25];
    const float* t_b2    = (const float*)d_in[26];
    const float* t_ln2g  = (const float*)d_in[27];
    const float* t_ln2b  = (const float*)d_in[28];
    const float* head_W1 = (const float*)d_in[29];
    const float* head_b1 = (const float*)d_in[30];
    const float* head_W2 = (const float*)d_in[31];
    const float* head_b2 = (const float*)d_in[32];

    const size_t M1 = 1u << 20;                      // 1M floats
    float* f    = (float*)d_ws;
    float* h32  = f;                                 // [0, 2M)
    bf16*  hb   = (bf16*)(f + 2 * M1);               // [2M, 3M)
    float* agg  = f + 3 * M1;                        // [3M, 5M)  (spatial)
    bf16*  o_b  = (bf16*)(f + 3 * M1);               // temporal reuse of agg
    float* z32  = f + 5 * M1;                        // [5M, 7M)
    bf16*  zb   = (bf16*)(f + 7 * M1);               // [7M, 8M)
    float* qkv  = f + 8 * M1;                        // [8M, 14M)
    bf16*  f1b  = (bf16*)(f + 8 * M1);               // reuse of qkv region
    float* gout = f + 14 * M1;                       // [14M, 16M)
    float* spb  = f + 16 * M1;                       // 1152 fl
    bf16*  BpBase = (bf16*)(f + 16 * M1 + 4096);
    bf16* BpSPQKV = BpBase;                          // 3*4*24*512 = 147456
    bf16* BpWS    = BpSPQKV + 147456;                // 3*4*8*512  =  49152
    bf16* BpTQKV  = BpWS + 49152;                    // 147456
    bf16* BpWO    = BpTQKV + 147456;                 //  49152
    bf16* BpW1    = BpWO + 49152;                    // 3*4*32*512 = 196608
    bf16* BpW2    = BpW1 + 196608;                   // 3*16*8*512 = 196608

    // --- weight repack (one launch) ---
    RepackArgs ra;
    int s = 0;
    auto mk = [&](int i, const float* W, bf16* out, int K, int N, int ntt, int ntoff, int L) {
        ra.d[i] = {W, out, K, N, ntt, ntoff, L, s};
        s += L * (K >> 5) * (N >> 4) * 64;
    };
    mk(0, sp_Wq, BpSPQKV, 128, 128, 24, 0, 3);
    mk(1, sp_Wk, BpSPQKV, 128, 128, 24, 8, 3);
    mk(2, sp_Wv, BpSPQKV, 128, 128, 24, 16, 3);
    mk(3, sp_Ws, BpWS, 128, 128, 8, 0, 3);
    mk(4, t_Wqkv, BpTQKV, 128, 384, 24, 0, 3);
    mk(5, t_Wo, BpWO, 128, 128, 8, 0, 3);
    mk(6, t_W1, BpW1, 128, 512, 32, 0, 3);
    mk(7, t_W2, BpW2, 512, 128, 8, 0, 3);
    ra.total = s;
    k_repack<<<(s + 255) / 256, 256, 0, stream>>>(ra);
    k_packbias<<<(3 * 384 + 255) / 256, 256, 0, stream>>>(sp_bq, sp_bk, sp_bv, spb);

    k_proj<<<NT_ * D_ / 256, 256, 0, stream>>>(input_frames, proj_W, proj_b, h32, hb);

    for (int l = 0; l < 3; l++) {
        k_mfma_gemm<24, 0, 0><<<dim3(256, 1), 256, 0, stream>>>(
            hb, 128, (const short8*)BpSPQKV + (size_t)l * 6144, 24,
            spb + l * 384, qkv, 384);
        k_edge_attn<<<dim3(BT_, 2), 128, 0, stream>>>(
            qkv, edge_attr, sp_We + l * D_, sp_be + l * D_, agg);
        k_mfma_gemm<8, 0, 0><<<dim3(256, 1), 256, 0, stream>>>(
            hb, 128, (const short8*)BpWS + (size_t)l * 2048, 8,
            sp_bs + l * D_, gout, 128);
        k_ln<<<NT_ / 4, 256, 0, stream>>>(gout, h32, agg,
                                          sp_lng + l * D_, sp_lnb + l * D_, h32, hb);
    }

    k_trans<<<ROWS_ * D_ / 256, 256, 0, stream>>>(h32, tpos, z32, zb);

    for (int l = 0; l < 3; l++) {
        k_mfma_gemm<24, 0, 0><<<dim3(256, 1), 256, 0, stream>>>(
            zb, 128, (const short8*)BpTQKV + (size_t)l * 6144, 24,
            t_bqkv + l * 384, qkv, 384);
        k_tattn<<<BN_, 128, 0, stream>>>(qkv, o_b);
        k_mfma_gemm<8, 0, 0><<<dim3(256, 1), 256, 0, stream>>>(
            o_b, 128, (const short8*)BpWO + (size_t)l * 2048, 8,
            t_bo + l * D_, gout, 128);
        k_ln<<<ROWS_ / 4, 256, 0, stream>>>(gout, z32, nullptr,
                                            t_ln1g + l * D_, t_ln1b + l * D_, z32, zb);
        k_mfma_gemm<16, 1, 1><<<dim3(256, 2), 256, 0, stream>>>(
            zb, 128, (const short8*)BpW1 + (size_t)l * 8192, 32,
            t_b1 + l * 512, f1b, 512);
        k_mfma_gemm<8, 0, 0><<<dim3(256, 1), 256, 0, stream>>>(
            f1b, 512, (const short8*)BpW2 + (size_t)l * 8192, 8,
            t_b2 + l * D_, gout, 128);
        k_ln<<<ROWS_ / 4, 256, 0, stream>>>(gout, z32, nullptr,
                                            t_ln2g + l * D_, t_ln2b + l * D_, z32, zb);
    }

    k_head<<<BN_, 128, 0, stream>>>(z32, head_W1, head_b1, head_W2, head_b2,
                                    (float*)d_out);
}

// Round 4
// 521.199 us; speedup vs baseline: 3.9485x; 1.1095x over previous
//
#include <hip/hip_runtime.h>
#include <hip/hip_bf16.h>
#include <math.h>

typedef __hip_bfloat16 bf16;
typedef short short8 __attribute__((ext_vector_type(8)));
typedef float floatx4 __attribute__((ext_vector_type(4)));

#define B_    8
#define T_    32
#define N_    64
#define F_    6
#define D_    128
#define E_    4032      // N*(N-1)
#define BT_   256       // B*T
#define NT_   16384     // BT*N  (spatial rows)
#define BN_   512       // B*N   (temporal batches)
#define ROWS_ 16384     // BN*T  (temporal rows)
#define QS_   392       // LDS qkv row stride (shorts): 392*2=784 B, 16B-aligned

__device__ __forceinline__ float gelu_exact(float x) {
    return 0.5f * x * (1.0f + erff(x * 0.70710678118654752f));
}
__device__ __forceinline__ float bfbits2f(short s) {
    unsigned int u = ((unsigned int)(unsigned short)s) << 16;
    return __uint_as_float(u);
}
// load 32 consecutive bf16 from LDS (16B-aligned) as fp32
__device__ __forceinline__ void ld32lds(const bf16* p, float* o) {
    const short8* sp = (const short8*)p;
#pragma unroll
    for (int i = 0; i < 4; i++) {
        short8 s = sp[i];
#pragma unroll
        for (int j = 0; j < 8; j++) o[i * 8 + j] = bfbits2f(s[j]);
    }
}

// ---------------------------------------------------------------------------
// Repack weights (fp32, row-major KxN, L layers) into MFMA B-fragment layout:
// Bp[((l*ktiles + kt)*ntt + nt + ntoff)*64 + lane][j] =
//     bf16( W[l][kt*32 + (lane>>4)*8 + j][nt*16 + (lane&15)] )
struct RepackDesc { const float* W; bf16* out; int K, N, ntt, ntoff, L, start; };
struct RepackArgs { RepackDesc d[8]; int total; };

__global__ void k_repack(RepackArgs ra) {
    int gid = blockIdx.x * blockDim.x + threadIdx.x;
    if (gid >= ra.total) return;
    int fi = 0;
    while (fi < 7 && gid >= ra.d[fi + 1].start) fi++;
    RepackDesc dd = ra.d[fi];
    int r = gid - dd.start;
    int lane = r & 63; r >>= 6;
    int ntiles = dd.N >> 4;
    int nt = r % ntiles; r /= ntiles;
    int ktiles = dd.K >> 5;
    int kt = r % ktiles;
    int l = r / ktiles;
    int quad = lane >> 4, cc = lane & 15;
    const float* Wl = dd.W + (size_t)l * dd.K * dd.N;
    bf16* o = dd.out + ((((size_t)l * ktiles + kt) * dd.ntt + nt + dd.ntoff) * 64 + lane) * 8;
    int kb = kt * 32 + quad * 8;
    int n = nt * 16 + cc;
#pragma unroll
    for (int j = 0; j < 8; j++)
        o[j] = __float2bfloat16(Wl[(size_t)(kb + j) * dd.N + n]);
}

// concat spatial q/k/v biases: spb[l][0:128)=bq, [128:256)=bk, [256:384)=bv
__global__ void k_packbias(const float* __restrict__ bq, const float* __restrict__ bk,
                           const float* __restrict__ bv, float* __restrict__ out) {
    int i = blockIdx.x * blockDim.x + threadIdx.x;
    if (i >= 3 * 384) return;
    int l = i / 384, c = i % 384;
    float v = (c < 128) ? bq[l * 128 + c]
            : (c < 256) ? bk[l * 128 + c - 128]
                        : bv[l * 128 + c - 256];
    out[i] = v;
}

// ---------------------------------------------------------------------------
// Plain MFMA GEMM (used for W1 only). Block=256=4 waves; wave w -> rows
// blk*64+w*16; NT 16-col tiles per wave, ntbase = blockIdx.y*NT.
template<int NT, int ACT, int OBF>
__global__ __launch_bounds__(256)
void k_mfma_gemm(const bf16* __restrict__ A, int K, const short8* __restrict__ Bp,
                 int ntt, const float* __restrict__ bias, void* __restrict__ Cv,
                 int ldc) {
    int lane = threadIdx.x & 63;
    int wave = threadIdx.x >> 6;
    int quad = lane >> 4, col = lane & 15;
    int ntbase = blockIdx.y * NT;
    size_t arow = (size_t)(blockIdx.x * 64 + wave * 16 + col) * K;
    const short8* Ap = (const short8*)(A + arow) + quad;
    floatx4 acc[NT];
#pragma unroll
    for (int t = 0; t < NT; t++) acc[t] = (floatx4){0.f, 0.f, 0.f, 0.f};
    int kch = K >> 5;
    for (int kt = 0; kt < kch; kt++) {
        short8 a = Ap[kt * 4];
        const short8* bp = Bp + ((size_t)kt * ntt + ntbase) * 64 + lane;
#pragma unroll
        for (int t = 0; t < NT; t++)
            acc[t] = __builtin_amdgcn_mfma_f32_16x16x32_bf16(a, bp[t * 64], acc[t], 0, 0, 0);
    }
    int orow0 = blockIdx.x * 64 + wave * 16 + quad * 4;
#pragma unroll
    for (int t = 0; t < NT; t++) {
        int oc = (ntbase + t) * 16 + col;
        float bv = bias[oc];
#pragma unroll
        for (int r = 0; r < 4; r++) {
            float v = acc[t][r] + bv;
            if (ACT) v = gelu_exact(v);
            size_t idx = (size_t)(orow0 + r) * ldc + oc;
            if (OBF) ((bf16*)Cv)[idx] = __float2bfloat16(v);
            else     ((float*)Cv)[idx] = v;
        }
    }
}

// ---------------------------------------------------------------------------
// Fused MFMA GEMM (N=128) + bias + residual(s) + LayerNorm.
// Wave covers 16 rows x all 128 cols (8 tiles) -> LN reduce via quad shuffles.
// io32 is BOTH the main residual input and the fp32 output (elementwise safe).
__global__ __launch_bounds__(256)
void k_mfma_ln(const bf16* __restrict__ A, int K, const short8* __restrict__ Bp,
               const float* __restrict__ bias, const float* __restrict__ res2,
               const float* __restrict__ g, const float* __restrict__ bb,
               float* io32, bf16* __restrict__ outb) {
    int lane = threadIdx.x & 63;
    int wave = threadIdx.x >> 6;
    int quad = lane >> 4, col = lane & 15;
    const short8* Ap = (const short8*)(A + (size_t)(blockIdx.x * 64 + wave * 16 + col) * K) + quad;
    floatx4 acc[8];
#pragma unroll
    for (int t = 0; t < 8; t++) acc[t] = (floatx4){0.f, 0.f, 0.f, 0.f};
    int kch = K >> 5;
    for (int kt = 0; kt < kch; kt++) {
        short8 a = Ap[kt * 4];
        const short8* bp = Bp + (size_t)(kt * 8) * 64 + lane;
#pragma unroll
        for (int t = 0; t < 8; t++)
            acc[t] = __builtin_amdgcn_mfma_f32_16x16x32_bf16(a, bp[t * 64], acc[t], 0, 0, 0);
    }
    int orow0 = blockIdx.x * 64 + wave * 16 + quad * 4;
    float rs[4] = {0.f, 0.f, 0.f, 0.f};
#pragma unroll
    for (int t = 0; t < 8; t++) {
        int c = t * 16 + col;
        float bv = bias[c];
#pragma unroll
        for (int r = 0; r < 4; r++) {
            size_t idx = (size_t)(orow0 + r) * 128 + c;
            float v = acc[t][r] + bv + io32[idx];
            if (res2) v += res2[idx];
            acc[t][r] = v;
            rs[r] += v;
        }
    }
#pragma unroll
    for (int m = 1; m <= 8; m <<= 1) {
#pragma unroll
        for (int r = 0; r < 4; r++) rs[r] += __shfl_xor(rs[r], m, 64);
    }
    float mean[4], vs[4] = {0.f, 0.f, 0.f, 0.f};
#pragma unroll
    for (int r = 0; r < 4; r++) mean[r] = rs[r] * (1.0f / 128.0f);
#pragma unroll
    for (int t = 0; t < 8; t++)
#pragma unroll
        for (int r = 0; r < 4; r++) {
            float d = acc[t][r] - mean[r];
            acc[t][r] = d;
            vs[r] += d * d;
        }
#pragma unroll
    for (int m = 1; m <= 8; m <<= 1) {
#pragma unroll
        for (int r = 0; r < 4; r++) vs[r] += __shfl_xor(vs[r], m, 64);
    }
    float inv[4];
#pragma unroll
    for (int r = 0; r < 4; r++) inv[r] = rsqrtf(vs[r] * (1.0f / 128.0f) + 1e-5f);
#pragma unroll
    for (int t = 0; t < 8; t++) {
        int c = t * 16 + col;
        float gc = g[c], bc = bb[c];
#pragma unroll
        for (int r = 0; r < 4; r++) {
            float y = acc[t][r] * inv[r] * gc + bc;
            size_t idx = (size_t)(orow0 + r) * 128 + c;
            io32[idx] = y;
            outb[idx] = __float2bfloat16(y);
        }
    }
}

// ---------------------------------------------------------------------------
// h = input @ proj_W + proj_b ; writes fp32 master + bf16 copy
__global__ void k_proj(const float* __restrict__ inp, const float* __restrict__ W,
                       const float* __restrict__ b, float* __restrict__ h,
                       bf16* __restrict__ hb) {
    int i = blockIdx.x * blockDim.x + threadIdx.x;
    int d = i & (D_ - 1);
    int node = i >> 7;
    float acc = b[d];
#pragma unroll
    for (int k = 0; k < F_; k++)
        acc = fmaf(inp[node * F_ + k], W[k * D_ + d], acc);
    h[i] = acc;
    hb[i] = __float2bfloat16(acc);
}

// ---------------------------------------------------------------------------
// FUSED spatial layer front: qkv = hb@Wqkv + b (MFMA -> LDS bf16), then
// rank-1 edge attention. One block per (b,t) graph; 256 thr = 4 waves.
__global__ __launch_bounds__(256)
void k_spatial(const bf16* __restrict__ A, const short8* __restrict__ Bp,
               const float* __restrict__ bias, const float* __restrict__ ea,
               const float* __restrict__ We, const float* __restrict__ be,
               float* __restrict__ agg) {
    __shared__ __align__(16) bf16 qs[64 * QS_];
    __shared__ float EAs[E_];
    __shared__ float WeS[128], beS[128];
    int bt = blockIdx.x;
    int tid = threadIdx.x;
    int lane = tid & 63, wave = tid >> 6;
    int quad = lane >> 4, col = lane & 15;
    // ---- phase 1: qkv GEMM (M=64, N=384, K=128) ----
    {
        const short8* Ap = (const short8*)(A + (size_t)(bt * 64 + wave * 16 + col) * 128) + quad;
        floatx4 acc[24];
#pragma unroll
        for (int t = 0; t < 24; t++) acc[t] = (floatx4){0.f, 0.f, 0.f, 0.f};
        for (int kt = 0; kt < 4; kt++) {
            short8 a = Ap[kt * 4];
            const short8* bp = Bp + (size_t)(kt * 24) * 64 + lane;
#pragma unroll
            for (int t = 0; t < 24; t++)
                acc[t] = __builtin_amdgcn_mfma_f32_16x16x32_bf16(a, bp[t * 64], acc[t], 0, 0, 0);
        }
#pragma unroll
        for (int t = 0; t < 24; t++) {
            int cg = t * 16 + col;
            float bv = bias[cg];
#pragma unroll
            for (int r = 0; r < 4; r++)
                qs[(wave * 16 + quad * 4 + r) * QS_ + cg] = __float2bfloat16(acc[t][r] + bv);
        }
    }
    const float* eab = ea + (size_t)bt * E_;
    for (int i = tid; i < E_; i += 256) EAs[i] = eab[i];
    if (tid < 128) { WeS[tid] = We[tid]; beS[tid] = be[tid]; }
    __syncthreads();
    // ---- phase 2: edge attention; thr = (hp, hh, dst) ----
    int dst = tid & 63, hh = (tid >> 6) & 1, hp = tid >> 7;
    int off = hp * 64 + hh * 32;          // column base within head-dim 128
    float qr[32];
    ld32lds(&qs[dst * QS_ + off], qr);
    float qWe = 0.f, qbe = 0.f;
#pragma unroll
    for (int c = 0; c < 32; c++) {
        qWe = fmaf(qr[c], WeS[off + c], qWe);
        qbe = fmaf(qr[c], beS[off + c], qbe);
    }
    const float scale = 0.17677669529663687f;   // 1/sqrt(32)
    float mmax = -1e30f, l = 0.f, accEA = 0.f;
    float acc[32];
#pragma unroll
    for (int c = 0; c < 32; c++) acc[c] = 0.f;
    for (int s = 0; s < 64; s++) {
        if (s == dst) continue;
        float kr[32], vr[32];
        ld32lds(&qs[s * QS_ + 128 + off], kr);
        ld32lds(&qs[s * QS_ + 256 + off], vr);
        float d0 = 0.f, d1 = 0.f, d2 = 0.f, d3 = 0.f;
#pragma unroll
        for (int c = 0; c < 32; c += 4) {
            d0 = fmaf(qr[c], kr[c], d0);
            d1 = fmaf(qr[c + 1], kr[c + 1], d1);
            d2 = fmaf(qr[c + 2], kr[c + 2], d2);
            d3 = fmaf(qr[c + 3], kr[c + 3], d3);
        }
        float dot = (d0 + d1) + (d2 + d3);
        int eid = s * 63 + dst - (dst > s ? 1 : 0);
        float eav = EAs[eid];
        float alpha = scale * (dot + eav * qWe + qbe);
        float mnew = fmaxf(mmax, alpha);
        float corr = __expf(mmax - mnew);
        float w = __expf(alpha - mnew);
        l = l * corr + w;
        accEA = accEA * corr + w * eav;
#pragma unroll
        for (int c = 0; c < 32; c++) acc[c] = fmaf(acc[c], corr, w * vr[c]);
        mmax = mnew;
    }
    float inv = 1.0f / l;
    float* ag = agg + (size_t)(bt * 64 + dst) * 128 + off;
#pragma unroll
    for (int c = 0; c < 32; c++)
        ag[c] = fmaf(accEA * WeS[off + c] + acc[c], inv, beS[off + c]);
}

// ---------------------------------------------------------------------------
// h (B,T,N,D) -> z (B*N, T, D) + temporal pos; fp32 + bf16
__global__ void k_trans(const float* __restrict__ h, const float* __restrict__ pos,
                        float* __restrict__ z, bf16* __restrict__ zb) {
    int i = blockIdx.x * blockDim.x + threadIdx.x;
    int d = i & 127;
    int r = i >> 7;          // r = bn*T + t
    int t = r & 31;
    int bn = r >> 5;
    int b = bn >> 6;
    int n = bn & 63;
    int node = (b * T_ + t) * N_ + n;
    float v = h[(size_t)node * D_ + d] + pos[t * D_ + d];
    z[i] = v;
    zb[i] = __float2bfloat16(v);
}

// ---------------------------------------------------------------------------
// FUSED temporal layer front: qkv = zb@Wqkv + b (MFMA -> LDS bf16), then
// causal attention. One block per (b,n) sequence; 128 thr = 2 waves.
__global__ __launch_bounds__(128)
void k_temporal(const bf16* __restrict__ A, const short8* __restrict__ Bp,
                const float* __restrict__ bias, bf16* __restrict__ o) {
    __shared__ __align__(16) bf16 qs[32 * QS_];
    int bn = blockIdx.x;
    int tid = threadIdx.x;
    int lane = tid & 63, wave = tid >> 6;
    int quad = lane >> 4, col = lane & 15;
    // ---- phase 1: qkv GEMM (M=32, N=384, K=128) ----
    {
        const short8* Ap = (const short8*)(A + (size_t)(bn * 32 + wave * 16 + col) * 128) + quad;
        floatx4 acc[24];
#pragma unroll
        for (int t = 0; t < 24; t++) acc[t] = (floatx4){0.f, 0.f, 0.f, 0.f};
        for (int kt = 0; kt < 4; kt++) {
            short8 a = Ap[kt * 4];
            const short8* bp = Bp + (size_t)(kt * 24) * 64 + lane;
#pragma unroll
            for (int t = 0; t < 24; t++)
                acc[t] = __builtin_amdgcn_mfma_f32_16x16x32_bf16(a, bp[t * 64], acc[t], 0, 0, 0);
        }
#pragma unroll
        for (int t = 0; t < 24; t++) {
            int cg = t * 16 + col;
            float bv = bias[cg];
#pragma unroll
            for (int r = 0; r < 4; r++)
                qs[(wave * 16 + quad * 4 + r) * QS_ + cg] = __float2bfloat16(acc[t][r] + bv);
        }
    }
    __syncthreads();
    // ---- phase 2: causal attention; thr = (head, t) ----
    int t = tid & 31, h = tid >> 5;
    int cb = h * 32;
    float qr[32];
    ld32lds(&qs[t * QS_ + cb], qr);
    const float scale = 0.17677669529663687f;
    float mmax = -1e30f, l = 0.f, acc[32];
#pragma unroll
    for (int c = 0; c < 32; c++) acc[c] = 0.f;
    for (int j = 0; j <= t; j++) {
        float kr[32], vr[32];
        ld32lds(&qs[j * QS_ + 128 + cb], kr);
        ld32lds(&qs[j * QS_ + 256 + cb], vr);
        float d0 = 0.f, d1 = 0.f, d2 = 0.f, d3 = 0.f;
#pragma unroll
        for (int c = 0; c < 32; c += 4) {
            d0 = fmaf(qr[c], kr[c], d0);
            d1 = fmaf(qr[c + 1], kr[c + 1], d1);
            d2 = fmaf(qr[c + 2], kr[c + 2], d2);
            d3 = fmaf(qr[c + 3], kr[c + 3], d3);
        }
        float alpha = ((d0 + d1) + (d2 + d3)) * scale;
        float mnew = fmaxf(mmax, alpha);
        float corr = __expf(mmax - mnew);
        float w = __expf(alpha - mnew);
        l = l * corr + w;
#pragma unroll
        for (int c = 0; c < 32; c++) acc[c] = fmaf(acc[c], corr, w * vr[c]);
        mmax = mnew;
    }
    float inv = 1.0f / l;
    bf16* orow = o + (size_t)(bn * 32 + t) * 128 + cb;
#pragma unroll
    for (int c = 0; c < 32; c++) orow[c] = __float2bfloat16(acc[c] * inv);
}

// ---------------------------------------------------------------------------
// Head: out[bn,:6] = gelu(z_last @ W1 + b1) @ W2 + b2  (fp32 out)
__global__ __launch_bounds__(128)
void k_head(const float* __restrict__ z, const float* __restrict__ W1,
            const float* __restrict__ b1, const float* __restrict__ W2,
            const float* __restrict__ b2, float* __restrict__ out) {
    int bn = blockIdx.x;
    int d = threadIdx.x;
    __shared__ float zl[128], h1[128];
    zl[d] = z[(size_t)(bn * 32 + 31) * 128 + d];
    __syncthreads();
    float acc = b1[d];
    for (int k = 0; k < 128; k++) acc = fmaf(zl[k], W1[k * 128 + d], acc);
    h1[d] = gelu_exact(acc);
    __syncthreads();
    if (d < F_) {
        float o = b2[d];
        for (int k = 0; k < 128; k++) o = fmaf(h1[k], W2[k * F_ + d], o);
        out[bn * F_ + d] = o;
    }
}

// ---------------------------------------------------------------------------
extern "C" void kernel_launch(void* const* d_in, const int* in_sizes, int n_in,
                              void* d_out, int out_size, void* d_ws, size_t ws_size,
                              hipStream_t stream) {
    const float* input_frames = (const float*)d_in[0];
    const float* edge_attr    = (const float*)d_in[1];
    const float* proj_W  = (const float*)d_in[2];
    const float* proj_b  = (const float*)d_in[3];
    const float* sp_Wq   = (const float*)d_in[4];
    const float* sp_bq   = (const float*)d_in[5];
    const float* sp_Wk   = (const float*)d_in[6];
    const float* sp_bk   = (const float*)d_in[7];
    const float* sp_Wv   = (const float*)d_in[8];
    const float* sp_bv   = (const float*)d_in[9];
    const float* sp_We   = (const float*)d_in[10];
    const float* sp_be   = (const float*)d_in[11];
    const float* sp_Ws   = (const float*)d_in[12];
    const float* sp_bs   = (const float*)d_in[13];
    const float* sp_lng  = (const float*)d_in[14];
    const float* sp_lnb  = (const float*)d_in[15];
    const float* tpos    = (const float*)d_in[16];
    const float* t_Wqkv  = (const float*)d_in[17];
    const float* t_bqkv  = (const float*)d_in[18];
    const float* t_Wo    = (const float*)d_in[19];
    const float* t_bo    = (const float*)d_in[20];
    const float* t_ln1g  = (const float*)d_in[21];
    const float* t_ln1b  = (const float*)d_in[22];
    const float* t_W1    = (const float*)d_in[23];
    const float* t_b1    = (const float*)d_in[24];
    const float* t_W2    = (const float*)d_in[25];
    const float* t_b2    = (const float*)d_in[26];
    const float* t_ln2g  = (const float*)d_in[27];
    const float* t_ln2b  = (const float*)d_in[28];
    const float* head_W1 = (const float*)d_in[29];
    const float* head_b1 = (const float*)d_in[30];
    const float* head_W2 = (const float*)d_in[31];
    const float* head_b2 = (const float*)d_in[32];

    const size_t M1 = 1u << 20;                      // 1M floats
    float* f    = (float*)d_ws;
    float* h32  = f;                                 // [0, 2M)
    bf16*  hb   = (bf16*)(f + 2 * M1);               // [2M, 3M)
    float* agg  = f + 3 * M1;                        // [3M, 5M)  (spatial)
    bf16*  o_b  = (bf16*)(f + 3 * M1);               // temporal reuse of agg
    float* z32  = f + 5 * M1;                        // [5M, 7M)
    bf16*  zb   = (bf16*)(f + 7 * M1);               // [7M, 8M)
    bf16*  f1b  = (bf16*)(f + 8 * M1);               // [8M, 12M) 16384x512 bf16
    float* spb  = f + 14 * M1;                       // 1152 fl
    bf16*  BpBase = (bf16*)(f + 14 * M1 + 4096);
    bf16* BpSPQKV = BpBase;                          // 3*4*24*512 = 147456
    bf16* BpWS    = BpSPQKV + 147456;                // 3*4*8*512  =  49152
    bf16* BpTQKV  = BpWS + 49152;                    // 147456
    bf16* BpWO    = BpTQKV + 147456;                 //  49152
    bf16* BpW1    = BpWO + 49152;                    // 3*4*32*512 = 196608
    bf16* BpW2    = BpW1 + 196608;                   // 3*16*8*512 = 196608

    // --- weight repack (one launch) ---
    RepackArgs ra;
    int s = 0;
    auto mk = [&](int i, const float* W, bf16* out, int K, int N, int ntt, int ntoff, int L) {
        ra.d[i] = {W, out, K, N, ntt, ntoff, L, s};
        s += L * (K >> 5) * (N >> 4) * 64;
    };
    mk(0, sp_Wq, BpSPQKV, 128, 128, 24, 0, 3);
    mk(1, sp_Wk, BpSPQKV, 128, 128, 24, 8, 3);
    mk(2, sp_Wv, BpSPQKV, 128, 128, 24, 16, 3);
    mk(3, sp_Ws, BpWS, 128, 128, 8, 0, 3);
    mk(4, t_Wqkv, BpTQKV, 128, 384, 24, 0, 3);
    mk(5, t_Wo, BpWO, 128, 128, 8, 0, 3);
    mk(6, t_W1, BpW1, 128, 512, 32, 0, 3);
    mk(7, t_W2, BpW2, 512, 128, 8, 0, 3);
    ra.total = s;
    k_repack<<<(s + 255) / 256, 256, 0, stream>>>(ra);
    k_packbias<<<(3 * 384 + 255) / 256, 256, 0, stream>>>(sp_bq, sp_bk, sp_bv, spb);

    k_proj<<<NT_ * D_ / 256, 256, 0, stream>>>(input_frames, proj_W, proj_b, h32, hb);

    for (int l = 0; l < 3; l++) {
        k_spatial<<<BT_, 256, 0, stream>>>(
            hb, (const short8*)BpSPQKV + (size_t)l * 6144, spb + l * 384,
            edge_attr, sp_We + l * D_, sp_be + l * D_, agg);
        k_mfma_ln<<<256, 256, 0, stream>>>(
            hb, 128, (const short8*)BpWS + (size_t)l * 2048, sp_bs + l * D_,
            agg, sp_lng + l * D_, sp_lnb + l * D_, h32, hb);
    }

    k_trans<<<ROWS_ * D_ / 256, 256, 0, stream>>>(h32, tpos, z32, zb);

    for (int l = 0; l < 3; l++) {
        k_temporal<<<BN_, 128, 0, stream>>>(
            zb, (const short8*)BpTQKV + (size_t)l * 6144, t_bqkv + l * 384, o_b);
        k_mfma_ln<<<256, 256, 0, stream>>>(
            o_b, 128, (const short8*)BpWO + (size_t)l * 2048, t_bo + l * D_,
            nullptr, t_ln1g + l * D_, t_ln1b + l * D_, z32, zb);
        k_mfma_gemm<16, 1, 1><<<dim3(256, 2), 256, 0, stream>>>(
            zb, 128, (const short8*)BpW1 + (size_t)l * 8192, 32,
            t_b1 + l * 512, f1b, 512);
        k_mfma_ln<<<256, 256, 0, stream>>>(
            f1b, 512, (const short8*)BpW2 + (size_t)l * 8192, t_b2 + l * D_,
            nullptr, t_ln2g + l * D_, t_ln2b + l * D_, z32, zb);
    }

    k_head<<<BN_, 128, 0, stream>>>(z32, head_W1, head_b1, head_W2, head_b2,
                                    (float*)d_out);
}

// Round 5
// 463.374 us; speedup vs baseline: 4.4412x; 1.1248x over previous
//
#include <hip/hip_runtime.h>
#include <hip/hip_bf16.h>
#include <math.h>

typedef __hip_bfloat16 bf16;
typedef short short8 __attribute__((ext_vector_type(8)));
typedef float floatx4 __attribute__((ext_vector_type(4)));

#define B_    8
#define T_    32
#define N_    64
#define F_    6
#define D_    128
#define E_    4032      // N*(N-1)
#define BT_   256       // B*T
#define BN_   512       // B*N

__device__ __forceinline__ float gelu_exact(float x) {
    return 0.5f * x * (1.0f + erff(x * 0.70710678118654752f));
}
__device__ __forceinline__ float bfbits2f(short s) {
    unsigned int u = ((unsigned int)(unsigned short)s) << 16;
    return __uint_as_float(u);
}
// load 32 consecutive bf16 from LDS (16B-aligned) as fp32
__device__ __forceinline__ void ld32lds(const bf16* p, float* o) {
    const short8* sp = (const short8*)p;
#pragma unroll
    for (int i = 0; i < 4; i++) {
        short8 s = sp[i];
#pragma unroll
        for (int j = 0; j < 8; j++) o[i * 8 + j] = bfbits2f(s[j]);
    }
}

// ---------------------------------------------------------------------------
// Repack weights (fp32, row-major KxN, L layers) into MFMA B-fragment layout:
// Bp[((l*ktiles + kt)*ntt + nt + ntoff)*64 + lane][j] =
//     bf16( W[l][kt*32 + (lane>>4)*8 + j][nt*16 + (lane&15)] )
struct RepackDesc { const float* W; bf16* out; int K, N, ntt, ntoff, L, start; };
struct RepackArgs { RepackDesc d[8]; int total; };

__global__ void k_repack(RepackArgs ra) {
    int gid = blockIdx.x * blockDim.x + threadIdx.x;
    if (gid >= ra.total) return;
    int fi = 0;
    while (fi < 7 && gid >= ra.d[fi + 1].start) fi++;
    RepackDesc dd = ra.d[fi];
    int r = gid - dd.start;
    int lane = r & 63; r >>= 6;
    int ntiles = dd.N >> 4;
    int nt = r % ntiles; r /= ntiles;
    int ktiles = dd.K >> 5;
    int kt = r % ktiles;
    int l = r / ktiles;
    int quad = lane >> 4, cc = lane & 15;
    const float* Wl = dd.W + (size_t)l * dd.K * dd.N;
    bf16* o = dd.out + ((((size_t)l * ktiles + kt) * dd.ntt + nt + dd.ntoff) * 64 + lane) * 8;
    int kb = kt * 32 + quad * 8;
    int n = nt * 16 + cc;
#pragma unroll
    for (int j = 0; j < 8; j++)
        o[j] = __float2bfloat16(Wl[(size_t)(kb + j) * dd.N + n]);
}

// concat spatial q/k/v biases: spb[l][0:128)=bq, [128:256)=bk, [256:384)=bv
__global__ void k_packbias(const float* __restrict__ bq, const float* __restrict__ bk,
                           const float* __restrict__ bv, float* __restrict__ out) {
    int i = blockIdx.x * blockDim.x + threadIdx.x;
    if (i >= 3 * 384) return;
    int l = i / 384, c = i % 384;
    float v = (c < 128) ? bq[l * 128 + c]
            : (c < 256) ? bk[l * 128 + c - 128]
                        : bv[l * 128 + c - 256];
    out[i] = v;
}

// ---------------------------------------------------------------------------
// FUSED 3-layer spatial stack. One block per (b,t) graph, 256 thr = 4 waves.
// Per layer: qkv MFMA GEMM -> LDS; rank-1 edge attention -> LDS agg;
// Ws MFMA GEMM + residual + LN (h fp32 master in registers, bf16 in LDS).
// Epilogue of layer 2 writes z = h + pos, transposed to (B*N, T, D).
__global__ __launch_bounds__(256)
void k_spatial3(const float* __restrict__ inp, const float* __restrict__ projW,
                const float* __restrict__ projB,
                const short8* __restrict__ BpQKV, const short8* __restrict__ BpWS,
                const float* __restrict__ spb, const float* __restrict__ bs,
                const float* __restrict__ lng, const float* __restrict__ lnb,
                const float* __restrict__ ea, const float* __restrict__ Weg,
                const float* __restrict__ beg, const float* __restrict__ tpos,
                float* __restrict__ z32g) {
    __shared__ short smem[32768];            // 64 KB exactly
    bf16* qs = (bf16*)smem;                  // 64 x 384 qkv (stride 384)
    bf16* hb = (bf16*)(smem + 24576);        // 64 x 128 h bf16 (stride 128)
    float* fsm = (float*)smem;               // overlays qs: stage-W / agg(129)

    int bt = blockIdx.x;
    int tid = threadIdx.x;
    int lane = tid & 63, wave = tid >> 6;
    int quad = lane >> 4, col = lane & 15;

    // ---- stage: proj (h = input @ W + b), h master in regs (C-layout) ----
    for (int i = tid; i < 896; i += 256)
        fsm[i] = (i < 768) ? projW[i] : projB[i - 768];
    __syncthreads();
    float hreg[32];
#pragma unroll
    for (int r = 0; r < 4; r++) {
        int n = wave * 16 + quad * 4 + r;
        const float* xr = inp + (size_t)(bt * 64 + n) * F_;
        float xin[6];
#pragma unroll
        for (int k2 = 0; k2 < 6; k2++) xin[k2] = xr[k2];
#pragma unroll
        for (int tt = 0; tt < 8; tt++) {
            int c = tt * 16 + col;
            float a = fsm[768 + c];
#pragma unroll
            for (int k2 = 0; k2 < 6; k2++) a = fmaf(xin[k2], fsm[k2 * 128 + c], a);
            hreg[tt * 4 + r] = a;
            hb[n * 128 + c] = __float2bfloat16(a);
        }
    }
    __syncthreads();

    const float scale = 0.17677669529663687f;   // 1/sqrt(32)
    for (int l = 0; l < 3; l++) {
        // ---- phase 1: qkv GEMM (rows wave*16..+15, all 384 cols) ----
        {
            floatx4 acc[24];
#pragma unroll
            for (int tt = 0; tt < 24; tt++) acc[tt] = (floatx4){0.f, 0.f, 0.f, 0.f};
            const short8* bpl = BpQKV + (size_t)l * 6144;
            for (int kt = 0; kt < 4; kt++) {
                short8 a = *(const short8*)&hb[(wave * 16 + col) * 128 + kt * 32 + quad * 8];
                const short8* bp = bpl + (size_t)(kt * 24) * 64 + lane;
#pragma unroll
                for (int tt = 0; tt < 24; tt++)
                    acc[tt] = __builtin_amdgcn_mfma_f32_16x16x32_bf16(a, bp[tt * 64], acc[tt], 0, 0, 0);
            }
            __syncthreads();                 // prior-layer agg fully consumed
            const float* bias = spb + l * 384;
#pragma unroll
            for (int tt = 0; tt < 24; tt++) {
                int c = tt * 16 + col;
                float bv = bias[c];
#pragma unroll
                for (int r = 0; r < 4; r++)
                    qs[(wave * 16 + quad * 4 + r) * 384 + c] = __float2bfloat16(acc[tt][r] + bv);
            }
        }
        __syncthreads();
        // ---- phase 2: edge attention (all 256 thr: dst x 4 col-groups) ----
        {
            int dst = lane;
            int off = (wave >> 1) * 64 + (wave & 1) * 32;
            float qr[32];
            ld32lds(&qs[dst * 384 + off], qr);
            const float* Wel = Weg + l * 128;
            const float* bel = beg + l * 128;
            float qWe = 0.f, qbe = 0.f;
#pragma unroll
            for (int c = 0; c < 32; c++) {
                qWe = fmaf(qr[c], Wel[off + c], qWe);
                qbe = fmaf(qr[c], bel[off + c], qbe);
            }
            const float* eag = ea + (size_t)bt * E_;
            float mmax = -1e30f, lsum = 0.f, accEA = 0.f;
            float acc[32];
#pragma unroll
            for (int c = 0; c < 32; c++) acc[c] = 0.f;
            float eav_n = eag[dst - (dst > 0 ? 1 : 0)];
            for (int s = 0; s < 64; s++) {
                float eav = eav_n;
                if (s < 63) {
                    int sn = s + 1;
                    eav_n = eag[sn * 63 + dst - (dst > sn ? 1 : 0)];   // prefetch
                }
                if (s == dst) continue;
                float kr[32], vr[32];
                ld32lds(&qs[s * 384 + 128 + off], kr);
                ld32lds(&qs[s * 384 + 256 + off], vr);
                float d0 = 0.f, d1 = 0.f, d2 = 0.f, d3 = 0.f;
#pragma unroll
                for (int c = 0; c < 32; c += 4) {
                    d0 = fmaf(qr[c], kr[c], d0);
                    d1 = fmaf(qr[c + 1], kr[c + 1], d1);
                    d2 = fmaf(qr[c + 2], kr[c + 2], d2);
                    d3 = fmaf(qr[c + 3], kr[c + 3], d3);
                }
                float alpha = scale * ((d0 + d1) + (d2 + d3) + eav * qWe + qbe);
                float mnew = fmaxf(mmax, alpha);
                float corr = __expf(mmax - mnew);
                float w = __expf(alpha - mnew);
                lsum = lsum * corr + w;
                accEA = accEA * corr + w * eav;
#pragma unroll
                for (int c = 0; c < 32; c++) acc[c] = fmaf(acc[c], corr, w * vr[c]);
                mmax = mnew;
            }
            float inv = 1.0f / lsum;
            __syncthreads();                 // all qs reads complete
#pragma unroll
            for (int c = 0; c < 32; c++)     // agg into fsm, stride 129
                fsm[dst * 129 + off + c] = fmaf(accEA * Wel[off + c] + acc[c], inv, bel[off + c]);
        }
        __syncthreads();
        // ---- epilogue: Ws GEMM + agg + residual + LN ----
        {
            floatx4 acc2[8];
#pragma unroll
            for (int tt = 0; tt < 8; tt++) acc2[tt] = (floatx4){0.f, 0.f, 0.f, 0.f};
            const short8* bpl = BpWS + (size_t)l * 2048;
            for (int kt = 0; kt < 4; kt++) {
                short8 a = *(const short8*)&hb[(wave * 16 + col) * 128 + kt * 32 + quad * 8];
                const short8* bp = bpl + (size_t)(kt * 8) * 64 + lane;
#pragma unroll
                for (int tt = 0; tt < 8; tt++)
                    acc2[tt] = __builtin_amdgcn_mfma_f32_16x16x32_bf16(a, bp[tt * 64], acc2[tt], 0, 0, 0);
            }
            const float* bsl = bs + l * 128;
            float vv[32], rs[4] = {0.f, 0.f, 0.f, 0.f};
#pragma unroll
            for (int tt = 0; tt < 8; tt++) {
                int c = tt * 16 + col;
                float bv = bsl[c];
#pragma unroll
                for (int r = 0; r < 4; r++) {
                    int row = wave * 16 + quad * 4 + r;
                    float v = acc2[tt][r] + bv + fsm[row * 129 + c] + hreg[tt * 4 + r];
                    vv[tt * 4 + r] = v;
                    rs[r] += v;
                }
            }
#pragma unroll
            for (int m = 1; m <= 8; m <<= 1)
#pragma unroll
                for (int r = 0; r < 4; r++) rs[r] += __shfl_xor(rs[r], m, 64);
            float mean[4], vs[4] = {0.f, 0.f, 0.f, 0.f};
#pragma unroll
            for (int r = 0; r < 4; r++) mean[r] = rs[r] * (1.0f / 128.0f);
#pragma unroll
            for (int i = 0; i < 32; i++) {
                float d = vv[i] - mean[i & 3];
                vv[i] = d;
                vs[i & 3] += d * d;
            }
#pragma unroll
            for (int m = 1; m <= 8; m <<= 1)
#pragma unroll
                for (int r = 0; r < 4; r++) vs[r] += __shfl_xor(vs[r], m, 64);
            float inv2[4];
#pragma unroll
            for (int r = 0; r < 4; r++) inv2[r] = rsqrtf(vs[r] * (1.0f / 128.0f) + 1e-5f);
            const float* gl = lng + l * 128;
            const float* bl = lnb + l * 128;
            if (l < 2) {
#pragma unroll
                for (int tt = 0; tt < 8; tt++) {
                    int c = tt * 16 + col;
                    float gc = gl[c], bc = bl[c];
#pragma unroll
                    for (int r = 0; r < 4; r++) {
                        float y = vv[tt * 4 + r] * inv2[r] * gc + bc;
                        int n = wave * 16 + quad * 4 + r;
                        hreg[tt * 4 + r] = y;
                        hb[n * 128 + c] = __float2bfloat16(y);
                    }
                }
            } else {                          // final layer: write z = h + pos
                int b = bt >> 5, t_ = bt & 31;
#pragma unroll
                for (int tt = 0; tt < 8; tt++) {
                    int c = tt * 16 + col;
                    float gc = gl[c], bc = bl[c], pc = tpos[t_ * 128 + c];
#pragma unroll
                    for (int r = 0; r < 4; r++) {
                        float y = vv[tt * 4 + r] * inv2[r] * gc + bc;
                        int n = wave * 16 + quad * 4 + r;
                        z32g[((size_t)(b * 64 + n) * 32 + t_) * 128 + c] = y + pc;
                    }
                }
            }
        }
        __syncthreads();
    }
}

// ---------------------------------------------------------------------------
// FUSED 3-layer temporal stack. One block per (b,n) sequence, 256 thr = 4 waves.
// Per layer: qkv GEMM -> LDS; causal attention; Wo GEMM + LN1 (waves 0/1);
// W1 GEMM + gelu (all waves) -> LDS; W2 GEMM + LN2 (waves 0/1).
// z fp32 master in waves-0/1 registers; zb bf16 in LDS. Writes only zlast.
__global__ __launch_bounds__(256)
void k_temporal3(const float* __restrict__ z32g,
                 const short8* __restrict__ BpQKV, const short8* __restrict__ BpWO,
                 const short8* __restrict__ BpW1, const short8* __restrict__ BpW2,
                 const float* __restrict__ bqkv, const float* __restrict__ bo,
                 const float* __restrict__ ln1g, const float* __restrict__ ln1b,
                 const float* __restrict__ b1, const float* __restrict__ b2,
                 const float* __restrict__ ln2g, const float* __restrict__ ln2b,
                 float* __restrict__ zlast) {
    __shared__ short uni[16640];     // 33280 B: f1(32x520) | qs(32x384) | o16 | z-stage
    __shared__ short zbm[4352];      // zb: 32 x 136 bf16
    bf16* qs = (bf16*)uni;
    bf16* f1 = (bf16*)uni;
    bf16* o16 = (bf16*)uni;
    float* zst = (float*)uni;
    bf16* zb = (bf16*)zbm;

    int bn = blockIdx.x;
    int tid = threadIdx.x;
    int lane = tid & 63, wave = tid >> 6;
    int quad = lane >> 4, col = lane & 15;
    int rsel = wave & 1, csel = wave >> 1;

    // ---- stage: z from global (already has pos) ----
    for (int i = tid; i < 4096; i += 256) {
        float v = z32g[(size_t)bn * 4096 + i];
        zst[i] = v;
        zb[(i >> 7) * 136 + (i & 127)] = __float2bfloat16(v);
    }
    __syncthreads();
    float zreg[32];
    if (wave < 2) {
#pragma unroll
        for (int tt = 0; tt < 8; tt++)
#pragma unroll
            for (int r = 0; r < 4; r++)
                zreg[tt * 4 + r] = zst[(wave * 16 + quad * 4 + r) * 128 + tt * 16 + col];
    }
    __syncthreads();

    const float scale = 0.17677669529663687f;
    for (int l = 0; l < 3; l++) {
        // ---- phase 1: qkv GEMM (rows rsel*16, cols csel*192, 12 tiles) ----
        {
            floatx4 acc[12];
#pragma unroll
            for (int tt = 0; tt < 12; tt++) acc[tt] = (floatx4){0.f, 0.f, 0.f, 0.f};
            const short8* bpl = BpQKV + (size_t)l * 6144;
            for (int kt = 0; kt < 4; kt++) {
                short8 a = *(const short8*)&zb[(rsel * 16 + col) * 136 + kt * 32 + quad * 8];
                const short8* bp = bpl + (size_t)(kt * 24 + csel * 12) * 64 + lane;
#pragma unroll
                for (int tt = 0; tt < 12; tt++)
                    acc[tt] = __builtin_amdgcn_mfma_f32_16x16x32_bf16(a, bp[tt * 64], acc[tt], 0, 0, 0);
            }
            __syncthreads();                 // stage / prior-layer f1 consumed
            const float* bias = bqkv + l * 384;
#pragma unroll
            for (int tt = 0; tt < 12; tt++) {
                int c = csel * 192 + tt * 16 + col;
                float bv = bias[c];
#pragma unroll
                for (int r = 0; r < 4; r++)
                    qs[(rsel * 16 + quad * 4 + r) * 384 + c] = __float2bfloat16(acc[tt][r] + bv);
            }
        }
        __syncthreads();
        // ---- phase 2: causal attention (tid < 128: 32 t x 4 heads) ----
        float oacc[32];
        float oinv = 0.f;
        int tq = tid & 31, cb = ((tid >> 5) & 3) * 32;
        if (tid < 128) {
            float qr[32];
            ld32lds(&qs[tq * 384 + cb], qr);
            float mmax = -1e30f, lsum = 0.f;
#pragma unroll
            for (int c = 0; c < 32; c++) oacc[c] = 0.f;
            for (int j = 0; j <= tq; j++) {
                float kr[32], vr[32];
                ld32lds(&qs[j * 384 + 128 + cb], kr);
                ld32lds(&qs[j * 384 + 256 + cb], vr);
                float d0 = 0.f, d1 = 0.f, d2 = 0.f, d3 = 0.f;
#pragma unroll
                for (int c = 0; c < 32; c += 4) {
                    d0 = fmaf(qr[c], kr[c], d0);
                    d1 = fmaf(qr[c + 1], kr[c + 1], d1);
                    d2 = fmaf(qr[c + 2], kr[c + 2], d2);
                    d3 = fmaf(qr[c + 3], kr[c + 3], d3);
                }
                float alpha = ((d0 + d1) + (d2 + d3)) * scale;
                float mnew = fmaxf(mmax, alpha);
                float corr = __expf(mmax - mnew);
                float w = __expf(alpha - mnew);
                lsum = lsum * corr + w;
#pragma unroll
                for (int c = 0; c < 32; c++) oacc[c] = fmaf(oacc[c], corr, w * vr[c]);
                mmax = mnew;
            }
            oinv = 1.0f / lsum;
        }
        __syncthreads();                     // qs reads done
        if (tid < 128) {
#pragma unroll
            for (int c = 0; c < 32; c++)
                o16[tq * 136 + cb + c] = __float2bfloat16(oacc[c] * oinv);
        }
        __syncthreads();
        // ---- Wo GEMM + residual + LN1 (waves 0/1) ----
        if (wave < 2) {
            floatx4 acc2[8];
#pragma unroll
            for (int tt = 0; tt < 8; tt++) acc2[tt] = (floatx4){0.f, 0.f, 0.f, 0.f};
            const short8* bpl = BpWO + (size_t)l * 2048;
            for (int kt = 0; kt < 4; kt++) {
                short8 a = *(const short8*)&o16[(wave * 16 + col) * 136 + kt * 32 + quad * 8];
                const short8* bp = bpl + (size_t)(kt * 8) * 64 + lane;
#pragma unroll
                for (int tt = 0; tt < 8; tt++)
                    acc2[tt] = __builtin_amdgcn_mfma_f32_16x16x32_bf16(a, bp[tt * 64], acc2[tt], 0, 0, 0);
            }
            const float* bol = bo + l * 128;
            float vv[32], rs[4] = {0.f, 0.f, 0.f, 0.f};
#pragma unroll
            for (int tt = 0; tt < 8; tt++) {
                int c = tt * 16 + col;
                float bv = bol[c];
#pragma unroll
                for (int r = 0; r < 4; r++) {
                    float v = acc2[tt][r] + bv + zreg[tt * 4 + r];
                    vv[tt * 4 + r] = v;
                    rs[r] += v;
                }
            }
#pragma unroll
            for (int m = 1; m <= 8; m <<= 1)
#pragma unroll
                for (int r = 0; r < 4; r++) rs[r] += __shfl_xor(rs[r], m, 64);
            float mean[4], vs[4] = {0.f, 0.f, 0.f, 0.f};
#pragma unroll
            for (int r = 0; r < 4; r++) mean[r] = rs[r] * (1.0f / 128.0f);
#pragma unroll
            for (int i = 0; i < 32; i++) {
                float d = vv[i] - mean[i & 3];
                vv[i] = d;
                vs[i & 3] += d * d;
            }
#pragma unroll
            for (int m = 1; m <= 8; m <<= 1)
#pragma unroll
                for (int r = 0; r < 4; r++) vs[r] += __shfl_xor(vs[r], m, 64);
            float inv2[4];
#pragma unroll
            for (int r = 0; r < 4; r++) inv2[r] = rsqrtf(vs[r] * (1.0f / 128.0f) + 1e-5f);
            const float* gl = ln1g + l * 128;
            const float* bl = ln1b + l * 128;
#pragma unroll
            for (int tt = 0; tt < 8; tt++) {
                int c = tt * 16 + col;
                float gc = gl[c], bc = bl[c];
#pragma unroll
                for (int r = 0; r < 4; r++) {
                    float y = vv[tt * 4 + r] * inv2[r] * gc + bc;
                    int row = wave * 16 + quad * 4 + r;
                    zreg[tt * 4 + r] = y;
                    zb[row * 136 + c] = __float2bfloat16(y);
                }
            }
        }
        __syncthreads();
        // ---- W1 GEMM + gelu (all waves; rows rsel*16, cols csel*256) ----
        {
            floatx4 acc3[16];
#pragma unroll
            for (int tt = 0; tt < 16; tt++) acc3[tt] = (floatx4){0.f, 0.f, 0.f, 0.f};
            const short8* bpl = BpW1 + (size_t)l * 8192;
            for (int kt = 0; kt < 4; kt++) {
                short8 a = *(const short8*)&zb[(rsel * 16 + col) * 136 + kt * 32 + quad * 8];
                const short8* bp = bpl + (size_t)(kt * 32 + csel * 16) * 64 + lane;
#pragma unroll
                for (int tt = 0; tt < 16; tt++)
                    acc3[tt] = __builtin_amdgcn_mfma_f32_16x16x32_bf16(a, bp[tt * 64], acc3[tt], 0, 0, 0);
            }
            const float* b1l = b1 + l * 512;
#pragma unroll
            for (int tt = 0; tt < 16; tt++) {
                int c = csel * 256 + tt * 16 + col;
                float bv = b1l[c];
#pragma unroll
                for (int r = 0; r < 4; r++) {
                    float v = gelu_exact(acc3[tt][r] + bv);
                    f1[(rsel * 16 + quad * 4 + r) * 520 + c] = __float2bfloat16(v);
                }
            }
        }
        __syncthreads();
        // ---- W2 GEMM + residual + LN2 (waves 0/1) ----
        if (wave < 2) {
            floatx4 acc4[8];
#pragma unroll
            for (int tt = 0; tt < 8; tt++) acc4[tt] = (floatx4){0.f, 0.f, 0.f, 0.f};
            const short8* bpl = BpW2 + (size_t)l * 8192;
            for (int kt = 0; kt < 16; kt++) {
                short8 a = *(const short8*)&f1[(wave * 16 + col) * 520 + kt * 32 + quad * 8];
                const short8* bp = bpl + (size_t)(kt * 8) * 64 + lane;
#pragma unroll
                for (int tt = 0; tt < 8; tt++)
                    acc4[tt] = __builtin_amdgcn_mfma_f32_16x16x32_bf16(a, bp[tt * 64], acc4[tt], 0, 0, 0);
            }
            const float* b2l = b2 + l * 128;
            float vv[32], rs[4] = {0.f, 0.f, 0.f, 0.f};
#pragma unroll
            for (int tt = 0; tt < 8; tt++) {
                int c = tt * 16 + col;
                float bv = b2l[c];
#pragma unroll
                for (int r = 0; r < 4; r++) {
                    float v = acc4[tt][r] + bv + zreg[tt * 4 + r];
                    vv[tt * 4 + r] = v;
                    rs[r] += v;
                }
            }
#pragma unroll
            for (int m = 1; m <= 8; m <<= 1)
#pragma unroll
                for (int r = 0; r < 4; r++) rs[r] += __shfl_xor(rs[r], m, 64);
            float mean[4], vs[4] = {0.f, 0.f, 0.f, 0.f};
#pragma unroll
            for (int r = 0; r < 4; r++) mean[r] = rs[r] * (1.0f / 128.0f);
#pragma unroll
            for (int i = 0; i < 32; i++) {
                float d = vv[i] - mean[i & 3];
                vv[i] = d;
                vs[i & 3] += d * d;
            }
#pragma unroll
            for (int m = 1; m <= 8; m <<= 1)
#pragma unroll
                for (int r = 0; r < 4; r++) vs[r] += __shfl_xor(vs[r], m, 64);
            float inv2[4];
#pragma unroll
            for (int r = 0; r < 4; r++) inv2[r] = rsqrtf(vs[r] * (1.0f / 128.0f) + 1e-5f);
            const float* gl = ln2g + l * 128;
            const float* bl = ln2b + l * 128;
#pragma unroll
            for (int tt = 0; tt < 8; tt++) {
                int c = tt * 16 + col;
                float gc = gl[c], bc = bl[c];
#pragma unroll
                for (int r = 0; r < 4; r++) {
                    float y = vv[tt * 4 + r] * inv2[r] * gc + bc;
                    int row = wave * 16 + quad * 4 + r;
                    zreg[tt * 4 + r] = y;
                    if (l < 2) zb[row * 136 + c] = __float2bfloat16(y);
                    else if (row == 31) zlast[(size_t)bn * 128 + c] = y;
                }
            }
        }
        __syncthreads();
    }
}

// ---------------------------------------------------------------------------
// Head: out[bn,:6] = gelu(zlast @ W1 + b1) @ W2 + b2  (fp32 out)
__global__ __launch_bounds__(128)
void k_head(const float* __restrict__ zlast, const float* __restrict__ W1,
            const float* __restrict__ b1, const float* __restrict__ W2,
            const float* __restrict__ b2, float* __restrict__ out) {
    int bn = blockIdx.x;
    int d = threadIdx.x;
    __shared__ float zl[128], h1[128];
    zl[d] = zlast[(size_t)bn * 128 + d];
    __syncthreads();
    float acc = b1[d];
    for (int k = 0; k < 128; k++) acc = fmaf(zl[k], W1[k * 128 + d], acc);
    h1[d] = gelu_exact(acc);
    __syncthreads();
    if (d < F_) {
        float o = b2[d];
        for (int k = 0; k < 128; k++) o = fmaf(h1[k], W2[k * F_ + d], o);
        out[bn * F_ + d] = o;
    }
}

// ---------------------------------------------------------------------------
extern "C" void kernel_launch(void* const* d_in, const int* in_sizes, int n_in,
                              void* d_out, int out_size, void* d_ws, size_t ws_size,
                              hipStream_t stream) {
    const float* input_frames = (const float*)d_in[0];
    const float* edge_attr    = (const float*)d_in[1];
    const float* proj_W  = (const float*)d_in[2];
    const float* proj_b  = (const float*)d_in[3];
    const float* sp_Wq   = (const float*)d_in[4];
    const float* sp_bq   = (const float*)d_in[5];
    const float* sp_Wk   = (const float*)d_in[6];
    const float* sp_bk   = (const float*)d_in[7];
    const float* sp_Wv   = (const float*)d_in[8];
    const float* sp_bv   = (const float*)d_in[9];
    const float* sp_We   = (const float*)d_in[10];
    const float* sp_be   = (const float*)d_in[11];
    const float* sp_Ws   = (const float*)d_in[12];
    const float* sp_bs   = (const float*)d_in[13];
    const float* sp_lng  = (const float*)d_in[14];
    const float* sp_lnb  = (const float*)d_in[15];
    const float* tpos    = (const float*)d_in[16];
    const float* t_Wqkv  = (const float*)d_in[17];
    const float* t_bqkv  = (const float*)d_in[18];
    const float* t_Wo    = (const float*)d_in[19];
    const float* t_bo    = (const float*)d_in[20];
    const float* t_ln1g  = (const float*)d_in[21];
    const float* t_ln1b  = (const float*)d_in[22];
    const float* t_W1    = (const float*)d_in[23];
    const float* t_b1    = (const float*)d_in[24];
    const float* t_W2    = (const float*)d_in[25];
    const float* t_b2    = (const float*)d_in[26];
    const float* t_ln2g  = (const float*)d_in[27];
    const float* t_ln2b  = (const float*)d_in[28];
    const float* head_W1 = (const float*)d_in[29];
    const float* head_b1 = (const float*)d_in[30];
    const float* head_W2 = (const float*)d_in[31];
    const float* head_b2 = (const float*)d_in[32];

    float* f     = (float*)d_ws;
    float* z32g  = f;                                  // 2M floats
    float* zlast = f + (1u << 21);                     // 64K floats
    float* spb   = f + (1u << 21) + 65536;             // 1152 floats
    bf16* BpBase = (bf16*)(f + (1u << 21) + 65536 + 2048);
    bf16* BpSPQKV = BpBase;                            // 147456 bf16
    bf16* BpWS    = BpSPQKV + 147456;                  //  49152
    bf16* BpTQKV  = BpWS + 49152;                      // 147456
    bf16* BpWO    = BpTQKV + 147456;                   //  49152
    bf16* BpW1    = BpWO + 49152;                      // 196608
    bf16* BpW2    = BpW1 + 196608;                     // 196608

    RepackArgs ra;
    int s = 0;
    auto mk = [&](int i, const float* W, bf16* out, int K, int N, int ntt, int ntoff, int L) {
        ra.d[i] = {W, out, K, N, ntt, ntoff, L, s};
        s += L * (K >> 5) * (N >> 4) * 64;
    };
    mk(0, sp_Wq, BpSPQKV, 128, 128, 24, 0, 3);
    mk(1, sp_Wk, BpSPQKV, 128, 128, 24, 8, 3);
    mk(2, sp_Wv, BpSPQKV, 128, 128, 24, 16, 3);
    mk(3, sp_Ws, BpWS, 128, 128, 8, 0, 3);
    mk(4, t_Wqkv, BpTQKV, 128, 384, 24, 0, 3);
    mk(5, t_Wo, BpWO, 128, 128, 8, 0, 3);
    mk(6, t_W1, BpW1, 128, 512, 32, 0, 3);
    mk(7, t_W2, BpW2, 512, 128, 8, 0, 3);
    ra.total = s;
    k_repack<<<(s + 255) / 256, 256, 0, stream>>>(ra);
    k_packbias<<<(3 * 384 + 255) / 256, 256, 0, stream>>>(sp_bq, sp_bk, sp_bv, spb);

    k_spatial3<<<BT_, 256, 0, stream>>>(
        input_frames, proj_W, proj_b,
        (const short8*)BpSPQKV, (const short8*)BpWS,
        spb, sp_bs, sp_lng, sp_lnb, edge_attr, sp_We, sp_be, tpos, z32g);

    k_temporal3<<<BN_, 256, 0, stream>>>(
        z32g, (const short8*)BpTQKV, (const short8*)BpWO,
        (const short8*)BpW1, (const short8*)BpW2,
        t_bqkv, t_bo, t_ln1g, t_ln1b, t_b1, t_b2, t_ln2g, t_ln2b, zlast);

    k_head<<<BN_, 128, 0, stream>>>(zlast, head_W1, head_b1, head_W2, head_b2,
                                    (float*)d_out);
}

// Round 6
// 312.850 us; speedup vs baseline: 6.5780x; 1.4811x over previous
//
#include <hip/hip_runtime.h>
#include <hip/hip_bf16.h>
#include <math.h>

typedef __hip_bfloat16 bf16;
typedef short short8 __attribute__((ext_vector_type(8)));
typedef float floatx4 __attribute__((ext_vector_type(4)));

#define B_    8
#define T_    32
#define N_    64
#define F_    6
#define D_    128
#define E_    4032      // N*(N-1)
#define BT_   256       // B*T
#define BN_   512       // B*N

__device__ __forceinline__ float gelu_exact(float x) {
    return 0.5f * x * (1.0f + erff(x * 0.70710678118654752f));
}
__device__ __forceinline__ float bfbits2f(short s) {
    unsigned int u = ((unsigned int)(unsigned short)s) << 16;
    return __uint_as_float(u);
}
// load 32 consecutive bf16 from LDS (16B-aligned) as fp32
__device__ __forceinline__ void ld32lds(const bf16* p, float* o) {
    const short8* sp = (const short8*)p;
#pragma unroll
    for (int i = 0; i < 4; i++) {
        short8 s = sp[i];
#pragma unroll
        for (int j = 0; j < 8; j++) o[i * 8 + j] = bfbits2f(s[j]);
    }
}

// ---------------------------------------------------------------------------
// Repack weights (fp32, row-major KxN, L layers) into MFMA B-fragment layout.
struct RepackDesc { const float* W; bf16* out; int K, N, ntt, ntoff, L, start; };
struct RepackArgs { RepackDesc d[8]; int total; };

__global__ void k_repack(RepackArgs ra) {
    int gid = blockIdx.x * blockDim.x + threadIdx.x;
    if (gid >= ra.total) return;
    int fi = 0;
    while (fi < 7 && gid >= ra.d[fi + 1].start) fi++;
    RepackDesc dd = ra.d[fi];
    int r = gid - dd.start;
    int lane = r & 63; r >>= 6;
    int ntiles = dd.N >> 4;
    int nt = r % ntiles; r /= ntiles;
    int ktiles = dd.K >> 5;
    int kt = r % ktiles;
    int l = r / ktiles;
    int quad = lane >> 4, cc = lane & 15;
    const float* Wl = dd.W + (size_t)l * dd.K * dd.N;
    bf16* o = dd.out + ((((size_t)l * ktiles + kt) * dd.ntt + nt + dd.ntoff) * 64 + lane) * 8;
    int kb = kt * 32 + quad * 8;
    int n = nt * 16 + cc;
#pragma unroll
    for (int j = 0; j < 8; j++)
        o[j] = __float2bfloat16(Wl[(size_t)(kb + j) * dd.N + n]);
}

__global__ void k_packbias(const float* __restrict__ bq, const float* __restrict__ bk,
                           const float* __restrict__ bv, float* __restrict__ out) {
    int i = blockIdx.x * blockDim.x + threadIdx.x;
    if (i >= 3 * 384) return;
    int l = i / 384, c = i % 384;
    float v = (c < 128) ? bq[l * 128 + c]
            : (c < 256) ? bk[l * 128 + c - 128]
                        : bv[l * 128 + c - 256];
    out[i] = v;
}

// ---------------------------------------------------------------------------
// FUSED 3-layer spatial stack. One block per (b,t) graph, 512 thr = 8 waves.
// MFMA attention: S=QK^T, softmax in regs, P->LDS, O=P*V (V transposed).
__global__ __launch_bounds__(512, 2)
void k_spatial3(const float* __restrict__ inp, const float* __restrict__ projW,
                const float* __restrict__ projB,
                const short8* __restrict__ BpQKV, const short8* __restrict__ BpWS,
                const float* __restrict__ spb, const float* __restrict__ bs,
                const float* __restrict__ lng, const float* __restrict__ lnb,
                const float* __restrict__ ea, const float* __restrict__ Weg,
                const float* __restrict__ beg, const float* __restrict__ tpos,
                float* __restrict__ z32g) {
    __shared__ short smem[32768];            // 64 KB exactly
    bf16* hb = (bf16*)smem;                  // [0,8192) sh: 64x128 h bf16
    bf16* qk = (bf16*)(smem + 8192);         // [8192,24576): 64x256 q|k
    bf16* Ps = (bf16*)(smem + 8192);         // overlay: h*4096 + m*64 + n
    float* aggf = (float*)(smem + 8192);     // overlay: m*128 + c (fp32)
    float* fsm = (float*)(smem + 8192);      // overlay: proj W staging
    bf16* Vt = (bf16*)(smem + 24576);        // [24576,32768): d*64 + src

    int bt = blockIdx.x;
    int tid = threadIdx.x;
    int lane = tid & 63, w = tid >> 6;
    int quad = lane >> 4, col = lane & 15;
    int w4 = w & 3, wh = w >> 2;
    const float scale = 0.17677669529663687f;   // 1/sqrt(32)

    // ---- proj: h = input @ W + b (waves 0-3 own rows w*16..+15) ----
    for (int i = tid; i < 896; i += 512)
        fsm[i] = (i < 768) ? projW[i] : projB[i - 768];
    __syncthreads();
    float hreg[32];
    if (w < 4) {
#pragma unroll
        for (int r = 0; r < 4; r++) {
            int n = w * 16 + quad * 4 + r;
            const float* xr = inp + (size_t)(bt * 64 + n) * F_;
            float xin[6];
#pragma unroll
            for (int k2 = 0; k2 < 6; k2++) xin[k2] = xr[k2];
#pragma unroll
            for (int tt = 0; tt < 8; tt++) {
                int c = tt * 16 + col;
                float a = fsm[768 + c];
#pragma unroll
                for (int k2 = 0; k2 < 6; k2++) a = fmaf(xin[k2], fsm[k2 * 128 + c], a);
                hreg[tt * 4 + r] = a;
                hb[n * 128 + c] = __float2bfloat16(a);
            }
        }
    }
    __syncthreads();

    for (int l = 0; l < 3; l++) {
        // ---- phase 1: qkv GEMM. wave=(mt=w4, colhalf=wh), 12 tiles ----
        {
            floatx4 acc[12];
#pragma unroll
            for (int tt = 0; tt < 12; tt++) acc[tt] = (floatx4){0.f, 0.f, 0.f, 0.f};
            const short8* bpl = BpQKV + (size_t)l * 6144;
            for (int kt = 0; kt < 4; kt++) {
                short8 a = *(const short8*)&hb[(w4 * 16 + col) * 128 + kt * 32 + quad * 8];
                const short8* bp = bpl + (size_t)(kt * 24 + wh * 12) * 64 + lane;
#pragma unroll
                for (int tt = 0; tt < 12; tt++)
                    acc[tt] = __builtin_amdgcn_mfma_f32_16x16x32_bf16(a, bp[tt * 64], acc[tt], 0, 0, 0);
            }
            const float* bias = spb + l * 384;
#pragma unroll
            for (int tt = 0; tt < 12; tt++) {
                int c = wh * 192 + tt * 16 + col;
                float bv = bias[c];
#pragma unroll
                for (int r = 0; r < 4; r++) {
                    int row = w4 * 16 + quad * 4 + r;
                    bf16 v = __float2bfloat16(acc[tt][r] + bv);
                    if (c < 256) qk[row * 256 + c] = v;
                    else         Vt[(c - 256) * 64 + row] = v;
                }
            }
        }
        __syncthreads();                     // B1: qk/Vt visible
        // ---- phase 2: attention. wave=(h=w4, rowhalf=wh) ----
        int h = w4, half = wh;
        int hoff = h * 32;
        const float* Wel = Weg + l * 128 + hoff;
        const float* bel = beg + l * 128 + hoff;
        // qWe per dst (lane&31 within half)
        float qWe;
        {
            int dst = half * 32 + (lane & 31);
            float qr[32];
            ld32lds(&qk[dst * 256 + hoff], qr);
            float s0 = 0.f;
#pragma unroll
            for (int c2 = 0; c2 < 32; c2++) s0 = fmaf(qr[c2], Wel[c2], s0);
            qWe = s0;
        }
        // S = Q K^T : 2 m-tiles x 4 n-tiles
        float s[2][4][4], ev[2][4][4];
        {
            short8 aA[2], bB[4];
#pragma unroll
            for (int mtl = 0; mtl < 2; mtl++)
                aA[mtl] = *(const short8*)&qk[((half * 2 + mtl) * 16 + col) * 256 + hoff + quad * 8];
#pragma unroll
            for (int nt = 0; nt < 4; nt++)
                bB[nt] = *(const short8*)&qk[(nt * 16 + col) * 256 + 128 + hoff + quad * 8];
#pragma unroll
            for (int mtl = 0; mtl < 2; mtl++)
#pragma unroll
                for (int nt = 0; nt < 4; nt++) {
                    floatx4 acc = (floatx4){0.f, 0.f, 0.f, 0.f};
                    acc = __builtin_amdgcn_mfma_f32_16x16x32_bf16(aA[mtl], bB[nt], acc, 0, 0, 0);
#pragma unroll
                    for (int r = 0; r < 4; r++) s[mtl][nt][r] = acc[r];
                }
        }
        // alpha = scale*(S + eav*qWe[m]); diag masked
        const float* eag = ea + (size_t)bt * E_;
        float mx[2][4], ls[2][4], ae[2][4], inv[2][4];
#pragma unroll
        for (int mtl = 0; mtl < 2; mtl++)
#pragma unroll
            for (int r = 0; r < 4; r++) {
                int m = half * 32 + mtl * 16 + quad * 4 + r;
                float qWeR = __shfl(qWe, mtl * 16 + quad * 4 + r, 64);
                float rmax = -1e30f;
#pragma unroll
                for (int nt = 0; nt < 4; nt++) {
                    int n = nt * 16 + col;
                    bool diag = (m == n);
                    int eid = diag ? 0 : (n * 63 + m - (m > n ? 1 : 0));
                    float eav = diag ? 0.f : eag[eid];
                    ev[mtl][nt][r] = eav;
                    float al = diag ? -1e30f
                                    : scale * (s[mtl][nt][r] + eav * qWeR);
                    s[mtl][nt][r] = al;
                    rmax = fmaxf(rmax, al);
                }
#pragma unroll
                for (int mk2 = 1; mk2 <= 8; mk2 <<= 1)
                    rmax = fmaxf(rmax, __shfl_xor(rmax, mk2, 64));
                float lsum = 0.f, aesum = 0.f;
#pragma unroll
                for (int nt = 0; nt < 4; nt++) {
                    float p = __expf(s[mtl][nt][r] - rmax);
                    s[mtl][nt][r] = p;
                    lsum += p;
                    aesum = fmaf(p, ev[mtl][nt][r], aesum);
                }
#pragma unroll
                for (int mk2 = 1; mk2 <= 8; mk2 <<= 1) {
                    lsum += __shfl_xor(lsum, mk2, 64);
                    aesum += __shfl_xor(aesum, mk2, 64);
                }
                ls[mtl][r] = lsum;
                ae[mtl][r] = aesum;
                inv[mtl][r] = 1.0f / lsum;
            }
        __syncthreads();                     // B2: all qk reads done
        // P stores (overlay qk region)
#pragma unroll
        for (int mtl = 0; mtl < 2; mtl++)
#pragma unroll
            for (int nt = 0; nt < 4; nt++) {
                int n = nt * 16 + col;
#pragma unroll
                for (int r = 0; r < 4; r++) {
                    int m = half * 32 + mtl * 16 + quad * 4 + r;
                    Ps[h * 4096 + m * 64 + n] = __float2bfloat16(s[mtl][nt][r]);
                }
            }
        // PV (wave-local: reads only rows this wave wrote)
        floatx4 oacc[2][2];
#pragma unroll
        for (int mtl = 0; mtl < 2; mtl++)
#pragma unroll
            for (int ntB = 0; ntB < 2; ntB++) oacc[mtl][ntB] = (floatx4){0.f, 0.f, 0.f, 0.f};
        for (int kt = 0; kt < 2; kt++) {
            short8 aP[2], bV[2];
#pragma unroll
            for (int mtl = 0; mtl < 2; mtl++)
                aP[mtl] = *(const short8*)&Ps[h * 4096 + (half * 32 + mtl * 16 + col) * 64 + kt * 32 + quad * 8];
#pragma unroll
            for (int ntB = 0; ntB < 2; ntB++)
                bV[ntB] = *(const short8*)&Vt[(hoff + ntB * 16 + col) * 64 + kt * 32 + quad * 8];
#pragma unroll
            for (int mtl = 0; mtl < 2; mtl++)
#pragma unroll
                for (int ntB = 0; ntB < 2; ntB++)
                    oacc[mtl][ntB] = __builtin_amdgcn_mfma_f32_16x16x32_bf16(aP[mtl], bV[ntB], oacc[mtl][ntB], 0, 0, 0);
        }
        __syncthreads();                     // B3: all PV reads done
        // agg = (O + accEA*We)*inv + be  -> fp32 overlay
#pragma unroll
        for (int mtl = 0; mtl < 2; mtl++)
#pragma unroll
            for (int ntB = 0; ntB < 2; ntB++) {
                int c = hoff + ntB * 16 + col;
                float Wc = Wel[ntB * 16 + col];
                float bc = bel[ntB * 16 + col];
#pragma unroll
                for (int r = 0; r < 4; r++) {
                    int m = half * 32 + mtl * 16 + quad * 4 + r;
                    aggf[m * 128 + c] = fmaf(fmaf(ae[mtl][r], Wc, oacc[mtl][ntB][r]),
                                             inv[mtl][r], bc);
                }
            }
        __syncthreads();                     // B4: agg visible
        // ---- epilogue: Ws GEMM + agg + residual + LN (waves 0-3) ----
        if (w < 4) {
            floatx4 acc2[8];
#pragma unroll
            for (int tt = 0; tt < 8; tt++) acc2[tt] = (floatx4){0.f, 0.f, 0.f, 0.f};
            const short8* bpl = BpWS + (size_t)l * 2048;
            for (int kt = 0; kt < 4; kt++) {
                short8 a = *(const short8*)&hb[(w * 16 + col) * 128 + kt * 32 + quad * 8];
                const short8* bp = bpl + (size_t)(kt * 8) * 64 + lane;
#pragma unroll
                for (int tt = 0; tt < 8; tt++)
                    acc2[tt] = __builtin_amdgcn_mfma_f32_16x16x32_bf16(a, bp[tt * 64], acc2[tt], 0, 0, 0);
            }
            const float* bsl = bs + l * 128;
            float vv[32], rs[4] = {0.f, 0.f, 0.f, 0.f};
#pragma unroll
            for (int tt = 0; tt < 8; tt++) {
                int c = tt * 16 + col;
                float bv = bsl[c];
#pragma unroll
                for (int r = 0; r < 4; r++) {
                    int row = w * 16 + quad * 4 + r;
                    float v = acc2[tt][r] + bv + aggf[row * 128 + c] + hreg[tt * 4 + r];
                    vv[tt * 4 + r] = v;
                    rs[r] += v;
                }
            }
#pragma unroll
            for (int m = 1; m <= 8; m <<= 1)
#pragma unroll
                for (int r = 0; r < 4; r++) rs[r] += __shfl_xor(rs[r], m, 64);
            float mean[4], vs[4] = {0.f, 0.f, 0.f, 0.f};
#pragma unroll
            for (int r = 0; r < 4; r++) mean[r] = rs[r] * (1.0f / 128.0f);
#pragma unroll
            for (int i = 0; i < 32; i++) {
                float d = vv[i] - mean[i & 3];
                vv[i] = d;
                vs[i & 3] += d * d;
            }
#pragma unroll
            for (int m = 1; m <= 8; m <<= 1)
#pragma unroll
                for (int r = 0; r < 4; r++) vs[r] += __shfl_xor(vs[r], m, 64);
            float inv2[4];
#pragma unroll
            for (int r = 0; r < 4; r++) inv2[r] = rsqrtf(vs[r] * (1.0f / 128.0f) + 1e-5f);
            const float* gl = lng + l * 128;
            const float* bl = lnb + l * 128;
            if (l < 2) {
#pragma unroll
                for (int tt = 0; tt < 8; tt++) {
                    int c = tt * 16 + col;
                    float gc = gl[c], bc = bl[c];
#pragma unroll
                    for (int r = 0; r < 4; r++) {
                        float y = vv[tt * 4 + r] * inv2[r] * gc + bc;
                        int n = w * 16 + quad * 4 + r;
                        hreg[tt * 4 + r] = y;
                        hb[n * 128 + c] = __float2bfloat16(y);
                    }
                }
            } else {                          // final: z = h + pos, transposed
                int b = bt >> 5, t_ = bt & 31;
#pragma unroll
                for (int tt = 0; tt < 8; tt++) {
                    int c = tt * 16 + col;
                    float gc = gl[c], bc = bl[c], pc = tpos[t_ * 128 + c];
#pragma unroll
                    for (int r = 0; r < 4; r++) {
                        float y = vv[tt * 4 + r] * inv2[r] * gc + bc;
                        int n = w * 16 + quad * 4 + r;
                        z32g[((size_t)(b * 64 + n) * 32 + t_) * 128 + c] = y + pc;
                    }
                }
            }
        }
        __syncthreads();                     // B5: hb/agg cycle complete
    }
}

// ---------------------------------------------------------------------------
// FUSED 3-layer temporal stack. One block per (b,n) sequence, 256 thr = 4 waves.
// MFMA causal attention (wave = head). Writes only z[t=31] row.
__global__ __launch_bounds__(256, 2)
void k_temporal3(const float* __restrict__ z32g,
                 const short8* __restrict__ BpQKV, const short8* __restrict__ BpWO,
                 const short8* __restrict__ BpW1, const short8* __restrict__ BpW2,
                 const float* __restrict__ bqkv, const float* __restrict__ bo,
                 const float* __restrict__ ln1g, const float* __restrict__ ln1b,
                 const float* __restrict__ b1, const float* __restrict__ b2,
                 const float* __restrict__ ln2g, const float* __restrict__ ln2b,
                 float* __restrict__ zlast) {
    __shared__ short smem[27392];            // 54784 B
    bf16* zb  = (bf16*)smem;                 // [0,4352): 32x136
    bf16* qk  = (bf16*)(smem + 4352);        // [4352,12800): 32x264 q|k
    bf16* Ps  = (bf16*)(smem + 12800);       // [12800,17920): h*1280+t*40
    bf16* Vt  = (bf16*)(smem + 17920);       // [17920,23040): d*40+t
    bf16* o16 = (bf16*)(smem + 23040);       // [23040,27392): 32x136
    bf16* f1  = (bf16*)(smem + 4352);        // overlay attn: 32x520

    int bn = blockIdx.x;
    int tid = threadIdx.x;
    int lane = tid & 63, w = tid >> 6;
    int quad = lane >> 4, col = lane & 15;
    int rsel = w & 1, csel = w >> 1;
    const float scale = 0.17677669529663687f;

    // ---- stage z: zb (all), zreg (waves 0/1) ----
    for (int i = tid; i < 4096; i += 256) {
        float v = z32g[(size_t)bn * 4096 + i];
        zb[(i >> 7) * 136 + (i & 127)] = __float2bfloat16(v);
    }
    float zreg[32];
    if (w < 2) {
#pragma unroll
        for (int tt = 0; tt < 8; tt++)
#pragma unroll
            for (int r = 0; r < 4; r++)
                zreg[tt * 4 + r] = z32g[(size_t)bn * 4096 +
                                        (w * 16 + quad * 4 + r) * 128 + tt * 16 + col];
    }
    __syncthreads();

    for (int l = 0; l < 3; l++) {
        // ---- phase 1: qkv GEMM. wave=(rsel,csel), 12 tiles ----
        {
            floatx4 acc[12];
#pragma unroll
            for (int tt = 0; tt < 12; tt++) acc[tt] = (floatx4){0.f, 0.f, 0.f, 0.f};
            const short8* bpl = BpQKV + (size_t)l * 6144;
            for (int kt = 0; kt < 4; kt++) {
                short8 a = *(const short8*)&zb[(rsel * 16 + col) * 136 + kt * 32 + quad * 8];
                const short8* bp = bpl + (size_t)(kt * 24 + csel * 12) * 64 + lane;
#pragma unroll
                for (int tt = 0; tt < 12; tt++)
                    acc[tt] = __builtin_amdgcn_mfma_f32_16x16x32_bf16(a, bp[tt * 64], acc[tt], 0, 0, 0);
            }
            const float* bias = bqkv + l * 384;
#pragma unroll
            for (int tt = 0; tt < 12; tt++) {
                int c = csel * 192 + tt * 16 + col;
                float bv = bias[c];
#pragma unroll
                for (int r = 0; r < 4; r++) {
                    int row = rsel * 16 + quad * 4 + r;
                    bf16 v = __float2bfloat16(acc[tt][r] + bv);
                    if (c < 256) qk[row * 264 + c] = v;
                    else         Vt[(c - 256) * 40 + row] = v;
                }
            }
        }
        __syncthreads();                     // B1: qk/Vt visible
        // ---- phase 2: causal attention, wave = head ----
        {
            int h = w, hoff = h * 32;
            float s[2][2][4];
            short8 aA[2], bB[2];
#pragma unroll
            for (int mt = 0; mt < 2; mt++)
                aA[mt] = *(const short8*)&qk[(mt * 16 + col) * 264 + hoff + quad * 8];
#pragma unroll
            for (int nt = 0; nt < 2; nt++)
                bB[nt] = *(const short8*)&qk[(nt * 16 + col) * 264 + 128 + hoff + quad * 8];
#pragma unroll
            for (int mt = 0; mt < 2; mt++)
#pragma unroll
                for (int nt = 0; nt < 2; nt++) {
                    floatx4 acc = (floatx4){0.f, 0.f, 0.f, 0.f};
                    acc = __builtin_amdgcn_mfma_f32_16x16x32_bf16(aA[mt], bB[nt], acc, 0, 0, 0);
#pragma unroll
                    for (int r = 0; r < 4; r++) s[mt][nt][r] = acc[r];
                }
            float inv[2][4];
#pragma unroll
            for (int mt = 0; mt < 2; mt++)
#pragma unroll
                for (int r = 0; r < 4; r++) {
                    int m = mt * 16 + quad * 4 + r;
                    float rmax = -1e30f;
#pragma unroll
                    for (int nt = 0; nt < 2; nt++) {
                        int n = nt * 16 + col;
                        float al = (n > m) ? -1e30f : s[mt][nt][r] * scale;
                        s[mt][nt][r] = al;
                        rmax = fmaxf(rmax, al);
                    }
#pragma unroll
                    for (int mk2 = 1; mk2 <= 8; mk2 <<= 1)
                        rmax = fmaxf(rmax, __shfl_xor(rmax, mk2, 64));
                    float lsum = 0.f;
#pragma unroll
                    for (int nt = 0; nt < 2; nt++) {
                        float p = __expf(s[mt][nt][r] - rmax);
                        s[mt][nt][r] = p;
                        lsum += p;
                    }
#pragma unroll
                    for (int mk2 = 1; mk2 <= 8; mk2 <<= 1)
                        lsum += __shfl_xor(lsum, mk2, 64);
                    inv[mt][r] = 1.0f / lsum;
                }
            // P stores (own region per head, wave-local consumption)
#pragma unroll
            for (int mt = 0; mt < 2; mt++)
#pragma unroll
                for (int nt = 0; nt < 2; nt++) {
                    int n = nt * 16 + col;
#pragma unroll
                    for (int r = 0; r < 4; r++)
                        Ps[h * 1280 + (mt * 16 + quad * 4 + r) * 40 + n] =
                            __float2bfloat16(s[mt][nt][r]);
                }
            // PV
            floatx4 oacc[2][2];
#pragma unroll
            for (int mt = 0; mt < 2; mt++)
#pragma unroll
                for (int nt = 0; nt < 2; nt++) oacc[mt][nt] = (floatx4){0.f, 0.f, 0.f, 0.f};
            short8 aP[2], bV[2];
#pragma unroll
            for (int mt = 0; mt < 2; mt++)
                aP[mt] = *(const short8*)&Ps[h * 1280 + (mt * 16 + col) * 40 + quad * 8];
#pragma unroll
            for (int nt = 0; nt < 2; nt++)
                bV[nt] = *(const short8*)&Vt[(hoff + nt * 16 + col) * 40 + quad * 8];
#pragma unroll
            for (int mt = 0; mt < 2; mt++)
#pragma unroll
                for (int nt = 0; nt < 2; nt++)
                    oacc[mt][nt] = __builtin_amdgcn_mfma_f32_16x16x32_bf16(aP[mt], bV[nt], oacc[mt][nt], 0, 0, 0);
            // o16 (dedicated region; per-head column sections disjoint)
#pragma unroll
            for (int mt = 0; mt < 2; mt++)
#pragma unroll
                for (int nt = 0; nt < 2; nt++) {
                    int c = hoff + nt * 16 + col;
#pragma unroll
                    for (int r = 0; r < 4; r++)
                        o16[(mt * 16 + quad * 4 + r) * 136 + c] =
                            __float2bfloat16(oacc[mt][nt][r] * inv[mt][r]);
                }
        }
        __syncthreads();                     // B2: o16 visible
        // ---- Wo GEMM + residual + LN1 (waves 0/1) ----
        if (w < 2) {
            floatx4 acc2[8];
#pragma unroll
            for (int tt = 0; tt < 8; tt++) acc2[tt] = (floatx4){0.f, 0.f, 0.f, 0.f};
            const short8* bpl = BpWO + (size_t)l * 2048;
            for (int kt = 0; kt < 4; kt++) {
                short8 a = *(const short8*)&o16[(w * 16 + col) * 136 + kt * 32 + quad * 8];
                const short8* bp = bpl + (size_t)(kt * 8) * 64 + lane;
#pragma unroll
                for (int tt = 0; tt < 8; tt++)
                    acc2[tt] = __builtin_amdgcn_mfma_f32_16x16x32_bf16(a, bp[tt * 64], acc2[tt], 0, 0, 0);
            }
            const float* bol = bo + l * 128;
            float vv[32], rs[4] = {0.f, 0.f, 0.f, 0.f};
#pragma unroll
            for (int tt = 0; tt < 8; tt++) {
                int c = tt * 16 + col;
                float bv = bol[c];
#pragma unroll
                for (int r = 0; r < 4; r++) {
                    float v = acc2[tt][r] + bv + zreg[tt * 4 + r];
                    vv[tt * 4 + r] = v;
                    rs[r] += v;
                }
            }
#pragma unroll
            for (int m = 1; m <= 8; m <<= 1)
#pragma unroll
                for (int r = 0; r < 4; r++) rs[r] += __shfl_xor(rs[r], m, 64);
            float mean[4], vs[4] = {0.f, 0.f, 0.f, 0.f};
#pragma unroll
            for (int r = 0; r < 4; r++) mean[r] = rs[r] * (1.0f / 128.0f);
#pragma unroll
            for (int i = 0; i < 32; i++) {
                float d = vv[i] - mean[i & 3];
                vv[i] = d;
                vs[i & 3] += d * d;
            }
#pragma unroll
            for (int m = 1; m <= 8; m <<= 1)
#pragma unroll
                for (int r = 0; r < 4; r++) vs[r] += __shfl_xor(vs[r], m, 64);
            float inv2[4];
#pragma unroll
            for (int r = 0; r < 4; r++) inv2[r] = rsqrtf(vs[r] * (1.0f / 128.0f) + 1e-5f);
            const float* gl = ln1g + l * 128;
            const float* bl = ln1b + l * 128;
#pragma unroll
            for (int tt = 0; tt < 8; tt++) {
                int c = tt * 16 + col;
                float gc = gl[c], bc = bl[c];
#pragma unroll
                for (int r = 0; r < 4; r++) {
                    float y = vv[tt * 4 + r] * inv2[r] * gc + bc;
                    int row = w * 16 + quad * 4 + r;
                    zreg[tt * 4 + r] = y;
                    zb[row * 136 + c] = __float2bfloat16(y);
                }
            }
        }
        __syncthreads();                     // B3: zb visible; attn bufs free
        // ---- W1 GEMM + gelu (all 4 waves) -> f1 (overlay) ----
        {
            floatx4 acc3[16];
#pragma unroll
            for (int tt = 0; tt < 16; tt++) acc3[tt] = (floatx4){0.f, 0.f, 0.f, 0.f};
            const short8* bpl = BpW1 + (size_t)l * 8192;
            for (int kt = 0; kt < 4; kt++) {
                short8 a = *(const short8*)&zb[(rsel * 16 + col) * 136 + kt * 32 + quad * 8];
                const short8* bp = bpl + (size_t)(kt * 32 + csel * 16) * 64 + lane;
#pragma unroll
                for (int tt = 0; tt < 16; tt++)
                    acc3[tt] = __builtin_amdgcn_mfma_f32_16x16x32_bf16(a, bp[tt * 64], acc3[tt], 0, 0, 0);
            }
            const float* b1l = b1 + l * 512;
#pragma unroll
            for (int tt = 0; tt < 16; tt++) {
                int c = csel * 256 + tt * 16 + col;
                float bv = b1l[c];
#pragma unroll
                for (int r = 0; r < 4; r++) {
                    float v = gelu_exact(acc3[tt][r] + bv);
                    f1[(rsel * 16 + quad * 4 + r) * 520 + c] = __float2bfloat16(v);
                }
            }
        }
        __syncthreads();                     // B4: f1 visible
        // ---- W2 GEMM + residual + LN2 (waves 0/1) ----
        if (w < 2) {
            floatx4 acc4[8];
#pragma unroll
            for (int tt = 0; tt < 8; tt++) acc4[tt] = (floatx4){0.f, 0.f, 0.f, 0.f};
            const short8* bpl = BpW2 + (size_t)l * 8192;
            for (int kt = 0; kt < 16; kt++) {
                short8 a = *(const short8*)&f1[(w * 16 + col) * 520 + kt * 32 + quad * 8];
                const short8* bp = bpl + (size_t)(kt * 8) * 64 + lane;
#pragma unroll
                for (int tt = 0; tt < 8; tt++)
                    acc4[tt] = __builtin_amdgcn_mfma_f32_16x16x32_bf16(a, bp[tt * 64], acc4[tt], 0, 0, 0);
            }
            const float* b2l = b2 + l * 128;
            float vv[32], rs[4] = {0.f, 0.f, 0.f, 0.f};
#pragma unroll
            for (int tt = 0; tt < 8; tt++) {
                int c = tt * 16 + col;
                float bv = b2l[c];
#pragma unroll
                for (int r = 0; r < 4; r++) {
                    float v = acc4[tt][r] + bv + zreg[tt * 4 + r];
                    vv[tt * 4 + r] = v;
                    rs[r] += v;
                }
            }
#pragma unroll
            for (int m = 1; m <= 8; m <<= 1)
#pragma unroll
                for (int r = 0; r < 4; r++) rs[r] += __shfl_xor(rs[r], m, 64);
            float mean[4], vs[4] = {0.f, 0.f, 0.f, 0.f};
#pragma unroll
            for (int r = 0; r < 4; r++) mean[r] = rs[r] * (1.0f / 128.0f);
#pragma unroll
            for (int i = 0; i < 32; i++) {
                float d = vv[i] - mean[i & 3];
                vv[i] = d;
                vs[i & 3] += d * d;
            }
#pragma unroll
            for (int m = 1; m <= 8; m <<= 1)
#pragma unroll
                for (int r = 0; r < 4; r++) vs[r] += __shfl_xor(vs[r], m, 64);
            float inv2[4];
#pragma unroll
            for (int r = 0; r < 4; r++) inv2[r] = rsqrtf(vs[r] * (1.0f / 128.0f) + 1e-5f);
            const float* gl = ln2g + l * 128;
            const float* bl = ln2b + l * 128;
#pragma unroll
            for (int tt = 0; tt < 8; tt++) {
                int c = tt * 16 + col;
                float gc = gl[c], bc = bl[c];
#pragma unroll
                for (int r = 0; r < 4; r++) {
                    float y = vv[tt * 4 + r] * inv2[r] * gc + bc;
                    int row = w * 16 + quad * 4 + r;
                    zreg[tt * 4 + r] = y;
                    if (l < 2) zb[row * 136 + c] = __float2bfloat16(y);
                    else if (row == 31) zlast[(size_t)bn * 128 + c] = y;
                }
            }
        }
        __syncthreads();                     // B5: loop end
    }
}

// ---------------------------------------------------------------------------
__global__ __launch_bounds__(128)
void k_head(const float* __restrict__ zlast, const float* __restrict__ W1,
            const float* __restrict__ b1, const float* __restrict__ W2,
            const float* __restrict__ b2, float* __restrict__ out) {
    int bn = blockIdx.x;
    int d = threadIdx.x;
    __shared__ float zl[128], h1[128];
    zl[d] = zlast[(size_t)bn * 128 + d];
    __syncthreads();
    float acc = b1[d];
    for (int k = 0; k < 128; k++) acc = fmaf(zl[k], W1[k * 128 + d], acc);
    h1[d] = gelu_exact(acc);
    __syncthreads();
    if (d < F_) {
        float o = b2[d];
        for (int k = 0; k < 128; k++) o = fmaf(h1[k], W2[k * F_ + d], o);
        out[bn * F_ + d] = o;
    }
}

// ---------------------------------------------------------------------------
extern "C" void kernel_launch(void* const* d_in, const int* in_sizes, int n_in,
                              void* d_out, int out_size, void* d_ws, size_t ws_size,
                              hipStream_t stream) {
    const float* input_frames = (const float*)d_in[0];
    const float* edge_attr    = (const float*)d_in[1];
    const float* proj_W  = (const float*)d_in[2];
    const float* proj_b  = (const float*)d_in[3];
    const float* sp_Wq   = (const float*)d_in[4];
    const float* sp_bq   = (const float*)d_in[5];
    const float* sp_Wk   = (const float*)d_in[6];
    const float* sp_bk   = (const float*)d_in[7];
    const float* sp_Wv   = (const float*)d_in[8];
    const float* sp_bv   = (const float*)d_in[9];
    const float* sp_We   = (const float*)d_in[10];
    const float* sp_be   = (const float*)d_in[11];
    const float* sp_Ws   = (const float*)d_in[12];
    const float* sp_bs   = (const float*)d_in[13];
    const float* sp_lng  = (const float*)d_in[14];
    const float* sp_lnb  = (const float*)d_in[15];
    const float* tpos    = (const float*)d_in[16];
    const float* t_Wqkv  = (const float*)d_in[17];
    const float* t_bqkv  = (const float*)d_in[18];
    const float* t_Wo    = (const float*)d_in[19];
    const float* t_bo    = (const float*)d_in[20];
    const float* t_ln1g  = (const float*)d_in[21];
    const float* t_ln1b  = (const float*)d_in[22];
    const float* t_W1    = (const float*)d_in[23];
    const float* t_b1    = (const float*)d_in[24];
    const float* t_W2    = (const float*)d_in[25];
    const float* t_b2    = (const float*)d_in[26];
    const float* t_ln2g  = (const float*)d_in[27];
    const float* t_ln2b  = (const float*)d_in[28];
    const float* head_W1 = (const float*)d_in[29];
    const float* head_b1 = (const float*)d_in[30];
    const float* head_W2 = (const float*)d_in[31];
    const float* head_b2 = (const float*)d_in[32];

    float* f     = (float*)d_ws;
    float* z32g  = f;                                  // 2M floats
    float* zlast = f + (1u << 21);                     // 64K floats
    float* spb   = f + (1u << 21) + 65536;             // 1152 floats
    bf16* BpBase = (bf16*)(f + (1u << 21) + 65536 + 2048);
    bf16* BpSPQKV = BpBase;                            // 147456 bf16
    bf16* BpWS    = BpSPQKV + 147456;                  //  49152
    bf16* BpTQKV  = BpWS + 49152;                      // 147456
    bf16* BpWO    = BpTQKV + 147456;                   //  49152
    bf16* BpW1    = BpWO + 49152;                      // 196608
    bf16* BpW2    = BpW1 + 196608;                     // 196608

    RepackArgs ra;
    int s = 0;
    auto mk = [&](int i, const float* W, bf16* out, int K, int N, int ntt, int ntoff, int L) {
        ra.d[i] = {W, out, K, N, ntt, ntoff, L, s};
        s += L * (K >> 5) * (N >> 4) * 64;
    };
    mk(0, sp_Wq, BpSPQKV, 128, 128, 24, 0, 3);
    mk(1, sp_Wk, BpSPQKV, 128, 128, 24, 8, 3);
    mk(2, sp_Wv, BpSPQKV, 128, 128, 24, 16, 3);
    mk(3, sp_Ws, BpWS, 128, 128, 8, 0, 3);
    mk(4, t_Wqkv, BpTQKV, 128, 384, 24, 0, 3);
    mk(5, t_Wo, BpWO, 128, 128, 8, 0, 3);
    mk(6, t_W1, BpW1, 128, 512, 32, 0, 3);
    mk(7, t_W2, BpW2, 512, 128, 8, 0, 3);
    ra.total = s;
    k_repack<<<(s + 255) / 256, 256, 0, stream>>>(ra);
    k_packbias<<<(3 * 384 + 255) / 256, 256, 0, stream>>>(sp_bq, sp_bk, sp_bv, spb);

    k_spatial3<<<BT_, 512, 0, stream>>>(
        input_frames, proj_W, proj_b,
        (const short8*)BpSPQKV, (const short8*)BpWS,
        spb, sp_bs, sp_lng, sp_lnb, edge_attr, sp_We, sp_be, tpos, z32g);

    k_temporal3<<<BN_, 256, 0, stream>>>(
        z32g, (const short8*)BpTQKV, (const short8*)BpWO,
        (const short8*)BpW1, (const short8*)BpW2,
        t_bqkv, t_bo, t_ln1g, t_ln1b, t_b1, t_b2, t_ln2g, t_ln2b, zlast);

    k_head<<<BN_, 128, 0, stream>>>(zlast, head_W1, head_b1, head_W2, head_b2,
                                    (float*)d_out);
}

// Round 7
// 289.465 us; speedup vs baseline: 7.1095x; 1.0808x over previous
//
#include <hip/hip_runtime.h>
#include <hip/hip_bf16.h>
#include <math.h>

typedef __hip_bfloat16 bf16;
typedef short short8 __attribute__((ext_vector_type(8)));
typedef float floatx4 __attribute__((ext_vector_type(4)));

#define B_    8
#define T_    32
#define N_    64
#define F_    6
#define D_    128
#define E_    4032      // N*(N-1)
#define BT_   256       // B*T
#define BN_   512       // B*N

__device__ __forceinline__ float gelu_exact(float x) {
    return 0.5f * x * (1.0f + erff(x * 0.70710678118654752f));
}
__device__ __forceinline__ float bfbits2f(short s) {
    unsigned int u = ((unsigned int)(unsigned short)s) << 16;
    return __uint_as_float(u);
}
// load 32 consecutive bf16 from LDS (16B-aligned) as fp32
__device__ __forceinline__ void ld32lds(const bf16* p, float* o) {
    const short8* sp = (const short8*)p;
#pragma unroll
    for (int i = 0; i < 4; i++) {
        short8 s = sp[i];
#pragma unroll
        for (int j = 0; j < 8; j++) o[i * 8 + j] = bfbits2f(s[j]);
    }
}

// ---------------------------------------------------------------------------
// Repack weights (fp32, row-major KxN, L layers) into MFMA B-fragment layout.
struct RepackDesc { const float* W; bf16* out; int K, N, ntt, ntoff, L, start; };
struct RepackArgs { RepackDesc d[9]; int total; };

__global__ void k_repack(RepackArgs ra) {
    int gid = blockIdx.x * blockDim.x + threadIdx.x;
    if (gid >= ra.total) return;
    int fi = 0;
    while (fi < 8 && gid >= ra.d[fi + 1].start) fi++;
    RepackDesc dd = ra.d[fi];
    int r = gid - dd.start;
    int lane = r & 63; r >>= 6;
    int ntiles = dd.N >> 4;
    int nt = r % ntiles; r /= ntiles;
    int ktiles = dd.K >> 5;
    int kt = r % ktiles;
    int l = r / ktiles;
    int quad = lane >> 4, cc = lane & 15;
    const float* Wl = dd.W + (size_t)l * dd.K * dd.N;
    bf16* o = dd.out + ((((size_t)l * ktiles + kt) * dd.ntt + nt + dd.ntoff) * 64 + lane) * 8;
    int kb = kt * 32 + quad * 8;
    int n = nt * 16 + cc;
#pragma unroll
    for (int j = 0; j < 8; j++)
        o[j] = __float2bfloat16(Wl[(size_t)(kb + j) * dd.N + n]);
}

__global__ void k_packbias(const float* __restrict__ bq, const float* __restrict__ bk,
                           const float* __restrict__ bv, float* __restrict__ out) {
    int i = blockIdx.x * blockDim.x + threadIdx.x;
    if (i >= 3 * 384) return;
    int l = i / 384, c = i % 384;
    float v = (c < 128) ? bq[l * 128 + c]
            : (c < 256) ? bk[l * 128 + c - 128]
                        : bv[l * 128 + c - 256];
    out[i] = v;
}

// ---------------------------------------------------------------------------
// FUSED 3-layer spatial stack. One block per (b,t) graph, 512 thr = 8 waves.
// Padded LDS strides (conflict-free), EAs staged in LDS, P hi/lo split PV.
__global__ __launch_bounds__(512, 1)
void k_spatial3(const float* __restrict__ inp, const float* __restrict__ projW,
                const float* __restrict__ projB,
                const short8* __restrict__ BpQKV, const short8* __restrict__ BpWS,
                const float* __restrict__ spb, const float* __restrict__ bs,
                const float* __restrict__ lng, const float* __restrict__ lnb,
                const float* __restrict__ ea, const float* __restrict__ Weg,
                const float* __restrict__ beg, const float* __restrict__ tpos,
                float* __restrict__ z32g) {
    __shared__ short smem[61312];            // 122624 B
    bf16* hb = (bf16*)smem;                  // [0,8704): 64 x 136
    bf16* qk = (bf16*)(smem + 8704);         // [8704,25600): 64 x 264 (q|k)
    float* aggf = (float*)(smem + 8704);     // overlay qk: 64 x 128 fp32
    float* fsm = (float*)(smem + 8704);      // overlay qk: proj staging
    bf16* Vt = (bf16*)(smem + 25600);        // [25600,34816): 128 x 72 (d-major)
    bf16* Ps = (bf16*)(smem + 34816);        // [34816,53248): h*4608 + m*72
    float* EAs = (float*)(smem + 53248);     // [53248,61312): 4032 fp32

    int bt = blockIdx.x;
    int tid = threadIdx.x;
    int lane = tid & 63, w = tid >> 6;
    int quad = lane >> 4, col = lane & 15;
    int w4 = w & 3, wh = w >> 2;
    const float scale = 0.17677669529663687f;   // 1/sqrt(32)

    // ---- stage: proj weights + EAs ----
    for (int i = tid; i < 896; i += 512)
        fsm[i] = (i < 768) ? projW[i] : projB[i - 768];
    {
        const float* eag = ea + (size_t)bt * E_;
        for (int i = tid; i < E_; i += 512) EAs[i] = eag[i];
    }
    __syncthreads();
    // ---- proj: h = input @ W + b (waves 0-3) ----
    float hreg[32];
    if (w < 4) {
#pragma unroll
        for (int r = 0; r < 4; r++) {
            int n = w * 16 + quad * 4 + r;
            const float* xr = inp + (size_t)(bt * 64 + n) * F_;
            float xin[6];
#pragma unroll
            for (int k2 = 0; k2 < 6; k2++) xin[k2] = xr[k2];
#pragma unroll
            for (int tt = 0; tt < 8; tt++) {
                int c = tt * 16 + col;
                float a = fsm[768 + c];
#pragma unroll
                for (int k2 = 0; k2 < 6; k2++) a = fmaf(xin[k2], fsm[k2 * 128 + c], a);
                hreg[tt * 4 + r] = a;
                hb[n * 136 + c] = __float2bfloat16(a);
            }
        }
    }
    __syncthreads();                         // B0

    for (int l = 0; l < 3; l++) {
        // ---- phase 1: qkv GEMM. wave=(mt=w4, colhalf=wh), 12 tiles ----
        {
            floatx4 acc[12];
#pragma unroll
            for (int tt = 0; tt < 12; tt++) acc[tt] = (floatx4){0.f, 0.f, 0.f, 0.f};
            const short8* bpl = BpQKV + (size_t)l * 6144;
            for (int kt = 0; kt < 4; kt++) {
                short8 a = *(const short8*)&hb[(w4 * 16 + col) * 136 + kt * 32 + quad * 8];
                const short8* bp = bpl + (size_t)(kt * 24 + wh * 12) * 64 + lane;
#pragma unroll
                for (int tt = 0; tt < 12; tt++)
                    acc[tt] = __builtin_amdgcn_mfma_f32_16x16x32_bf16(a, bp[tt * 64], acc[tt], 0, 0, 0);
            }
            const float* bias = spb + l * 384;
#pragma unroll
            for (int tt = 0; tt < 12; tt++) {
                int c = wh * 192 + tt * 16 + col;
                float bv = bias[c];
#pragma unroll
                for (int r = 0; r < 4; r++) {
                    int row = w4 * 16 + quad * 4 + r;
                    bf16 v = __float2bfloat16(acc[tt][r] + bv);
                    if (c < 256) qk[row * 264 + c] = v;
                    else         Vt[(c - 256) * 72 + row] = v;
                }
            }
        }
        __syncthreads();                     // B1: qk/Vt visible
        // ---- phase 2: attention. wave=(h=w4, rowhalf=wh) ----
        int h = w4, half = wh;
        int hoff = h * 32;
        const float* Wel = Weg + l * 128 + hoff;
        const float* bel = beg + l * 128 + hoff;
        float qWe;
        {
            int dst = half * 32 + (lane & 31);
            float qr[32];
            ld32lds(&qk[dst * 264 + hoff], qr);
            float s0 = 0.f, s1 = 0.f, s2 = 0.f, s3 = 0.f;
#pragma unroll
            for (int c2 = 0; c2 < 32; c2 += 4) {
                s0 = fmaf(qr[c2], Wel[c2], s0);
                s1 = fmaf(qr[c2 + 1], Wel[c2 + 1], s1);
                s2 = fmaf(qr[c2 + 2], Wel[c2 + 2], s2);
                s3 = fmaf(qr[c2 + 3], Wel[c2 + 3], s3);
            }
            qWe = (s0 + s1) + (s2 + s3);
        }
        float s[2][4][4], ev[2][4][4];
        {
            short8 aA[2], bB[4];
#pragma unroll
            for (int mtl = 0; mtl < 2; mtl++)
                aA[mtl] = *(const short8*)&qk[((half * 2 + mtl) * 16 + col) * 264 + hoff + quad * 8];
#pragma unroll
            for (int nt = 0; nt < 4; nt++)
                bB[nt] = *(const short8*)&qk[(nt * 16 + col) * 264 + 128 + hoff + quad * 8];
#pragma unroll
            for (int mtl = 0; mtl < 2; mtl++)
#pragma unroll
                for (int nt = 0; nt < 4; nt++) {
                    floatx4 acc = (floatx4){0.f, 0.f, 0.f, 0.f};
                    acc = __builtin_amdgcn_mfma_f32_16x16x32_bf16(aA[mtl], bB[nt], acc, 0, 0, 0);
#pragma unroll
                    for (int r = 0; r < 4; r++) s[mtl][nt][r] = acc[r];
                }
        }
        __syncthreads();                     // B2: all qk reads done
        // softmax with rank-1 edge term (EAs from LDS)
        float ls[2][4], ae[2][4], inv[2][4];
#pragma unroll
        for (int mtl = 0; mtl < 2; mtl++)
#pragma unroll
            for (int r = 0; r < 4; r++) {
                int m = half * 32 + mtl * 16 + quad * 4 + r;
                float qWeR = __shfl(qWe, mtl * 16 + quad * 4 + r, 64);
                float rmax = -1e30f;
#pragma unroll
                for (int nt = 0; nt < 4; nt++) {
                    int n = nt * 16 + col;
                    bool diag = (m == n);
                    int eid = diag ? 0 : (n * 63 + m - (m > n ? 1 : 0));
                    float eav = diag ? 0.f : EAs[eid];
                    ev[mtl][nt][r] = eav;
                    float al = diag ? -1e30f
                                    : scale * (s[mtl][nt][r] + eav * qWeR);
                    s[mtl][nt][r] = al;
                    rmax = fmaxf(rmax, al);
                }
#pragma unroll
                for (int mk2 = 1; mk2 <= 8; mk2 <<= 1)
                    rmax = fmaxf(rmax, __shfl_xor(rmax, mk2, 64));
                float lsum = 0.f, aesum = 0.f;
#pragma unroll
                for (int nt = 0; nt < 4; nt++) {
                    float p = __expf(s[mtl][nt][r] - rmax);
                    s[mtl][nt][r] = p;
                    lsum += p;
                    aesum = fmaf(p, ev[mtl][nt][r], aesum);
                }
#pragma unroll
                for (int mk2 = 1; mk2 <= 8; mk2 <<= 1) {
                    lsum += __shfl_xor(lsum, mk2, 64);
                    aesum += __shfl_xor(aesum, mk2, 64);
                }
                ls[mtl][r] = lsum;
                ae[mtl][r] = aesum;
                inv[mtl][r] = 1.0f / lsum;
            }
        // PV: two passes over n (32 each), P = hi + lo compensated bf16 split.
        // Wave-local Ps rows; hi chunk at +quad*16, lo at +8.
        bf16* PsH = Ps + h * 4608;
        floatx4 oacc[2][2];
#pragma unroll
        for (int mtl = 0; mtl < 2; mtl++)
#pragma unroll
            for (int ntB = 0; ntB < 2; ntB++) oacc[mtl][ntB] = (floatx4){0.f, 0.f, 0.f, 0.f};
#pragma unroll
        for (int p = 0; p < 2; p++) {
#pragma unroll
            for (int mtl = 0; mtl < 2; mtl++)
#pragma unroll
                for (int q2 = 0; q2 < 2; q2++) {
                    int nl = q2 * 16 + col;
                    int base0 = (half * 32 + mtl * 16 + quad * 4) * 72 + ((nl >> 3) * 2) * 8 + (nl & 7);
#pragma unroll
                    for (int r = 0; r < 4; r++) {
                        float p_ = s[mtl][2 * p + q2][r];
                        bf16 hi = __float2bfloat16(p_);
                        bf16 lo = __float2bfloat16(p_ - bfbits2f(*(short*)&hi));
                        PsH[base0 + r * 72] = hi;
                        PsH[base0 + r * 72 + 8] = lo;
                    }
                }
            short8 aPh[2], aPl[2], bV[2];
#pragma unroll
            for (int mtl = 0; mtl < 2; mtl++) {
                int rb = (half * 32 + mtl * 16 + col) * 72 + quad * 16;
                aPh[mtl] = *(const short8*)&PsH[rb];
                aPl[mtl] = *(const short8*)&PsH[rb + 8];
            }
#pragma unroll
            for (int ntB = 0; ntB < 2; ntB++)
                bV[ntB] = *(const short8*)&Vt[(hoff + ntB * 16 + col) * 72 + p * 32 + quad * 8];
#pragma unroll
            for (int mtl = 0; mtl < 2; mtl++)
#pragma unroll
                for (int ntB = 0; ntB < 2; ntB++) {
                    oacc[mtl][ntB] = __builtin_amdgcn_mfma_f32_16x16x32_bf16(aPh[mtl], bV[ntB], oacc[mtl][ntB], 0, 0, 0);
                    oacc[mtl][ntB] = __builtin_amdgcn_mfma_f32_16x16x32_bf16(aPl[mtl], bV[ntB], oacc[mtl][ntB], 0, 0, 0);
                }
        }
        // agg = (O + accEA*We)*inv + be -> aggf (overlay qk; qk reads done at B2)
#pragma unroll
        for (int mtl = 0; mtl < 2; mtl++)
#pragma unroll
            for (int ntB = 0; ntB < 2; ntB++) {
                int c = hoff + ntB * 16 + col;
                float Wc = Wel[ntB * 16 + col];
                float bc = bel[ntB * 16 + col];
#pragma unroll
                for (int r = 0; r < 4; r++) {
                    int m = half * 32 + mtl * 16 + quad * 4 + r;
                    aggf[m * 128 + c] = fmaf(fmaf(ae[mtl][r], Wc, oacc[mtl][ntB][r]),
                                             inv[mtl][r], bc);
                }
            }
        __syncthreads();                     // B3: agg visible
        // ---- epilogue: Ws GEMM + agg + residual + LN (waves 0-3) ----
        if (w < 4) {
            floatx4 acc2[8];
#pragma unroll
            for (int tt = 0; tt < 8; tt++) acc2[tt] = (floatx4){0.f, 0.f, 0.f, 0.f};
            const short8* bpl = BpWS + (size_t)l * 2048;
            for (int kt = 0; kt < 4; kt++) {
                short8 a = *(const short8*)&hb[(w * 16 + col) * 136 + kt * 32 + quad * 8];
                const short8* bp = bpl + (size_t)(kt * 8) * 64 + lane;
#pragma unroll
                for (int tt = 0; tt < 8; tt++)
                    acc2[tt] = __builtin_amdgcn_mfma_f32_16x16x32_bf16(a, bp[tt * 64], acc2[tt], 0, 0, 0);
            }
            const float* bsl = bs + l * 128;
            float vv[32], rs[4] = {0.f, 0.f, 0.f, 0.f};
#pragma unroll
            for (int tt = 0; tt < 8; tt++) {
                int c = tt * 16 + col;
                float bv = bsl[c];
#pragma unroll
                for (int r = 0; r < 4; r++) {
                    int row = w * 16 + quad * 4 + r;
                    float v = acc2[tt][r] + bv + aggf[row * 128 + c] + hreg[tt * 4 + r];
                    vv[tt * 4 + r] = v;
                    rs[r] += v;
                }
            }
#pragma unroll
            for (int m = 1; m <= 8; m <<= 1)
#pragma unroll
                for (int r = 0; r < 4; r++) rs[r] += __shfl_xor(rs[r], m, 64);
            float mean[4], vs[4] = {0.f, 0.f, 0.f, 0.f};
#pragma unroll
            for (int r = 0; r < 4; r++) mean[r] = rs[r] * (1.0f / 128.0f);
#pragma unroll
            for (int i = 0; i < 32; i++) {
                float d = vv[i] - mean[i & 3];
                vv[i] = d;
                vs[i & 3] += d * d;
            }
#pragma unroll
            for (int m = 1; m <= 8; m <<= 1)
#pragma unroll
                for (int r = 0; r < 4; r++) vs[r] += __shfl_xor(vs[r], m, 64);
            float inv2[4];
#pragma unroll
            for (int r = 0; r < 4; r++) inv2[r] = rsqrtf(vs[r] * (1.0f / 128.0f) + 1e-5f);
            const float* gl = lng + l * 128;
            const float* bl = lnb + l * 128;
            if (l < 2) {
#pragma unroll
                for (int tt = 0; tt < 8; tt++) {
                    int c = tt * 16 + col;
                    float gc = gl[c], bc = bl[c];
#pragma unroll
                    for (int r = 0; r < 4; r++) {
                        float y = vv[tt * 4 + r] * inv2[r] * gc + bc;
                        int n = w * 16 + quad * 4 + r;
                        hreg[tt * 4 + r] = y;
                        hb[n * 136 + c] = __float2bfloat16(y);
                    }
                }
            } else {                          // final: z = h + pos, transposed
                int b = bt >> 5, t_ = bt & 31;
#pragma unroll
                for (int tt = 0; tt < 8; tt++) {
                    int c = tt * 16 + col;
                    float gc = gl[c], bc = bl[c], pc = tpos[t_ * 128 + c];
#pragma unroll
                    for (int r = 0; r < 4; r++) {
                        float y = vv[tt * 4 + r] * inv2[r] * gc + bc;
                        int n = w * 16 + quad * 4 + r;
                        z32g[((size_t)(b * 64 + n) * 32 + t_) * 128 + c] = y + pc;
                    }
                }
            }
        }
        __syncthreads();                     // B4: layer complete
    }
}

// ---------------------------------------------------------------------------
// FUSED 3-layer temporal stack. One block per (b,n) sequence, 256 thr = 4 waves.
// MFMA causal attention with P hi/lo split. Writes zlastb (bf16 row t=31).
__global__ __launch_bounds__(256, 2)
void k_temporal3(const float* __restrict__ z32g,
                 const short8* __restrict__ BpQKV, const short8* __restrict__ BpWO,
                 const short8* __restrict__ BpW1, const short8* __restrict__ BpW2,
                 const float* __restrict__ bqkv, const float* __restrict__ bo,
                 const float* __restrict__ ln1g, const float* __restrict__ ln1b,
                 const float* __restrict__ b1, const float* __restrict__ b2,
                 const float* __restrict__ ln2g, const float* __restrict__ ln2b,
                 bf16* __restrict__ zlastb) {
    __shared__ short smem[31488];            // 62976 B
    bf16* zb  = (bf16*)smem;                 // [0,4352): 32 x 136
    bf16* qk  = (bf16*)(smem + 4352);        // [4352,12800): 32 x 264
    bf16* Ps  = (bf16*)(smem + 12800);       // [12800,22016): h*2304 + m*72
    bf16* Vt  = (bf16*)(smem + 22016);       // [22016,27136): d*40 + t
    bf16* o16 = (bf16*)(smem + 27136);       // [27136,31488): 32 x 136
    bf16* f1  = (bf16*)(smem + 4352);        // overlay qk/Ps/Vt: 32 x 520

    int bn = blockIdx.x;
    int tid = threadIdx.x;
    int lane = tid & 63, w = tid >> 6;
    int quad = lane >> 4, col = lane & 15;
    int rsel = w & 1, csel = w >> 1;
    const float scale = 0.17677669529663687f;

    for (int i = tid; i < 4096; i += 256) {
        float v = z32g[(size_t)bn * 4096 + i];
        zb[(i >> 7) * 136 + (i & 127)] = __float2bfloat16(v);
    }
    float zreg[32];
    if (w < 2) {
#pragma unroll
        for (int tt = 0; tt < 8; tt++)
#pragma unroll
            for (int r = 0; r < 4; r++)
                zreg[tt * 4 + r] = z32g[(size_t)bn * 4096 +
                                        (w * 16 + quad * 4 + r) * 128 + tt * 16 + col];
    }
    __syncthreads();

    for (int l = 0; l < 3; l++) {
        // ---- phase 1: qkv GEMM ----
        {
            floatx4 acc[12];
#pragma unroll
            for (int tt = 0; tt < 12; tt++) acc[tt] = (floatx4){0.f, 0.f, 0.f, 0.f};
            const short8* bpl = BpQKV + (size_t)l * 6144;
            for (int kt = 0; kt < 4; kt++) {
                short8 a = *(const short8*)&zb[(rsel * 16 + col) * 136 + kt * 32 + quad * 8];
                const short8* bp = bpl + (size_t)(kt * 24 + csel * 12) * 64 + lane;
#pragma unroll
                for (int tt = 0; tt < 12; tt++)
                    acc[tt] = __builtin_amdgcn_mfma_f32_16x16x32_bf16(a, bp[tt * 64], acc[tt], 0, 0, 0);
            }
            const float* bias = bqkv + l * 384;
#pragma unroll
            for (int tt = 0; tt < 12; tt++) {
                int c = csel * 192 + tt * 16 + col;
                float bv = bias[c];
#pragma unroll
                for (int r = 0; r < 4; r++) {
                    int row = rsel * 16 + quad * 4 + r;
                    bf16 v = __float2bfloat16(acc[tt][r] + bv);
                    if (c < 256) qk[row * 264 + c] = v;
                    else         Vt[(c - 256) * 40 + row] = v;
                }
            }
        }
        __syncthreads();                     // B1
        // ---- phase 2: causal attention, wave = head ----
        {
            int h = w, hoff = h * 32;
            bf16* PsH = Ps + h * 2304;
            float s[2][2][4];
            short8 aA[2], bB[2];
#pragma unroll
            for (int mt = 0; mt < 2; mt++)
                aA[mt] = *(const short8*)&qk[(mt * 16 + col) * 264 + hoff + quad * 8];
#pragma unroll
            for (int nt = 0; nt < 2; nt++)
                bB[nt] = *(const short8*)&qk[(nt * 16 + col) * 264 + 128 + hoff + quad * 8];
#pragma unroll
            for (int mt = 0; mt < 2; mt++)
#pragma unroll
                for (int nt = 0; nt < 2; nt++) {
                    floatx4 acc = (floatx4){0.f, 0.f, 0.f, 0.f};
                    acc = __builtin_amdgcn_mfma_f32_16x16x32_bf16(aA[mt], bB[nt], acc, 0, 0, 0);
#pragma unroll
                    for (int r = 0; r < 4; r++) s[mt][nt][r] = acc[r];
                }
            float inv[2][4];
#pragma unroll
            for (int mt = 0; mt < 2; mt++)
#pragma unroll
                for (int r = 0; r < 4; r++) {
                    int m = mt * 16 + quad * 4 + r;
                    float rmax = -1e30f;
#pragma unroll
                    for (int nt = 0; nt < 2; nt++) {
                        int n = nt * 16 + col;
                        float al = (n > m) ? -1e30f : s[mt][nt][r] * scale;
                        s[mt][nt][r] = al;
                        rmax = fmaxf(rmax, al);
                    }
#pragma unroll
                    for (int mk2 = 1; mk2 <= 8; mk2 <<= 1)
                        rmax = fmaxf(rmax, __shfl_xor(rmax, mk2, 64));
                    float lsum = 0.f;
#pragma unroll
                    for (int nt = 0; nt < 2; nt++) {
                        float p = __expf(s[mt][nt][r] - rmax);
                        s[mt][nt][r] = p;
                        lsum += p;
                    }
#pragma unroll
                    for (int mk2 = 1; mk2 <= 8; mk2 <<= 1)
                        lsum += __shfl_xor(lsum, mk2, 64);
                    inv[mt][r] = 1.0f / lsum;
                }
            // P hi/lo stores (wave-local)
#pragma unroll
            for (int mt = 0; mt < 2; mt++)
#pragma unroll
                for (int nt = 0; nt < 2; nt++) {
                    int n = nt * 16 + col;
                    int base0 = (mt * 16 + quad * 4) * 72 + ((n >> 3) * 2) * 8 + (n & 7);
#pragma unroll
                    for (int r = 0; r < 4; r++) {
                        float p_ = s[mt][nt][r];
                        bf16 hi = __float2bfloat16(p_);
                        bf16 lo = __float2bfloat16(p_ - bfbits2f(*(short*)&hi));
                        PsH[base0 + r * 72] = hi;
                        PsH[base0 + r * 72 + 8] = lo;
                    }
                }
            // PV (hi + lo)
            floatx4 oacc[2][2];
#pragma unroll
            for (int mt = 0; mt < 2; mt++)
#pragma unroll
                for (int nt = 0; nt < 2; nt++) oacc[mt][nt] = (floatx4){0.f, 0.f, 0.f, 0.f};
            short8 aPh[2], aPl[2], bV[2];
#pragma unroll
            for (int mt = 0; mt < 2; mt++) {
                int rb = (mt * 16 + col) * 72 + quad * 16;
                aPh[mt] = *(const short8*)&PsH[rb];
                aPl[mt] = *(const short8*)&PsH[rb + 8];
            }
#pragma unroll
            for (int nt = 0; nt < 2; nt++)
                bV[nt] = *(const short8*)&Vt[(hoff + nt * 16 + col) * 40 + quad * 8];
#pragma unroll
            for (int mt = 0; mt < 2; mt++)
#pragma unroll
                for (int nt = 0; nt < 2; nt++) {
                    oacc[mt][nt] = __builtin_amdgcn_mfma_f32_16x16x32_bf16(aPh[mt], bV[nt], oacc[mt][nt], 0, 0, 0);
                    oacc[mt][nt] = __builtin_amdgcn_mfma_f32_16x16x32_bf16(aPl[mt], bV[nt], oacc[mt][nt], 0, 0, 0);
                }
#pragma unroll
            for (int mt = 0; mt < 2; mt++)
#pragma unroll
                for (int nt = 0; nt < 2; nt++) {
                    int c = hoff + nt * 16 + col;
#pragma unroll
                    for (int r = 0; r < 4; r++)
                        o16[(mt * 16 + quad * 4 + r) * 136 + c] =
                            __float2bfloat16(oacc[mt][nt][r] * inv[mt][r]);
                }
        }
        __syncthreads();                     // B2
        // ---- Wo GEMM + residual + LN1 (waves 0/1) ----
        if (w < 2) {
            floatx4 acc2[8];
#pragma unroll
            for (int tt = 0; tt < 8; tt++) acc2[tt] = (floatx4){0.f, 0.f, 0.f, 0.f};
            const short8* bpl = BpWO + (size_t)l * 2048;
            for (int kt = 0; kt < 4; kt++) {
                short8 a = *(const short8*)&o16[(w * 16 + col) * 136 + kt * 32 + quad * 8];
                const short8* bp = bpl + (size_t)(kt * 8) * 64 + lane;
#pragma unroll
                for (int tt = 0; tt < 8; tt++)
                    acc2[tt] = __builtin_amdgcn_mfma_f32_16x16x32_bf16(a, bp[tt * 64], acc2[tt], 0, 0, 0);
            }
            const float* bol = bo + l * 128;
            float vv[32], rs[4] = {0.f, 0.f, 0.f, 0.f};
#pragma unroll
            for (int tt = 0; tt < 8; tt++) {
                int c = tt * 16 + col;
                float bv = bol[c];
#pragma unroll
                for (int r = 0; r < 4; r++) {
                    float v = acc2[tt][r] + bv + zreg[tt * 4 + r];
                    vv[tt * 4 + r] = v;
                    rs[r] += v;
                }
            }
#pragma unroll
            for (int m = 1; m <= 8; m <<= 1)
#pragma unroll
                for (int r = 0; r < 4; r++) rs[r] += __shfl_xor(rs[r], m, 64);
            float mean[4], vs[4] = {0.f, 0.f, 0.f, 0.f};
#pragma unroll
            for (int r = 0; r < 4; r++) mean[r] = rs[r] * (1.0f / 128.0f);
#pragma unroll
            for (int i = 0; i < 32; i++) {
                float d = vv[i] - mean[i & 3];
                vv[i] = d;
                vs[i & 3] += d * d;
            }
#pragma unroll
            for (int m = 1; m <= 8; m <<= 1)
#pragma unroll
                for (int r = 0; r < 4; r++) vs[r] += __shfl_xor(vs[r], m, 64);
            float inv2[4];
#pragma unroll
            for (int r = 0; r < 4; r++) inv2[r] = rsqrtf(vs[r] * (1.0f / 128.0f) + 1e-5f);
            const float* gl = ln1g + l * 128;
            const float* bl = ln1b + l * 128;
#pragma unroll
            for (int tt = 0; tt < 8; tt++) {
                int c = tt * 16 + col;
                float gc = gl[c], bc = bl[c];
#pragma unroll
                for (int r = 0; r < 4; r++) {
                    float y = vv[tt * 4 + r] * inv2[r] * gc + bc;
                    int row = w * 16 + quad * 4 + r;
                    zreg[tt * 4 + r] = y;
                    zb[row * 136 + c] = __float2bfloat16(y);
                }
            }
        }
        __syncthreads();                     // B3
        // ---- W1 GEMM + gelu (all 4 waves) -> f1 ----
        {
            floatx4 acc3[16];
#pragma unroll
            for (int tt = 0; tt < 16; tt++) acc3[tt] = (floatx4){0.f, 0.f, 0.f, 0.f};
            const short8* bpl = BpW1 + (size_t)l * 8192;
            for (int kt = 0; kt < 4; kt++) {
                short8 a = *(const short8*)&zb[(rsel * 16 + col) * 136 + kt * 32 + quad * 8];
                const short8* bp = bpl + (size_t)(kt * 32 + csel * 16) * 64 + lane;
#pragma unroll
                for (int tt = 0; tt < 16; tt++)
                    acc3[tt] = __builtin_amdgcn_mfma_f32_16x16x32_bf16(a, bp[tt * 64], acc3[tt], 0, 0, 0);
            }
            const float* b1l = b1 + l * 512;
#pragma unroll
            for (int tt = 0; tt < 16; tt++) {
                int c = csel * 256 + tt * 16 + col;
                float bv = b1l[c];
#pragma unroll
                for (int r = 0; r < 4; r++) {
                    float v = gelu_exact(acc3[tt][r] + bv);
                    f1[(rsel * 16 + quad * 4 + r) * 520 + c] = __float2bfloat16(v);
                }
            }
        }
        __syncthreads();                     // B4
        // ---- W2 GEMM + residual + LN2 (waves 0/1) ----
        if (w < 2) {
            floatx4 acc4[8];
#pragma unroll
            for (int tt = 0; tt < 8; tt++) acc4[tt] = (floatx4){0.f, 0.f, 0.f, 0.f};
            const short8* bpl = BpW2 + (size_t)l * 8192;
            for (int kt = 0; kt < 16; kt++) {
                short8 a = *(const short8*)&f1[(w * 16 + col) * 520 + kt * 32 + quad * 8];
                const short8* bp = bpl + (size_t)(kt * 8) * 64 + lane;
#pragma unroll
                for (int tt = 0; tt < 8; tt++)
                    acc4[tt] = __builtin_amdgcn_mfma_f32_16x16x32_bf16(a, bp[tt * 64], acc4[tt], 0, 0, 0);
            }
            const float* b2l = b2 + l * 128;
            float vv[32], rs[4] = {0.f, 0.f, 0.f, 0.f};
#pragma unroll
            for (int tt = 0; tt < 8; tt++) {
                int c = tt * 16 + col;
                float bv = b2l[c];
#pragma unroll
                for (int r = 0; r < 4; r++) {
                    float v = acc4[tt][r] + bv + zreg[tt * 4 + r];
                    vv[tt * 4 + r] = v;
                    rs[r] += v;
                }
            }
#pragma unroll
            for (int m = 1; m <= 8; m <<= 1)
#pragma unroll
                for (int r = 0; r < 4; r++) rs[r] += __shfl_xor(rs[r], m, 64);
            float mean[4], vs[4] = {0.f, 0.f, 0.f, 0.f};
#pragma unroll
            for (int r = 0; r < 4; r++) mean[r] = rs[r] * (1.0f / 128.0f);
#pragma unroll
            for (int i = 0; i < 32; i++) {
                float d = vv[i] - mean[i & 3];
                vv[i] = d;
                vs[i & 3] += d * d;
            }
#pragma unroll
            for (int m = 1; m <= 8; m <<= 1)
#pragma unroll
                for (int r = 0; r < 4; r++) vs[r] += __shfl_xor(vs[r], m, 64);
            float inv2[4];
#pragma unroll
            for (int r = 0; r < 4; r++) inv2[r] = rsqrtf(vs[r] * (1.0f / 128.0f) + 1e-5f);
            const float* gl = ln2g + l * 128;
            const float* bl = ln2b + l * 128;
#pragma unroll
            for (int tt = 0; tt < 8; tt++) {
                int c = tt * 16 + col;
                float gc = gl[c], bc = bl[c];
#pragma unroll
                for (int r = 0; r < 4; r++) {
                    float y = vv[tt * 4 + r] * inv2[r] * gc + bc;
                    int row = w * 16 + quad * 4 + r;
                    zreg[tt * 4 + r] = y;
                    if (l < 2) zb[row * 136 + c] = __float2bfloat16(y);
                    else if (row == 31) zlastb[(size_t)bn * 128 + c] = __float2bfloat16(y);
                }
            }
        }
        __syncthreads();                     // B5
    }
}

// ---------------------------------------------------------------------------
// Head (MFMA): out = gelu(zlast @ W1 + b1) @ W2 + b2. Grid 8 x 256 thr.
__global__ __launch_bounds__(256)
void k_head(const bf16* __restrict__ zlastb, const short8* __restrict__ BpHW1,
            const float* __restrict__ b1, const float* __restrict__ W2,
            const float* __restrict__ b2, float* __restrict__ out) {
    __shared__ bf16 h1[64 * 136];
    int blk = blockIdx.x;
    int tid = threadIdx.x;
    int lane = tid & 63, w = tid >> 6;
    int quad = lane >> 4, col = lane & 15;
    {
        floatx4 acc[8];
#pragma unroll
        for (int tt = 0; tt < 8; tt++) acc[tt] = (floatx4){0.f, 0.f, 0.f, 0.f};
        const short8* Ap = (const short8*)(zlastb + (size_t)(blk * 64 + w * 16 + col) * 128) + quad;
        for (int kt = 0; kt < 4; kt++) {
            short8 a = Ap[kt * 4];
            const short8* bp = BpHW1 + (size_t)(kt * 8) * 64 + lane;
#pragma unroll
            for (int tt = 0; tt < 8; tt++)
                acc[tt] = __builtin_amdgcn_mfma_f32_16x16x32_bf16(a, bp[tt * 64], acc[tt], 0, 0, 0);
        }
#pragma unroll
        for (int tt = 0; tt < 8; tt++) {
            int c = tt * 16 + col;
            float bv = b1[c];
#pragma unroll
            for (int r = 0; r < 4; r++)
                h1[(w * 16 + quad * 4 + r) * 136 + c] = __float2bfloat16(gelu_exact(acc[tt][r] + bv));
        }
    }
    __syncthreads();
    for (int idx = tid; idx < 512; idx += 256) {
        int row = idx >> 3, c = idx & 7;
        if (c < 6) {
            float a0 = 0.f, a1 = 0.f, a2 = 0.f, a3 = 0.f;
            const bf16* hr = &h1[row * 136];
#pragma unroll 8
            for (int k = 0; k < 128; k += 4) {
                a0 = fmaf(bfbits2f(*(const short*)&hr[k]),     W2[k * 6 + c], a0);
                a1 = fmaf(bfbits2f(*(const short*)&hr[k + 1]), W2[(k + 1) * 6 + c], a1);
                a2 = fmaf(bfbits2f(*(const short*)&hr[k + 2]), W2[(k + 2) * 6 + c], a2);
                a3 = fmaf(bfbits2f(*(const short*)&hr[k + 3]), W2[(k + 3) * 6 + c], a3);
            }
            out[(size_t)(blk * 64 + row) * 6 + c] = (a0 + a1) + (a2 + a3) + b2[c];
        }
    }
}

// ---------------------------------------------------------------------------
extern "C" void kernel_launch(void* const* d_in, const int* in_sizes, int n_in,
                              void* d_out, int out_size, void* d_ws, size_t ws_size,
                              hipStream_t stream) {
    const float* input_frames = (const float*)d_in[0];
    const float* edge_attr    = (const float*)d_in[1];
    const float* proj_W  = (const float*)d_in[2];
    const float* proj_b  = (const float*)d_in[3];
    const float* sp_Wq   = (const float*)d_in[4];
    const float* sp_bq   = (const float*)d_in[5];
    const float* sp_Wk   = (const float*)d_in[6];
    const float* sp_bk   = (const float*)d_in[7];
    const float* sp_Wv   = (const float*)d_in[8];
    const float* sp_bv   = (const float*)d_in[9];
    const float* sp_We   = (const float*)d_in[10];
    const float* sp_be   = (const float*)d_in[11];
    const float* sp_Ws   = (const float*)d_in[12];
    const float* sp_bs   = (const float*)d_in[13];
    const float* sp_lng  = (const float*)d_in[14];
    const float* sp_lnb  = (const float*)d_in[15];
    const float* tpos    = (const float*)d_in[16];
    const float* t_Wqkv  = (const float*)d_in[17];
    const float* t_bqkv  = (const float*)d_in[18];
    const float* t_Wo    = (const float*)d_in[19];
    const float* t_bo    = (const float*)d_in[20];
    const float* t_ln1g  = (const float*)d_in[21];
    const float* t_ln1b  = (const float*)d_in[22];
    const float* t_W1    = (const float*)d_in[23];
    const float* t_b1    = (const float*)d_in[24];
    const float* t_W2    = (const float*)d_in[25];
    const float* t_b2    = (const float*)d_in[26];
    const float* t_ln2g  = (const float*)d_in[27];
    const float* t_ln2b  = (const float*)d_in[28];
    const float* head_W1 = (const float*)d_in[29];
    const float* head_b1 = (const float*)d_in[30];
    const float* head_W2 = (const float*)d_in[31];
    const float* head_b2 = (const float*)d_in[32];

    float* f     = (float*)d_ws;
    float* z32g  = f;                                  // 2M floats
    bf16*  zlastb = (bf16*)(f + (1u << 21));           // 64K bf16
    float* spb   = f + (1u << 21) + 65536;             // 1152 floats
    bf16* BpBase = (bf16*)(f + (1u << 21) + 65536 + 2048);
    bf16* BpSPQKV = BpBase;                            // 147456 bf16
    bf16* BpWS    = BpSPQKV + 147456;                  //  49152
    bf16* BpTQKV  = BpWS + 49152;                      // 147456
    bf16* BpWO    = BpTQKV + 147456;                   //  49152
    bf16* BpW1    = BpWO + 49152;                      // 196608
    bf16* BpW2    = BpW1 + 196608;                     // 196608
    bf16* BpHW1   = BpW2 + 196608;                     //  16384

    RepackArgs ra;
    int s = 0;
    auto mk = [&](int i, const float* W, bf16* out, int K, int N, int ntt, int ntoff, int L) {
        ra.d[i] = {W, out, K, N, ntt, ntoff, L, s};
        s += L * (K >> 5) * (N >> 4) * 64;
    };
    mk(0, sp_Wq, BpSPQKV, 128, 128, 24, 0, 3);
    mk(1, sp_Wk, BpSPQKV, 128, 128, 24, 8, 3);
    mk(2, sp_Wv, BpSPQKV, 128, 128, 24, 16, 3);
    mk(3, sp_Ws, BpWS, 128, 128, 8, 0, 3);
    mk(4, t_Wqkv, BpTQKV, 128, 384, 24, 0, 3);
    mk(5, t_Wo, BpWO, 128, 128, 8, 0, 3);
    mk(6, t_W1, BpW1, 128, 512, 32, 0, 3);
    mk(7, t_W2, BpW2, 512, 128, 8, 0, 3);
    mk(8, head_W1, BpHW1, 128, 128, 8, 0, 1);
    ra.total = s;
    k_repack<<<(s + 255) / 256, 256, 0, stream>>>(ra);
    k_packbias<<<(3 * 384 + 255) / 256, 256, 0, stream>>>(sp_bq, sp_bk, sp_bv, spb);

    k_spatial3<<<BT_, 512, 0, stream>>>(
        input_frames, proj_W, proj_b,
        (const short8*)BpSPQKV, (const short8*)BpWS,
        spb, sp_bs, sp_lng, sp_lnb, edge_attr, sp_We, sp_be, tpos, z32g);

    k_temporal3<<<BN_, 256, 0, stream>>>(
        z32g, (const short8*)BpTQKV, (const short8*)BpWO,
        (const short8*)BpW1, (const short8*)BpW2,
        t_bqkv, t_bo, t_ln1g, t_ln1b, t_b1, t_b2, t_ln2g, t_ln2b, zlastb);

    k_head<<<8, 256, 0, stream>>>(zlastb, (const short8*)BpHW1, head_b1,
                                  head_W2, head_b2, (float*)d_out);
}

// Round 8
// 285.252 us; speedup vs baseline: 7.2144x; 1.0148x over previous
//
#include <hip/hip_runtime.h>
#include <hip/hip_bf16.h>
#include <math.h>

typedef __hip_bfloat16 bf16;
typedef short short8 __attribute__((ext_vector_type(8)));
typedef float floatx4 __attribute__((ext_vector_type(4)));

#define B_    8
#define T_    32
#define N_    64
#define F_    6
#define D_    128
#define E_    4032      // N*(N-1)
#define BT_   256       // B*T
#define BN_   512       // B*N

__device__ __forceinline__ float gelu_exact(float x) {
    return 0.5f * x * (1.0f + erff(x * 0.70710678118654752f));
}
__device__ __forceinline__ float bfbits2f(short s) {
    unsigned int u = ((unsigned int)(unsigned short)s) << 16;
    return __uint_as_float(u);
}
// load 32 consecutive bf16 from LDS (16B-aligned) as fp32
__device__ __forceinline__ void ld32lds(const bf16* p, float* o) {
    const short8* sp = (const short8*)p;
#pragma unroll
    for (int i = 0; i < 4; i++) {
        short8 s = sp[i];
#pragma unroll
        for (int j = 0; j < 8; j++) o[i * 8 + j] = bfbits2f(s[j]);
    }
}

// ---------------------------------------------------------------------------
// Repack weights (fp32, row-major KxN, L layers) into MFMA B-fragment layout.
struct RepackDesc { const float* W; bf16* out; int K, N, ntt, ntoff, L, start; };
struct RepackArgs { RepackDesc d[9]; int total; };

__global__ void k_repack(RepackArgs ra) {
    int gid = blockIdx.x * blockDim.x + threadIdx.x;
    if (gid >= ra.total) return;
    int fi = 0;
    while (fi < 8 && gid >= ra.d[fi + 1].start) fi++;
    RepackDesc dd = ra.d[fi];
    int r = gid - dd.start;
    int lane = r & 63; r >>= 6;
    int ntiles = dd.N >> 4;
    int nt = r % ntiles; r /= ntiles;
    int ktiles = dd.K >> 5;
    int kt = r % ktiles;
    int l = r / ktiles;
    int quad = lane >> 4, cc = lane & 15;
    const float* Wl = dd.W + (size_t)l * dd.K * dd.N;
    bf16* o = dd.out + ((((size_t)l * ktiles + kt) * dd.ntt + nt + dd.ntoff) * 64 + lane) * 8;
    int kb = kt * 32 + quad * 8;
    int n = nt * 16 + cc;
#pragma unroll
    for (int j = 0; j < 8; j++)
        o[j] = __float2bfloat16(Wl[(size_t)(kb + j) * dd.N + n]);
}

__global__ void k_packbias(const float* __restrict__ bq, const float* __restrict__ bk,
                           const float* __restrict__ bv, float* __restrict__ out) {
    int i = blockIdx.x * blockDim.x + threadIdx.x;
    if (i >= 3 * 384) return;
    int l = i / 384, c = i % 384;
    float v = (c < 128) ? bq[l * 128 + c]
            : (c < 256) ? bk[l * 128 + c - 128]
                        : bv[l * 128 + c - 256];
    out[i] = v;
}

// ---------------------------------------------------------------------------
// FUSED 3-layer spatial stack. One block per (b,t) graph, 512 thr = 8 waves.
// Padded LDS strides (conflict-free), EAs staged in LDS, P hi/lo split PV.
__global__ __launch_bounds__(512, 1)
void k_spatial3(const float* __restrict__ inp, const float* __restrict__ projW,
                const float* __restrict__ projB,
                const short8* __restrict__ BpQKV, const short8* __restrict__ BpWS,
                const float* __restrict__ spb, const float* __restrict__ bs,
                const float* __restrict__ lng, const float* __restrict__ lnb,
                const float* __restrict__ ea, const float* __restrict__ Weg,
                const float* __restrict__ beg, const float* __restrict__ tpos,
                float* __restrict__ z32g) {
    __shared__ short smem[61312];            // 122624 B
    bf16* hb = (bf16*)smem;                  // [0,8704): 64 x 136
    bf16* qk = (bf16*)(smem + 8704);         // 64 x 264 (q|k)
    float* aggf = (float*)(smem + 8704);     // overlay qk: 64 x 128 fp32
    float* fsm = (float*)(smem + 8704);      // overlay qk: proj staging
    bf16* Vt = (bf16*)(smem + 25600);        // 128 x 72 (d-major)
    bf16* Ps = (bf16*)(smem + 34816);        // h*4608 + m*72
    float* EAs = (float*)(smem + 53248);     // 4032 fp32

    int bt = blockIdx.x;
    int tid = threadIdx.x;
    int lane = tid & 63, w = tid >> 6;
    int quad = lane >> 4, col = lane & 15;
    int w4 = w & 3, wh = w >> 2;
    const float scale = 0.17677669529663687f;   // 1/sqrt(32)

    for (int i = tid; i < 896; i += 512)
        fsm[i] = (i < 768) ? projW[i] : projB[i - 768];
    {
        const float* eag = ea + (size_t)bt * E_;
        for (int i = tid; i < E_; i += 512) EAs[i] = eag[i];
    }
    __syncthreads();
    float hreg[32];
    if (w < 4) {
#pragma unroll
        for (int r = 0; r < 4; r++) {
            int n = w * 16 + quad * 4 + r;
            const float* xr = inp + (size_t)(bt * 64 + n) * F_;
            float xin[6];
#pragma unroll
            for (int k2 = 0; k2 < 6; k2++) xin[k2] = xr[k2];
#pragma unroll
            for (int tt = 0; tt < 8; tt++) {
                int c = tt * 16 + col;
                float a = fsm[768 + c];
#pragma unroll
                for (int k2 = 0; k2 < 6; k2++) a = fmaf(xin[k2], fsm[k2 * 128 + c], a);
                hreg[tt * 4 + r] = a;
                hb[n * 136 + c] = __float2bfloat16(a);
            }
        }
    }
    __syncthreads();                         // B0

    for (int l = 0; l < 3; l++) {
        // ---- phase 1: qkv GEMM ----
        {
            floatx4 acc[12];
#pragma unroll
            for (int tt = 0; tt < 12; tt++) acc[tt] = (floatx4){0.f, 0.f, 0.f, 0.f};
            const short8* bpl = BpQKV + (size_t)l * 6144;
            for (int kt = 0; kt < 4; kt++) {
                short8 a = *(const short8*)&hb[(w4 * 16 + col) * 136 + kt * 32 + quad * 8];
                const short8* bp = bpl + (size_t)(kt * 24 + wh * 12) * 64 + lane;
#pragma unroll
                for (int tt = 0; tt < 12; tt++)
                    acc[tt] = __builtin_amdgcn_mfma_f32_16x16x32_bf16(a, bp[tt * 64], acc[tt], 0, 0, 0);
            }
            const float* bias = spb + l * 384;
#pragma unroll
            for (int tt = 0; tt < 12; tt++) {
                int c = wh * 192 + tt * 16 + col;
                float bv = bias[c];
#pragma unroll
                for (int r = 0; r < 4; r++) {
                    int row = w4 * 16 + quad * 4 + r;
                    bf16 v = __float2bfloat16(acc[tt][r] + bv);
                    if (c < 256) qk[row * 264 + c] = v;
                    else         Vt[(c - 256) * 72 + row] = v;
                }
            }
        }
        __syncthreads();                     // B1
        // ---- phase 2: attention. wave=(h=w4, rowhalf=wh) ----
        int h = w4, half = wh;
        int hoff = h * 32;
        const float* Wel = Weg + l * 128 + hoff;
        const float* bel = beg + l * 128 + hoff;
        float qWe;
        {
            int dst = half * 32 + (lane & 31);
            float qr[32];
            ld32lds(&qk[dst * 264 + hoff], qr);
            float s0 = 0.f, s1 = 0.f, s2 = 0.f, s3 = 0.f;
#pragma unroll
            for (int c2 = 0; c2 < 32; c2 += 4) {
                s0 = fmaf(qr[c2], Wel[c2], s0);
                s1 = fmaf(qr[c2 + 1], Wel[c2 + 1], s1);
                s2 = fmaf(qr[c2 + 2], Wel[c2 + 2], s2);
                s3 = fmaf(qr[c2 + 3], Wel[c2 + 3], s3);
            }
            qWe = (s0 + s1) + (s2 + s3);
        }
        float s[2][4][4], ev[2][4][4];
        {
            short8 aA[2], bB[4];
#pragma unroll
            for (int mtl = 0; mtl < 2; mtl++)
                aA[mtl] = *(const short8*)&qk[((half * 2 + mtl) * 16 + col) * 264 + hoff + quad * 8];
#pragma unroll
            for (int nt = 0; nt < 4; nt++)
                bB[nt] = *(const short8*)&qk[(nt * 16 + col) * 264 + 128 + hoff + quad * 8];
#pragma unroll
            for (int mtl = 0; mtl < 2; mtl++)
#pragma unroll
                for (int nt = 0; nt < 4; nt++) {
                    floatx4 acc = (floatx4){0.f, 0.f, 0.f, 0.f};
                    acc = __builtin_amdgcn_mfma_f32_16x16x32_bf16(aA[mtl], bB[nt], acc, 0, 0, 0);
#pragma unroll
                    for (int r = 0; r < 4; r++) s[mtl][nt][r] = acc[r];
                }
        }
        __syncthreads();                     // B2
        float ls[2][4], ae[2][4], inv[2][4];
#pragma unroll
        for (int mtl = 0; mtl < 2; mtl++)
#pragma unroll
            for (int r = 0; r < 4; r++) {
                int m = half * 32 + mtl * 16 + quad * 4 + r;
                float qWeR = __shfl(qWe, mtl * 16 + quad * 4 + r, 64);
                float rmax = -1e30f;
#pragma unroll
                for (int nt = 0; nt < 4; nt++) {
                    int n = nt * 16 + col;
                    bool diag = (m == n);
                    int eid = diag ? 0 : (n * 63 + m - (m > n ? 1 : 0));
                    float eav = diag ? 0.f : EAs[eid];
                    ev[mtl][nt][r] = eav;
                    float al = diag ? -1e30f
                                    : scale * (s[mtl][nt][r] + eav * qWeR);
                    s[mtl][nt][r] = al;
                    rmax = fmaxf(rmax, al);
                }
#pragma unroll
                for (int mk2 = 1; mk2 <= 8; mk2 <<= 1)
                    rmax = fmaxf(rmax, __shfl_xor(rmax, mk2, 64));
                float lsum = 0.f, aesum = 0.f;
#pragma unroll
                for (int nt = 0; nt < 4; nt++) {
                    float p = __expf(s[mtl][nt][r] - rmax);
                    s[mtl][nt][r] = p;
                    lsum += p;
                    aesum = fmaf(p, ev[mtl][nt][r], aesum);
                }
#pragma unroll
                for (int mk2 = 1; mk2 <= 8; mk2 <<= 1) {
                    lsum += __shfl_xor(lsum, mk2, 64);
                    aesum += __shfl_xor(aesum, mk2, 64);
                }
                ls[mtl][r] = lsum;
                ae[mtl][r] = aesum;
                inv[mtl][r] = 1.0f / lsum;
            }
        bf16* PsH = Ps + h * 4608;
        floatx4 oacc[2][2];
#pragma unroll
        for (int mtl = 0; mtl < 2; mtl++)
#pragma unroll
            for (int ntB = 0; ntB < 2; ntB++) oacc[mtl][ntB] = (floatx4){0.f, 0.f, 0.f, 0.f};
#pragma unroll
        for (int p = 0; p < 2; p++) {
#pragma unroll
            for (int mtl = 0; mtl < 2; mtl++)
#pragma unroll
                for (int q2 = 0; q2 < 2; q2++) {
                    int nl = q2 * 16 + col;
                    int base0 = (half * 32 + mtl * 16 + quad * 4) * 72 + ((nl >> 3) * 2) * 8 + (nl & 7);
#pragma unroll
                    for (int r = 0; r < 4; r++) {
                        float p_ = s[mtl][2 * p + q2][r];
                        bf16 hi = __float2bfloat16(p_);
                        bf16 lo = __float2bfloat16(p_ - bfbits2f(*(short*)&hi));
                        PsH[base0 + r * 72] = hi;
                        PsH[base0 + r * 72 + 8] = lo;
                    }
                }
            short8 aPh[2], aPl[2], bV[2];
#pragma unroll
            for (int mtl = 0; mtl < 2; mtl++) {
                int rb = (half * 32 + mtl * 16 + col) * 72 + quad * 16;
                aPh[mtl] = *(const short8*)&PsH[rb];
                aPl[mtl] = *(const short8*)&PsH[rb + 8];
            }
#pragma unroll
            for (int ntB = 0; ntB < 2; ntB++)
                bV[ntB] = *(const short8*)&Vt[(hoff + ntB * 16 + col) * 72 + p * 32 + quad * 8];
#pragma unroll
            for (int mtl = 0; mtl < 2; mtl++)
#pragma unroll
                for (int ntB = 0; ntB < 2; ntB++) {
                    oacc[mtl][ntB] = __builtin_amdgcn_mfma_f32_16x16x32_bf16(aPh[mtl], bV[ntB], oacc[mtl][ntB], 0, 0, 0);
                    oacc[mtl][ntB] = __builtin_amdgcn_mfma_f32_16x16x32_bf16(aPl[mtl], bV[ntB], oacc[mtl][ntB], 0, 0, 0);
                }
        }
#pragma unroll
        for (int mtl = 0; mtl < 2; mtl++)
#pragma unroll
            for (int ntB = 0; ntB < 2; ntB++) {
                int c = hoff + ntB * 16 + col;
                float Wc = Wel[ntB * 16 + col];
                float bc = bel[ntB * 16 + col];
#pragma unroll
                for (int r = 0; r < 4; r++) {
                    int m = half * 32 + mtl * 16 + quad * 4 + r;
                    aggf[m * 128 + c] = fmaf(fmaf(ae[mtl][r], Wc, oacc[mtl][ntB][r]),
                                             inv[mtl][r], bc);
                }
            }
        __syncthreads();                     // B3
        // ---- epilogue: Ws GEMM + agg + residual + LN (waves 0-3) ----
        if (w < 4) {
            floatx4 acc2[8];
#pragma unroll
            for (int tt = 0; tt < 8; tt++) acc2[tt] = (floatx4){0.f, 0.f, 0.f, 0.f};
            const short8* bpl = BpWS + (size_t)l * 2048;
            for (int kt = 0; kt < 4; kt++) {
                short8 a = *(const short8*)&hb[(w * 16 + col) * 136 + kt * 32 + quad * 8];
                const short8* bp = bpl + (size_t)(kt * 8) * 64 + lane;
#pragma unroll
                for (int tt = 0; tt < 8; tt++)
                    acc2[tt] = __builtin_amdgcn_mfma_f32_16x16x32_bf16(a, bp[tt * 64], acc2[tt], 0, 0, 0);
            }
            const float* bsl = bs + l * 128;
            float vv[32], rs[4] = {0.f, 0.f, 0.f, 0.f};
#pragma unroll
            for (int tt = 0; tt < 8; tt++) {
                int c = tt * 16 + col;
                float bv = bsl[c];
#pragma unroll
                for (int r = 0; r < 4; r++) {
                    int row = w * 16 + quad * 4 + r;
                    float v = acc2[tt][r] + bv + aggf[row * 128 + c] + hreg[tt * 4 + r];
                    vv[tt * 4 + r] = v;
                    rs[r] += v;
                }
            }
#pragma unroll
            for (int m = 1; m <= 8; m <<= 1)
#pragma unroll
                for (int r = 0; r < 4; r++) rs[r] += __shfl_xor(rs[r], m, 64);
            float mean[4], vs[4] = {0.f, 0.f, 0.f, 0.f};
#pragma unroll
            for (int r = 0; r < 4; r++) mean[r] = rs[r] * (1.0f / 128.0f);
#pragma unroll
            for (int i = 0; i < 32; i++) {
                float d = vv[i] - mean[i & 3];
                vv[i] = d;
                vs[i & 3] += d * d;
            }
#pragma unroll
            for (int m = 1; m <= 8; m <<= 1)
#pragma unroll
                for (int r = 0; r < 4; r++) vs[r] += __shfl_xor(vs[r], m, 64);
            float inv2[4];
#pragma unroll
            for (int r = 0; r < 4; r++) inv2[r] = rsqrtf(vs[r] * (1.0f / 128.0f) + 1e-5f);
            const float* gl = lng + l * 128;
            const float* bl = lnb + l * 128;
            if (l < 2) {
#pragma unroll
                for (int tt = 0; tt < 8; tt++) {
                    int c = tt * 16 + col;
                    float gc = gl[c], bc = bl[c];
#pragma unroll
                    for (int r = 0; r < 4; r++) {
                        float y = vv[tt * 4 + r] * inv2[r] * gc + bc;
                        int n = w * 16 + quad * 4 + r;
                        hreg[tt * 4 + r] = y;
                        hb[n * 136 + c] = __float2bfloat16(y);
                    }
                }
            } else {
                int b = bt >> 5, t_ = bt & 31;
#pragma unroll
                for (int tt = 0; tt < 8; tt++) {
                    int c = tt * 16 + col;
                    float gc = gl[c], bc = bl[c], pc = tpos[t_ * 128 + c];
#pragma unroll
                    for (int r = 0; r < 4; r++) {
                        float y = vv[tt * 4 + r] * inv2[r] * gc + bc;
                        int n = w * 16 + quad * 4 + r;
                        z32g[((size_t)(b * 64 + n) * 32 + t_) * 128 + c] = y + pc;
                    }
                }
            }
        }
        __syncthreads();                     // B4
    }
}

// ---------------------------------------------------------------------------
// FUSED 3-layer temporal stack. One block per (b,n) sequence, 512 thr = 8 waves
// — ALL waves active in every phase; LN via cross-wave LDS partials.
// LDS 64000 B -> 2 blocks/CU (4 waves/SIMD).
__global__ __launch_bounds__(512, 4)
void k_temporal3(const float* __restrict__ z32g,
                 const short8* __restrict__ BpQKV, const short8* __restrict__ BpWO,
                 const short8* __restrict__ BpW1, const short8* __restrict__ BpW2,
                 const float* __restrict__ bqkv, const float* __restrict__ bo,
                 const float* __restrict__ ln1g, const float* __restrict__ ln1b,
                 const float* __restrict__ b1, const float* __restrict__ b2,
                 const float* __restrict__ ln2g, const float* __restrict__ ln2b,
                 bf16* __restrict__ zlastb) {
    __shared__ short smem[32000];            // 64000 B (short units)
    bf16* zb  = (bf16*)smem;                 // [0,4352): 32 x 136
    bf16* qk  = (bf16*)(smem + 4352);        // [4352,12800): 32 x 264
    bf16* Ps  = (bf16*)(smem + 12800);       // [12800,22016): (h*2+mh)*1152
    bf16* Vt  = (bf16*)(smem + 22016);       // [22016,27136): d*40 + t
    bf16* o16 = (bf16*)(smem + 27136);       // [27136,31488): 32 x 136
    float* lnp = (float*)(smem + 31488);     // [31488,32000): 4x32x2 fp32
    bf16* f1  = (bf16*)(smem + 4352);        // overlay qk+Ps: 32 x 520

    int bn = blockIdx.x;
    int tid = threadIdx.x;
    int lane = tid & 63, w = tid >> 6;
    int quad = lane >> 4, col = lane & 15;
    int mt = w & 1, cq = w >> 1;             // GEMM split: m-tile x col-quarter
    const float scale = 0.17677669529663687f;

    // ---- stage z ----
    for (int i = tid; i < 4096; i += 512) {
        float v = z32g[(size_t)bn * 4096 + i];
        zb[(i >> 7) * 136 + (i & 127)] = __float2bfloat16(v);
    }
    float zreg[8];                           // rows mt*16.., cols cq*32..+31
#pragma unroll
    for (int t2 = 0; t2 < 2; t2++)
#pragma unroll
        for (int r = 0; r < 4; r++)
            zreg[t2 * 4 + r] = z32g[(size_t)bn * 4096 +
                                    (mt * 16 + quad * 4 + r) * 128 + cq * 32 + t2 * 16 + col];
    __syncthreads();

    for (int l = 0; l < 3; l++) {
        // ---- phase 1: qkv GEMM. wave=(mt, nq=cq): 6 tiles of 96-col band ----
        {
            floatx4 acc[6];
#pragma unroll
            for (int tt = 0; tt < 6; tt++) acc[tt] = (floatx4){0.f, 0.f, 0.f, 0.f};
            const short8* bpl = BpQKV + (size_t)l * 6144;
            for (int kt = 0; kt < 4; kt++) {
                short8 a = *(const short8*)&zb[(mt * 16 + col) * 136 + kt * 32 + quad * 8];
                const short8* bp = bpl + (size_t)(kt * 24 + cq * 6) * 64 + lane;
#pragma unroll
                for (int tt = 0; tt < 6; tt++)
                    acc[tt] = __builtin_amdgcn_mfma_f32_16x16x32_bf16(a, bp[tt * 64], acc[tt], 0, 0, 0);
            }
            const float* bias = bqkv + l * 384;
#pragma unroll
            for (int tt = 0; tt < 6; tt++) {
                int c = cq * 96 + tt * 16 + col;
                float bv = bias[c];
#pragma unroll
                for (int r = 0; r < 4; r++) {
                    int row = mt * 16 + quad * 4 + r;
                    bf16 v = __float2bfloat16(acc[tt][r] + bv);
                    if (c < 256) qk[row * 264 + c] = v;
                    else         Vt[(c - 256) * 40 + row] = v;
                }
            }
        }
        __syncthreads();                     // B1
        // ---- phase 2: attention. wave=(h=w&3, mh=w>>2): M=16 rows ----
        {
            int h = w & 3, mh = w >> 2;
            int hoff = h * 32;
            bf16* PsH = Ps + (h * 2 + mh) * 1152;
            float s[2][4];
            short8 aA = *(const short8*)&qk[(mh * 16 + col) * 264 + hoff + quad * 8];
            short8 bB[2];
#pragma unroll
            for (int nt = 0; nt < 2; nt++)
                bB[nt] = *(const short8*)&qk[(nt * 16 + col) * 264 + 128 + hoff + quad * 8];
#pragma unroll
            for (int nt = 0; nt < 2; nt++) {
                floatx4 acc = (floatx4){0.f, 0.f, 0.f, 0.f};
                acc = __builtin_amdgcn_mfma_f32_16x16x32_bf16(aA, bB[nt], acc, 0, 0, 0);
#pragma unroll
                for (int r = 0; r < 4; r++) s[nt][r] = acc[r];
            }
            float inv[4];
#pragma unroll
            for (int r = 0; r < 4; r++) {
                int m = mh * 16 + quad * 4 + r;
                float rmax = -1e30f;
#pragma unroll
                for (int nt = 0; nt < 2; nt++) {
                    int n = nt * 16 + col;
                    float al = (n > m) ? -1e30f : s[nt][r] * scale;
                    s[nt][r] = al;
                    rmax = fmaxf(rmax, al);
                }
#pragma unroll
                for (int mk2 = 1; mk2 <= 8; mk2 <<= 1)
                    rmax = fmaxf(rmax, __shfl_xor(rmax, mk2, 64));
                float lsum = 0.f;
#pragma unroll
                for (int nt = 0; nt < 2; nt++) {
                    float p = __expf(s[nt][r] - rmax);
                    s[nt][r] = p;
                    lsum += p;
                }
#pragma unroll
                for (int mk2 = 1; mk2 <= 8; mk2 <<= 1)
                    lsum += __shfl_xor(lsum, mk2, 64);
                inv[r] = 1.0f / lsum;
            }
            // P hi/lo stores (wave-local region)
#pragma unroll
            for (int nt = 0; nt < 2; nt++) {
                int n = nt * 16 + col;
                int base0 = (quad * 4) * 72 + ((n >> 3) * 2) * 8 + (n & 7);
#pragma unroll
                for (int r = 0; r < 4; r++) {
                    float p_ = s[nt][r];
                    bf16 hi = __float2bfloat16(p_);
                    bf16 lo = __float2bfloat16(p_ - bfbits2f(*(short*)&hi));
                    PsH[base0 + r * 72] = hi;
                    PsH[base0 + r * 72 + 8] = lo;
                }
            }
            // PV (hi + lo)
            floatx4 oacc[2];
#pragma unroll
            for (int nt = 0; nt < 2; nt++) oacc[nt] = (floatx4){0.f, 0.f, 0.f, 0.f};
            short8 aPh = *(const short8*)&PsH[col * 72 + quad * 16];
            short8 aPl = *(const short8*)&PsH[col * 72 + quad * 16 + 8];
            short8 bV[2];
#pragma unroll
            for (int nt = 0; nt < 2; nt++)
                bV[nt] = *(const short8*)&Vt[(hoff + nt * 16 + col) * 40 + quad * 8];
#pragma unroll
            for (int nt = 0; nt < 2; nt++) {
                oacc[nt] = __builtin_amdgcn_mfma_f32_16x16x32_bf16(aPh, bV[nt], oacc[nt], 0, 0, 0);
                oacc[nt] = __builtin_amdgcn_mfma_f32_16x16x32_bf16(aPl, bV[nt], oacc[nt], 0, 0, 0);
            }
#pragma unroll
            for (int nt = 0; nt < 2; nt++) {
                int c = hoff + nt * 16 + col;
#pragma unroll
                for (int r = 0; r < 4; r++)
                    o16[(mh * 16 + quad * 4 + r) * 136 + c] =
                        __float2bfloat16(oacc[nt][r] * inv[r]);
            }
        }
        __syncthreads();                     // B2
        // ---- Wo GEMM + residual + LN1: wave=(mt, cq), 2 tiles ----
        {
            floatx4 acc2[2];
#pragma unroll
            for (int tt = 0; tt < 2; tt++) acc2[tt] = (floatx4){0.f, 0.f, 0.f, 0.f};
            const short8* bpl = BpWO + (size_t)l * 2048;
            for (int kt = 0; kt < 4; kt++) {
                short8 a = *(const short8*)&o16[(mt * 16 + col) * 136 + kt * 32 + quad * 8];
                const short8* bp = bpl + (size_t)(kt * 8 + cq * 2) * 64 + lane;
#pragma unroll
                for (int tt = 0; tt < 2; tt++)
                    acc2[tt] = __builtin_amdgcn_mfma_f32_16x16x32_bf16(a, bp[tt * 64], acc2[tt], 0, 0, 0);
            }
            const float* bol = bo + l * 128;
            float vv[8], rs[4] = {0.f, 0.f, 0.f, 0.f}, rq[4] = {0.f, 0.f, 0.f, 0.f};
#pragma unroll
            for (int tt = 0; tt < 2; tt++) {
                int c = cq * 32 + tt * 16 + col;
                float bv = bol[c];
#pragma unroll
                for (int r = 0; r < 4; r++) {
                    float v = acc2[tt][r] + bv + zreg[tt * 4 + r];
                    vv[tt * 4 + r] = v;
                    rs[r] += v;
                    rq[r] = fmaf(v, v, rq[r]);
                }
            }
#pragma unroll
            for (int m = 1; m <= 8; m <<= 1)
#pragma unroll
                for (int r = 0; r < 4; r++) {
                    rs[r] += __shfl_xor(rs[r], m, 64);
                    rq[r] += __shfl_xor(rq[r], m, 64);
                }
            if (col == 0) {
#pragma unroll
                for (int r = 0; r < 4; r++) {
                    int row = mt * 16 + quad * 4 + r;
                    lnp[(cq * 32 + row) * 2] = rs[r];
                    lnp[(cq * 32 + row) * 2 + 1] = rq[r];
                }
            }
            __syncthreads();                 // B3
            const float* gl = ln1g + l * 128;
            const float* bl = ln1b + l * 128;
#pragma unroll
            for (int r = 0; r < 4; r++) {
                int row = mt * 16 + quad * 4 + r;
                float sm = 0.f, sq = 0.f;
#pragma unroll
                for (int q2 = 0; q2 < 4; q2++) {
                    sm += lnp[(q2 * 32 + row) * 2];
                    sq += lnp[(q2 * 32 + row) * 2 + 1];
                }
                float mean = sm * (1.0f / 128.0f);
                float var = sq * (1.0f / 128.0f) - mean * mean;
                float iv = rsqrtf(var + 1e-5f);
#pragma unroll
                for (int tt = 0; tt < 2; tt++) {
                    int c = cq * 32 + tt * 16 + col;
                    float y = (vv[tt * 4 + r] - mean) * iv * gl[c] + bl[c];
                    zreg[tt * 4 + r] = y;
                    zb[row * 136 + c] = __float2bfloat16(y);
                }
            }
        }
        __syncthreads();                     // B4
        // ---- W1 GEMM + gelu: wave=(mt, nq=cq): 8 tiles of 128-col band ----
        {
            floatx4 acc3[8];
#pragma unroll
            for (int tt = 0; tt < 8; tt++) acc3[tt] = (floatx4){0.f, 0.f, 0.f, 0.f};
            const short8* bpl = BpW1 + (size_t)l * 8192;
            for (int kt = 0; kt < 4; kt++) {
                short8 a = *(const short8*)&zb[(mt * 16 + col) * 136 + kt * 32 + quad * 8];
                const short8* bp = bpl + (size_t)(kt * 32 + cq * 8) * 64 + lane;
#pragma unroll
                for (int tt = 0; tt < 8; tt++)
                    acc3[tt] = __builtin_amdgcn_mfma_f32_16x16x32_bf16(a, bp[tt * 64], acc3[tt], 0, 0, 0);
            }
            const float* b1l = b1 + l * 512;
#pragma unroll
            for (int tt = 0; tt < 8; tt++) {
                int c = cq * 128 + tt * 16 + col;
                float bv = b1l[c];
#pragma unroll
                for (int r = 0; r < 4; r++) {
                    float v = gelu_exact(acc3[tt][r] + bv);
                    f1[(mt * 16 + quad * 4 + r) * 520 + c] = __float2bfloat16(v);
                }
            }
        }
        __syncthreads();                     // B5
        // ---- W2 GEMM + residual + LN2: wave=(mt, cq), 2 tiles, K=512 ----
        {
            floatx4 acc4[2];
#pragma unroll
            for (int tt = 0; tt < 2; tt++) acc4[tt] = (floatx4){0.f, 0.f, 0.f, 0.f};
            const short8* bpl = BpW2 + (size_t)l * 8192;
            for (int kt = 0; kt < 16; kt++) {
                short8 a = *(const short8*)&f1[(mt * 16 + col) * 520 + kt * 32 + quad * 8];
                const short8* bp = bpl + (size_t)(kt * 8 + cq * 2) * 64 + lane;
#pragma unroll
                for (int tt = 0; tt < 2; tt++)
                    acc4[tt] = __builtin_amdgcn_mfma_f32_16x16x32_bf16(a, bp[tt * 64], acc4[tt], 0, 0, 0);
            }
            const float* b2l = b2 + l * 128;
            float vv[8], rs[4] = {0.f, 0.f, 0.f, 0.f}, rq[4] = {0.f, 0.f, 0.f, 0.f};
#pragma unroll
            for (int tt = 0; tt < 2; tt++) {
                int c = cq * 32 + tt * 16 + col;
                float bv = b2l[c];
#pragma unroll
                for (int r = 0; r < 4; r++) {
                    float v = acc4[tt][r] + bv + zreg[tt * 4 + r];
                    vv[tt * 4 + r] = v;
                    rs[r] += v;
                    rq[r] = fmaf(v, v, rq[r]);
                }
            }
#pragma unroll
            for (int m = 1; m <= 8; m <<= 1)
#pragma unroll
                for (int r = 0; r < 4; r++) {
                    rs[r] += __shfl_xor(rs[r], m, 64);
                    rq[r] += __shfl_xor(rq[r], m, 64);
                }
            if (col == 0) {
#pragma unroll
                for (int r = 0; r < 4; r++) {
                    int row = mt * 16 + quad * 4 + r;
                    lnp[(cq * 32 + row) * 2] = rs[r];
                    lnp[(cq * 32 + row) * 2 + 1] = rq[r];
                }
            }
            __syncthreads();                 // B6
            const float* gl = ln2g + l * 128;
            const float* bl = ln2b + l * 128;
#pragma unroll
            for (int r = 0; r < 4; r++) {
                int row = mt * 16 + quad * 4 + r;
                float sm = 0.f, sq = 0.f;
#pragma unroll
                for (int q2 = 0; q2 < 4; q2++) {
                    sm += lnp[(q2 * 32 + row) * 2];
                    sq += lnp[(q2 * 32 + row) * 2 + 1];
                }
                float mean = sm * (1.0f / 128.0f);
                float var = sq * (1.0f / 128.0f) - mean * mean;
                float iv = rsqrtf(var + 1e-5f);
#pragma unroll
                for (int tt = 0; tt < 2; tt++) {
                    int c = cq * 32 + tt * 16 + col;
                    float y = (vv[tt * 4 + r] - mean) * iv * gl[c] + bl[c];
                    zreg[tt * 4 + r] = y;
                    if (l < 2) zb[row * 136 + c] = __float2bfloat16(y);
                    else if (row == 31) zlastb[(size_t)bn * 128 + c] = __float2bfloat16(y);
                }
            }
        }
        __syncthreads();                     // B7
    }
}

// ---------------------------------------------------------------------------
// Head (MFMA): out = gelu(zlast @ W1 + b1) @ W2 + b2. Grid 8 x 256 thr.
__global__ __launch_bounds__(256)
void k_head(const bf16* __restrict__ zlastb, const short8* __restrict__ BpHW1,
            const float* __restrict__ b1, const float* __restrict__ W2,
            const float* __restrict__ b2, float* __restrict__ out) {
    __shared__ bf16 h1[64 * 136];
    int blk = blockIdx.x;
    int tid = threadIdx.x;
    int lane = tid & 63, w = tid >> 6;
    int quad = lane >> 4, col = lane & 15;
    {
        floatx4 acc[8];
#pragma unroll
        for (int tt = 0; tt < 8; tt++) acc[tt] = (floatx4){0.f, 0.f, 0.f, 0.f};
        const short8* Ap = (const short8*)(zlastb + (size_t)(blk * 64 + w * 16 + col) * 128) + quad;
        for (int kt = 0; kt < 4; kt++) {
            short8 a = Ap[kt * 4];
            const short8* bp = BpHW1 + (size_t)(kt * 8) * 64 + lane;
#pragma unroll
            for (int tt = 0; tt < 8; tt++)
                acc[tt] = __builtin_amdgcn_mfma_f32_16x16x32_bf16(a, bp[tt * 64], acc[tt], 0, 0, 0);
        }
#pragma unroll
        for (int tt = 0; tt < 8; tt++) {
            int c = tt * 16 + col;
            float bv = b1[c];
#pragma unroll
            for (int r = 0; r < 4; r++)
                h1[(w * 16 + quad * 4 + r) * 136 + c] = __float2bfloat16(gelu_exact(acc[tt][r] + bv));
        }
    }
    __syncthreads();
    for (int idx = tid; idx < 512; idx += 256) {
        int row = idx >> 3, c = idx & 7;
        if (c < 6) {
            float a0 = 0.f, a1 = 0.f, a2 = 0.f, a3 = 0.f;
            const bf16* hr = &h1[row * 136];
#pragma unroll 8
            for (int k = 0; k < 128; k += 4) {
                a0 = fmaf(bfbits2f(*(const short*)&hr[k]),     W2[k * 6 + c], a0);
                a1 = fmaf(bfbits2f(*(const short*)&hr[k + 1]), W2[(k + 1) * 6 + c], a1);
                a2 = fmaf(bfbits2f(*(const short*)&hr[k + 2]), W2[(k + 2) * 6 + c], a2);
                a3 = fmaf(bfbits2f(*(const short*)&hr[k + 3]), W2[(k + 3) * 6 + c], a3);
            }
            out[(size_t)(blk * 64 + row) * 6 + c] = (a0 + a1) + (a2 + a3) + b2[c];
        }
    }
}

// ---------------------------------------------------------------------------
extern "C" void kernel_launch(void* const* d_in, const int* in_sizes, int n_in,
                              void* d_out, int out_size, void* d_ws, size_t ws_size,
                              hipStream_t stream) {
    const float* input_frames = (const float*)d_in[0];
    const float* edge_attr    = (const float*)d_in[1];
    const float* proj_W  = (const float*)d_in[2];
    const float* proj_b  = (const float*)d_in[3];
    const float* sp_Wq   = (const float*)d_in[4];
    const float* sp_bq   = (const float*)d_in[5];
    const float* sp_Wk   = (const float*)d_in[6];
    const float* sp_bk   = (const float*)d_in[7];
    const float* sp_Wv   = (const float*)d_in[8];
    const float* sp_bv   = (const float*)d_in[9];
    const float* sp_We   = (const float*)d_in[10];
    const float* sp_be   = (const float*)d_in[11];
    const float* sp_Ws   = (const float*)d_in[12];
    const float* sp_bs   = (const float*)d_in[13];
    const float* sp_lng  = (const float*)d_in[14];
    const float* sp_lnb  = (const float*)d_in[15];
    const float* tpos    = (const float*)d_in[16];
    const float* t_Wqkv  = (const float*)d_in[17];
    const float* t_bqkv  = (const float*)d_in[18];
    const float* t_Wo    = (const float*)d_in[19];
    const float* t_bo    = (const float*)d_in[20];
    const float* t_ln1g  = (const float*)d_in[21];
    const float* t_ln1b  = (const float*)d_in[22];
    const float* t_W1    = (const float*)d_in[23];
    const float* t_b1    = (const float*)d_in[24];
    const float* t_W2    = (const float*)d_in[25];
    const float* t_b2    = (const float*)d_in[26];
    const float* t_ln2g  = (const float*)d_in[27];
    const float* t_ln2b  = (const float*)d_in[28];
    const float* head_W1 = (const float*)d_in[29];
    const float* head_b1 = (const float*)d_in[30];
    const float* head_W2 = (const float*)d_in[31];
    const float* head_b2 = (const float*)d_in[32];

    float* f     = (float*)d_ws;
    float* z32g  = f;                                  // 2M floats
    bf16*  zlastb = (bf16*)(f + (1u << 21));           // 64K bf16
    float* spb   = f + (1u << 21) + 65536;             // 1152 floats
    bf16* BpBase = (bf16*)(f + (1u << 21) + 65536 + 2048);
    bf16* BpSPQKV = BpBase;                            // 147456 bf16
    bf16* BpWS    = BpSPQKV + 147456;                  //  49152
    bf16* BpTQKV  = BpWS + 49152;                      // 147456
    bf16* BpWO    = BpTQKV + 147456;                   //  49152
    bf16* BpW1    = BpWO + 49152;                      // 196608
    bf16* BpW2    = BpW1 + 196608;                     // 196608
    bf16* BpHW1   = BpW2 + 196608;                     //  16384

    RepackArgs ra;
    int s = 0;
    auto mk = [&](int i, const float* W, bf16* out, int K, int N, int ntt, int ntoff, int L) {
        ra.d[i] = {W, out, K, N, ntt, ntoff, L, s};
        s += L * (K >> 5) * (N >> 4) * 64;
    };
    mk(0, sp_Wq, BpSPQKV, 128, 128, 24, 0, 3);
    mk(1, sp_Wk, BpSPQKV, 128, 128, 24, 8, 3);
    mk(2, sp_Wv, BpSPQKV, 128, 128, 24, 16, 3);
    mk(3, sp_Ws, BpWS, 128, 128, 8, 0, 3);
    mk(4, t_Wqkv, BpTQKV, 128, 384, 24, 0, 3);
    mk(5, t_Wo, BpWO, 128, 128, 8, 0, 3);
    mk(6, t_W1, BpW1, 128, 512, 32, 0, 3);
    mk(7, t_W2, BpW2, 512, 128, 8, 0, 3);
    mk(8, head_W1, BpHW1, 128, 128, 8, 0, 1);
    ra.total = s;
    k_repack<<<(s + 255) / 256, 256, 0, stream>>>(ra);
    k_packbias<<<(3 * 384 + 255) / 256, 256, 0, stream>>>(sp_bq, sp_bk, sp_bv, spb);

    k_spatial3<<<BT_, 512, 0, stream>>>(
        input_frames, proj_W, proj_b,
        (const short8*)BpSPQKV, (const short8*)BpWS,
        spb, sp_bs, sp_lng, sp_lnb, edge_attr, sp_We, sp_be, tpos, z32g);

    k_temporal3<<<BN_, 512, 0, stream>>>(
        z32g, (const short8*)BpTQKV, (const short8*)BpWO,
        (const short8*)BpW1, (const short8*)BpW2,
        t_bqkv, t_bo, t_ln1g, t_ln1b, t_b1, t_b2, t_ln2g, t_ln2b, zlastb);

    k_head<<<8, 256, 0, stream>>>(zlastb, (const short8*)BpHW1, head_b1,
                                  head_W2, head_b2, (float*)d_out);
}